// Round 3
// baseline (261.727 us; speedup 1.0000x reference)
//
#include <hip/hip_runtime.h>
#include <hip/hip_fp16.h>
#include <math.h>

#define HC 32      // H*C
#define CH 16      // channels per head
#define NSLOPE 0.2f
#define NB2MAX 512 // max coarse buckets (128 nodes each; N <= 65536)
#define TILE 8192
#define CBMAX 6144 // colbuf per 128-node bucket (avg ~4.2K pairs)
#define NSL 128    // edge slices for src histogram -> exactly 256 blocks (1/CU)
#define HGRP 8     // slice groups for k_hred (NSL % HGRP == 0)
#define HLDS 12544 // LDS words per half-range histogram (supports halfN <= 25088)

// pair entry: (dst<<16) | src ; self pairs appended
__device__ __forceinline__ unsigned gen_pair(const int* __restrict__ ei, int E, int i){
    if (i < E) return (unsigned(ei[E+i]) << 16) | unsigned(ei[i]);
    unsigned n = i - E; return (n << 16) | n;
}

// packed fp16 max (ROCm 7.2 header lacks __hmax2)
__device__ __forceinline__ __half2 pkmax2(__half2 a, __half2 b){
    union { __half2 h; unsigned u; } ua, ub, ud;
    ua.h = a; ub.h = b;
    asm("v_pk_max_f16 %0, %1, %2" : "=v"(ud.u) : "v"(ua.u), "v"(ub.u));
    return ud.h;
}

__device__ __forceinline__ __half2 sfx2(__half2 x, int off){
    union { __half2 h; int i; } u; u.h = x;
    u.i = __shfl_xor(u.i, off);
    return u.h;
}

// src-degree histogram (multi-copy LDS, packed u16 counters) + fused coarse
// dst histogram (p==0 blocks). NOTE: scattered global atomics are ~50MB of
// write-through traffic on MI355X (round-1 regression) — LDS privatization
// with a 12.8MB coalesced spill buffer is strictly faster.
__global__ void k_hsrc(const int* __restrict__ ei, int E, int halfN,
                       unsigned* __restrict__ hb, unsigned* __restrict__ gPair){
    __shared__ unsigned h[HLDS];
    __shared__ unsigned hp[NB2MAX];
    int t = threadIdx.x;                 // 512
    int nWloc = halfN >> 1;
    for (int i = t; i < nWloc; i += 512) h[i] = 0;
    int p = blockIdx.x & 1;
    if (p == 0) hp[t] = 0;
    __syncthreads();
    int slice = blockIdx.x >> 1;
    int base  = p * halfN;
    int chunk = (E + NSL - 1) / NSL;
    int lo = slice*chunk, hi = lo + chunk; if (hi > E) hi = E;
    if (p == 0){
        for (int i = lo + t; i < hi; i += 512){
            int s = ei[i] - base;
            if ((unsigned)s < (unsigned)halfN)
                atomicAdd(&h[s >> 1], 1u << (16*(s & 1)));
            atomicAdd(&hp[unsigned(ei[E+i]) >> 7], 1u);   // coarse dst histogram (128-node buckets)
        }
    } else {
        for (int i = lo + t; i < hi; i += 512){
            int s = ei[i] - base;
            if ((unsigned)s < (unsigned)halfN)
                atomicAdd(&h[s >> 1], 1u << (16*(s & 1)));
        }
    }
    __syncthreads();
    unsigned* out = hb + (size_t)blockIdx.x * nWloc;
    for (int w = t; w < nWloc; w += 512) out[w] = h[w];
    if (p == 0 && hp[t]) atomicAdd(&gPair[t], hp[t]);
}

// reduce NSL slice copies into degS; HGRP partial groups via dense atomics (degS pre-zeroed)
__global__ void k_hred(const unsigned* __restrict__ hb, unsigned* __restrict__ degS,
                       int nWloc){
    int idx = blockIdx.x*blockDim.x + threadIdx.x;
    int total = 2*nWloc;
    int grp = idx / total;
    if (grp >= HGRP) return;
    int rem = idx - grp*total;
    int p = (rem < nWloc) ? 0 : 1;
    int w = rem - p*nWloc;
    unsigned s = 0;
    int sl0 = grp*(NSL/HGRP), sl1 = sl0 + NSL/HGRP;
    for (int sl = sl0; sl < sl1; ++sl)
        s += hb[(size_t)(sl*2 + p)*nWloc + w];
    if (s) atomicAdd(&degS[rem], s);
}

// fused: add self-loop counts, 512-bucket scan, graph bounds, layer-1 weight pack
__global__ void k_setup(unsigned* __restrict__ gPair,
                        int* __restrict__ partBase, int* __restrict__ gcur,
                        int* __restrict__ rsN, int EP, int nb,
                        const int* __restrict__ batch, int* __restrict__ gb, int N, int G,
                        const float* __restrict__ W1l, const float* __restrict__ b1l,
                        const float* __restrict__ W1r, const float* __restrict__ b1r,
                        const float* __restrict__ att1, const float* __restrict__ bias1,
                        float4* __restrict__ tabA, float4* __restrict__ tabB){
    __shared__ int sp[NB2MAX];
    int t = threadIdx.x;   // 512
    int vp = 0;
    if (t < nb){
        int selfc = N - t*128;
        selfc = (selfc < 0) ? 0 : (selfc > 128 ? 128 : selfc);
        vp = (int)gPair[t] + selfc;
        gPair[t] = (unsigned)vp;          // total pairs per bucket (incl self-loops)
    }
    sp[t] = vp;
    __syncthreads();
    for (int d = 1; d < NB2MAX; d <<= 1){
        int x = (t >= d) ? sp[t-d] : 0;
        __syncthreads();
        sp[t] += x;
        __syncthreads();
    }
    if (t < nb){ partBase[t] = sp[t] - vp; gcur[t] = sp[t] - vp; }
    if (t == 0) rsN[0] = EP;
    for (int g = t; g <= G; g += 512){
        int lo = 0, hi = N;
        while (lo < hi){ int mid = (lo+hi)>>1; if (batch[mid] < g) lo = mid+1; else hi = mid; }
        gb[g] = lo;
    }
    if (t < HC){
        tabA[t] = make_float4(W1l[t*3] + b1l[t], W1l[t*3+1], W1l[t*3+2], att1[t]);
        tabB[t] = make_float4(W1r[t*3] + b1r[t], W1r[t*3+1], W1r[t*3+2], bias1[t]);
    }
}

// P2: per-tile LDS counting sort into 512 coarse buckets (bucket = dst>>7 = e>>23).
// Full tiles cache their 32 pair-entries in registers (static indices only) so
// the edge list is read once per tile, not twice.
__global__ void k_p2(const int* __restrict__ ei, int E, int EP,
                     int* __restrict__ gcur, unsigned* __restrict__ part){
    __shared__ int bcnt[NB2MAX], bstart[NB2MAX], c2[NB2MAX], gpos[NB2MAX], sc[256];
    __shared__ unsigned sorted[TILE];
    __shared__ unsigned short bktof[TILE];
    int t = threadIdx.x;   // 256
    int base = blockIdx.x * TILE;
    int cnt = EP - base; if (cnt > TILE) cnt = TILE;
    bool full = (cnt == TILE);

    bcnt[t] = 0; bcnt[t+256] = 0; c2[t] = 0; c2[t+256] = 0;
    __syncthreads();
    unsigned ec[TILE/256];
    if (full){
        #pragma unroll
        for (int q = 0; q < TILE/256; ++q)
            ec[q] = gen_pair(ei, E, base + t + q*256);
        #pragma unroll
        for (int q = 0; q < TILE/256; ++q)
            atomicAdd(&bcnt[ec[q] >> 23], 1);
    } else {
        for (int j = t; j < cnt; j += 256){
            unsigned e = gen_pair(ei, E, base + j);
            atomicAdd(&bcnt[e >> 23], 1);
        }
    }
    __syncthreads();
    int v0 = bcnt[2*t], v1 = bcnt[2*t+1];
    int s = v0 + v1;
    sc[t] = s;
    __syncthreads();
    for (int d = 1; d < 256; d <<= 1){
        int x = (t >= d) ? sc[t-d] : 0;
        __syncthreads();
        sc[t] += x;
        __syncthreads();
    }
    int excl = sc[t] - s;
    bstart[2*t]   = excl;
    bstart[2*t+1] = excl + v0;
    #pragma unroll
    for (int q = 0; q < 2; ++q){
        int bb = 2*t + q;
        int v = (q == 0) ? v0 : v1;
        if (v > 0){
            gpos[bb] = atomicAdd(&gcur[bb], v);
            int bs = bstart[bb];
            for (int j = 0; j < v; ++j) bktof[bs + j] = (unsigned short)bb;
        }
    }
    __syncthreads();
    if (full){
        #pragma unroll
        for (int q = 0; q < TILE/256; ++q){
            unsigned e = ec[q];
            int b = e >> 23;
            int off = atomicAdd(&c2[b], 1);
            sorted[bstart[b] + off] = e;
        }
    } else {
        for (int j = t; j < cnt; j += 256){
            unsigned e = gen_pair(ei, E, base + j);
            int b = e >> 23;
            int off = atomicAdd(&c2[b], 1);
            sorted[bstart[b] + off] = e;
        }
    }
    __syncthreads();
    for (int k = t; k < cnt; k += 256){
        int b = bktof[k];
        part[gpos[b] + (k - bstart[b])] = sorted[k];
    }
}

// fine pass: one block per 128-node bucket -> rs, (deg,rnd), col (coalesced out)
__global__ void k_fine(const unsigned* __restrict__ part, const int* __restrict__ partBase,
                       const unsigned* __restrict__ gPair,
                       const unsigned* __restrict__ degS, const float* __restrict__ rnd,
                       int* __restrict__ rs, float2* __restrict__ dr,
                       int* __restrict__ col, int N){
    __shared__ int pcnt[128], c2[128], lrs[129], sc[128];
    __shared__ int colbuf[CBMAX];
    int b = blockIdx.x, t = threadIdx.x;   // 256
    int beg = partBase[b], end = beg + (int)gPair[b];
    if (t < 128){ pcnt[t] = 0; c2[t] = 0; }
    __syncthreads();
    for (int k = beg + t; k < end; k += 256)
        atomicAdd(&pcnt[(part[k] >> 16) & 127], 1);
    __syncthreads();
    int v = (t < 128) ? pcnt[t] : 0;
    if (t < 128) sc[t] = v;
    __syncthreads();
    for (int d = 1; d < 128; d <<= 1){
        int x = (t >= d && t < 128) ? sc[t-d] : 0;
        __syncthreads();
        if (t < 128) sc[t] += x;
        __syncthreads();
    }
    if (t < 128){
        lrs[t] = sc[t] - v;
        if (t == 127) lrs[128] = sc[127];
    }
    __syncthreads();
    int n = (b << 7) + t;
    if (t < 128 && n < N){
        rs[n] = partBase[b] + lrs[t];
        unsigned s16 = (degS[n >> 1] >> (16*(n & 1))) & 0xFFFFu;
        dr[n] = make_float2((float)(pcnt[t] - 1 + (int)s16), rnd[n]);
    }
    for (int k = beg + t; k < end; k += 256){
        unsigned e = part[k];
        int j = (e >> 16) & 127;
        int pos = lrs[j] + atomicAdd(&c2[j], 1);
        if (pos < CBMAX) colbuf[pos] = (int)(e & 0xFFFFu);
    }
    __syncthreads();
    int npair = lrs[128];
    int cb = partBase[b];
    for (int k = t; k < npair; k += 256) col[cb + k] = colbuf[k];
}

// fused layer-1 GATv2 + layer-2 input projection. Single-shot edge loop:
// all col loads issue first, then all dr gathers (clamped addresses, masked
// contributions) — one dependent chain instead of 2-3 serial iterations.
__global__ void k_gat1(const int* __restrict__ rs, const int* __restrict__ col,
                       const float2* __restrict__ dr,
                       const float4* __restrict__ tabA, const float4* __restrict__ tabB,
                       const float* __restrict__ W2l, const float* __restrict__ b2l,
                       const float* __restrict__ W2r, const float* __restrict__ b2r,
                       __half* __restrict__ A16, __half* __restrict__ B16, int N){
    __shared__ float wl[HC][HC+1], wr[HC][HC+1];   // [j][k] transposed, +1 pad
    __shared__ float blS[HC], brS[HC];
    int t = threadIdx.x;                 // 256
    for (int w = t; w < HC*HC; w += 256){
        int k = w >> 5, j = w & 31;
        wl[j][k] = W2l[w];
        wr[j][k] = W2r[w];
    }
    if (t < HC){ blS[t] = b2l[t]; brS[t] = b2r[t]; }
    __syncthreads();

    int d = blockIdx.x*(blockDim.x >> 4) + (t >> 4);
    if (d >= N) return;
    int lane = t & 15;
    int h = lane >> 3, r = lane & 7;

    float2 drd = dr[d];
    float base[CH], v[CH], w[CH], at[CH];
    #pragma unroll
    for (int c = 0; c < CH; ++c){
        float4 a4 = tabA[h*CH + c];
        float4 b4 = tabB[h*CH + c];
        float xr = b4.x + b4.y*drd.x + b4.z*drd.y;
        base[c] = a4.x + xr; v[c] = a4.y; w[c] = a4.z; at[c] = a4.w;
    }

    float l = 0.f, S1 = 0.f, S2 = 0.f;
    int beg = rs[d], end = rs[d+1];
    int p = beg + r;
    // main quad loop: runs only when per-head degree > 32
    for (; p + 24 < end; p += 32){
        int s0 = col[p], s1 = col[p+8], s2 = col[p+16], s3 = col[p+24];
        float2 d0 = dr[s0], d1 = dr[s1], d2 = dr[s2], d3 = dr[s3];
        float sc0 = 0.f, sc1 = 0.f, sc2 = 0.f, sc3 = 0.f;
        #pragma unroll
        for (int c = 0; c < CH; ++c){
            float m0 = base[c] + v[c]*d0.x + w[c]*d0.y;
            float m1 = base[c] + v[c]*d1.x + w[c]*d1.y;
            float m2 = base[c] + v[c]*d2.x + w[c]*d2.y;
            float m3 = base[c] + v[c]*d3.x + w[c]*d3.y;
            m0 = (m0 > 0.f) ? m0 : NSLOPE*m0;
            m1 = (m1 > 0.f) ? m1 : NSLOPE*m1;
            m2 = (m2 > 0.f) ? m2 : NSLOPE*m2;
            m3 = (m3 > 0.f) ? m3 : NSLOPE*m3;
            sc0 += m0*at[c]; sc1 += m1*at[c]; sc2 += m2*at[c]; sc3 += m3*at[c];
        }
        float ex0 = __expf(sc0), ex1 = __expf(sc1);
        float ex2 = __expf(sc2), ex3 = __expf(sc3);
        l  += ex0 + ex1;            l  += ex2 + ex3;
        S1 += ex0*d0.x + ex1*d1.x;  S1 += ex2*d2.x + ex3*d3.x;
        S2 += ex0*d0.y + ex1*d1.y;  S2 += ex2*d2.y + ex3*d3.y;
    }
    {   // masked tail: up to 3 edges; clamped addresses keep all loads in flight
        bool q0 = p < end, q1 = p + 8 < end, q2 = p + 16 < end;
        int pc0 = q0 ? p : beg, pc1 = q1 ? p + 8 : beg, pc2 = q2 ? p + 16 : beg;
        int s0 = col[pc0], s1 = col[pc1], s2 = col[pc2];
        float2 d0 = dr[s0], d1 = dr[s1], d2 = dr[s2];
        float sc0 = 0.f, sc1 = 0.f, sc2 = 0.f;
        #pragma unroll
        for (int c = 0; c < CH; ++c){
            float m0 = base[c] + v[c]*d0.x + w[c]*d0.y;
            float m1 = base[c] + v[c]*d1.x + w[c]*d1.y;
            float m2 = base[c] + v[c]*d2.x + w[c]*d2.y;
            m0 = (m0 > 0.f) ? m0 : NSLOPE*m0;
            m1 = (m1 > 0.f) ? m1 : NSLOPE*m1;
            m2 = (m2 > 0.f) ? m2 : NSLOPE*m2;
            sc0 += m0*at[c]; sc1 += m1*at[c]; sc2 += m2*at[c];
        }
        float ex0 = q0 ? __expf(sc0) : 0.f;
        float ex1 = q1 ? __expf(sc1) : 0.f;
        float ex2 = q2 ? __expf(sc2) : 0.f;
        l  += ex0 + ex1;            l  += ex2;
        S1 += ex0*d0.x + ex1*d1.x;  S1 += ex2*d2.x;
        S2 += ex0*d0.y + ex1*d1.y;  S2 += ex2*d2.y;
    }

    #pragma unroll
    for (int off = 4; off >= 1; off >>= 1){
        l  += __shfl_xor(l,  off);
        S1 += __shfl_xor(S1, off);
        S2 += __shfl_xor(S2, off);
    }

    // layer-1 output channels 2*lane, 2*lane+1 (ELU'd), in-register
    float invl = 1.f/(l + 1e-16f);
    int c0 = r*2;
    float4 a40 = tabA[h*CH + c0],     b40 = tabB[h*CH + c0];
    float4 a41 = tabA[h*CH + c0 + 1], b41 = tabB[h*CH + c0 + 1];
    float v0 = a40.x + (a40.y*S1 + a40.z*S2)*invl + b40.w;
    float v1 = a41.x + (a41.y*S1 + a41.z*S2)*invl + b41.w;
    float x0 = (v0 > 0.f) ? v0 : expm1f(v0);
    float x1 = (v1 > 0.f) ? v1 : expm1f(v1);

    // in-subgroup 32x32 projection: out[k] = b[k] + sum_j x[j]*W[k][j]
    int k0 = 2*lane;
    float a0 = blS[k0], a1 = blS[k0+1];
    float g0 = brS[k0], g1 = brS[k0+1];
    #pragma unroll
    for (int tt = 0; tt < 16; ++tt){
        float xa = __shfl(x0, tt, 16);     // x[2*tt]
        float xb = __shfl(x1, tt, 16);     // x[2*tt+1]
        int j = 2*tt;
        a0 += xa*wl[j][k0]   + xb*wl[j+1][k0];
        a1 += xa*wl[j][k0+1] + xb*wl[j+1][k0+1];
        g0 += xa*wr[j][k0]   + xb*wr[j+1][k0];
        g1 += xa*wr[j][k0+1] + xb*wr[j+1][k0+1];
    }
    *(__half2*)(A16 + (size_t)d*HC + k0) = __floats2half2_rn(a0, a1);
    *(__half2*)(B16 + (size_t)d*HC + k0) = __floats2half2_rn(g0, g1);
}

// one edge-head contribution: fp16 score + masked exp + fp16 accumulate.
// VALID=false contributes exact zeros (bit-identical to skipping).
#define EDGE2(X, VALID) do { \
    __half2 sc2_ = __float2half2_rn(0.f); \
    _Pragma("unroll") \
    for (int i_ = 0; i_ < 8; ++i_){ \
        __half2 m_  = __hadd2((X).h2[i_], xr.h2[i_]); \
        __half2 lk_ = pkmax2(m_, __hmul2(m_, ns2)); \
        sc2_ = __hfma2(lk_, at2[i_], sc2_); \
    } \
    float ex_ = __expf(__low2float(sc2_) + __high2float(sc2_)); \
    if (!(VALID)) ex_ = 0.f; \
    l += ex_; \
    __half2 exh_ = __float2half2_rn(ex_); \
    _Pragma("unroll") \
    for (int i_ = 0; i_ < 8; ++i_) acc2[i_] = __hfma2((X).h2[i_], exh_, acc2[i_]); \
} while(0)

// fused layer-2 GATv2 + mean-pool accumulation: head-paired 32-lane subgroup
// per dst; single-shot masked edge processing (deg<=64 common case = one
// dependent chain); packed fp16 math; channel-splitting halving merge;
// epilogue ELUs and atomicAdds into pooled[batch[d]][k] (L2-resident).
__global__ void k_gat(const int* __restrict__ rs, const int* __restrict__ col,
                      const __half* __restrict__ A16, const __half* __restrict__ B16,
                      const float* __restrict__ att, const float* __restrict__ bias,
                      const int* __restrict__ batch, float* __restrict__ pooled, int N){
    int d = blockIdx.x*(blockDim.x >> 5) + (threadIdx.x >> 5);
    int lane = threadIdx.x & 31;
    if (d >= N) return;
    int h = lane >> 4, r = lane & 15;

    union U { uint4 u[2]; __half2 h2[8]; };
    U xr;
    {
        const uint4* bp = (const uint4*)(B16 + (size_t)d*HC + h*CH);
        xr.u[0] = bp[0]; xr.u[1] = bp[1];
    }
    __half2 at2[8];
    const float* atf = att + h*CH;
    #pragma unroll
    for (int i = 0; i < 8; ++i) at2[i] = __floats2half2_rn(atf[2*i], atf[2*i+1]);
    const __half2 ns2 = __float2half2_rn(NSLOPE);

    float l = 0.f;
    __half2 acc2[8];
    #pragma unroll
    for (int i = 0; i < 8; ++i) acc2[i] = __float2half2_rn(0.f);

    int beg = rs[d], end = rs[d+1];
    int p = beg + r;

    // main quad loop: runs only when subgroup degree > 64
    for (; p + 48 < end; p += 64){
        int s0 = col[p], s1 = col[p+16], s2 = col[p+32], s3 = col[p+48];
        const uint4* rp0 = (const uint4*)(A16 + (size_t)s0*HC + h*CH);
        const uint4* rp1 = (const uint4*)(A16 + (size_t)s1*HC + h*CH);
        const uint4* rp2 = (const uint4*)(A16 + (size_t)s2*HC + h*CH);
        const uint4* rp3 = (const uint4*)(A16 + (size_t)s3*HC + h*CH);
        U a, b, c, e;
        a.u[0] = rp0[0]; a.u[1] = rp0[1];
        b.u[0] = rp1[0]; b.u[1] = rp1[1];
        c.u[0] = rp2[0]; c.u[1] = rp2[1];
        e.u[0] = rp3[0]; e.u[1] = rp3[1];
        EDGE2(a, true); EDGE2(b, true); EDGE2(c, true); EDGE2(e, true);
    }
    {   // masked tail: up to 3 edges; clamped addresses keep all loads in flight
        bool q0 = p < end, q1 = p + 16 < end, q2 = p + 32 < end;
        int pc0 = q0 ? p : beg, pc1 = q1 ? p + 16 : beg, pc2 = q2 ? p + 32 : beg;
        int s0 = col[pc0], s1 = col[pc1], s2 = col[pc2];
        const uint4* rp0 = (const uint4*)(A16 + (size_t)s0*HC + h*CH);
        const uint4* rp1 = (const uint4*)(A16 + (size_t)s1*HC + h*CH);
        const uint4* rp2 = (const uint4*)(A16 + (size_t)s2*HC + h*CH);
        U a, b, c;
        a.u[0] = rp0[0]; a.u[1] = rp0[1];
        b.u[0] = rp1[0]; b.u[1] = rp1[1];
        c.u[0] = rp2[0]; c.u[1] = rp2[1];
        EDGE2(a, q0); EDGE2(b, q1); EDGE2(c, q2);
    }

    // channel-splitting halving merge across the 16-lane half.
    __half2 v4[4];
    {
        bool hi = (r & 8) != 0;
        #pragma unroll
        for (int i = 0; i < 4; ++i){
            __half2 send = hi ? acc2[i] : acc2[i+4];
            __half2 recv = sfx2(send, 8);
            v4[i] = __hadd2(hi ? acc2[i+4] : acc2[i], recv);
        }
    }
    __half2 v2[2];
    {
        bool hi = (r & 4) != 0;
        __half2 s0 = hi ? v4[0] : v4[2];
        __half2 s1 = hi ? v4[1] : v4[3];
        __half2 r0 = sfx2(s0, 4);
        __half2 r1 = sfx2(s1, 4);
        v2[0] = __hadd2(hi ? v4[2] : v4[0], r0);
        v2[1] = __hadd2(hi ? v4[3] : v4[1], r1);
    }
    __half2 v1;
    {
        bool hi = (r & 2) != 0;
        __half2 send = hi ? v2[0] : v2[1];
        __half2 recv = sfx2(send, 2);
        v1 = __hadd2(hi ? v2[1] : v2[0], recv);
    }
    float mine;
    {
        bool hi = (r & 1) != 0;
        float lo = __low2float(v1), hf = __high2float(v1);
        float send = hi ? lo : hf;
        float recv = __shfl_xor(send, 1);
        mine = (hi ? hf : lo) + recv;   // lane r owns channel r total
    }
    #pragma unroll
    for (int off = 8; off >= 1; off >>= 1) l += __shfl_xor(l, off);

    float invl = 1.f/(l + 1e-16f);
    float val = mine*invl + bias[h*CH + r];
    val = (val > 0.f) ? val : expm1f(val);
    atomicAdd(&pooled[(size_t)batch[d]*HC + h*CH + r], val);
}

// tiny classifier: mean over graph (counts from gb) + fc + log_softmax
__global__ void k_fc(const float* __restrict__ pooled, const int* __restrict__ gb,
                     const float* __restrict__ Wfc, const float* __restrict__ bfc,
                     float* __restrict__ out, int G){
    int t = threadIdx.x;            // 64 -> two graphs per wave
    int g = blockIdx.x*2 + (t >> 5);
    int c = t & 31;
    if (g >= G) return;
    float cnt = (float)(gb[g+1] - gb[g]);
    if (cnt < 1.f) cnt = 1.f;
    float pv = pooled[g*HC + c] / cnt;
    float p0 = pv * Wfc[c];
    float p1 = pv * Wfc[HC + c];
    #pragma unroll
    for (int off = 16; off >= 1; off >>= 1){
        p0 += __shfl_xor(p0, off, 32);
        p1 += __shfl_xor(p1, off, 32);
    }
    if (c == 0){
        float l0 = p0 + bfc[0], l1 = p1 + bfc[1];
        float m = (l0 > l1) ? l0 : l1;
        float lse = m + logf(__expf(l0 - m) + __expf(l1 - m));
        out[g*2 + 0] = l0 - lse;
        out[g*2 + 1] = l1 - lse;
    }
}

extern "C" void kernel_launch(void* const* d_in, const int* in_sizes, int n_in,
                              void* d_out, int out_size, void* d_ws, size_t ws_size,
                              hipStream_t stream) {
    const int*   ei    = (const int*)  d_in[0];
    const int*   batch = (const int*)  d_in[1];
    const float* rnd   = (const float*)d_in[2];
    const float* W1l   = (const float*)d_in[3];
    const float* b1l   = (const float*)d_in[4];
    const float* W1r   = (const float*)d_in[5];
    const float* b1r   = (const float*)d_in[6];
    const float* att1  = (const float*)d_in[7];
    const float* bias1 = (const float*)d_in[8];
    const float* W2l   = (const float*)d_in[9];
    const float* b2l   = (const float*)d_in[10];
    const float* W2r   = (const float*)d_in[11];
    const float* b2r   = (const float*)d_in[12];
    const float* att2  = (const float*)d_in[13];
    const float* bias2 = (const float*)d_in[14];
    const float* Wfc   = (const float*)d_in[15];
    const float* bfc   = (const float*)d_in[16];

    const int E  = in_sizes[0] / 2;
    const int N  = in_sizes[1];
    const int G  = out_size / 2;
    const int EP = E + N;                    // pairs (edges + self-loops)
    const int NB2 = (N + 127) >> 7;          // 128-node coarse buckets
    const int halfN = (((N + 1) >> 1) + 1) & ~1;   // even half-range
    const int nWloc = halfN >> 1;            // packed u16 words per half

    // workspace layout. Liveness-based aliasing:
    //   hb (12.8MB, k_hsrc->k_hred) aliases [0 .. 12.8MB): A16,B16 and the low
    //     part of col are all written strictly AFTER hb dies.
    //   part (6.6MB, k_p2->k_fine) aliases [0 .. 6.6MB): A16/B16 written after.
    //   dr/rs/col sit above the hb region; degS+ctrl above those.
    float* ws        = (float*)d_ws;
    __half* A16      = (__half*)ws;             // N*HC halfs
    __half* B16      = A16 + (size_t)N*HC;      // N*HC halfs
    unsigned* hb     = (unsigned*)ws;           // NSL*2 * nWloc words
    unsigned* part   = (unsigned*)ws;           // EP u32
    size_t off       = (size_t)NSL*2*nWloc;     // words consumed by hb
    if (off < (size_t)EP)   off = EP;           // ... and part
    if (off < (size_t)N*HC) off = (size_t)N*HC; // ... and A16+B16
    off = (off + 1) & ~(size_t)1;
    float2* dr       = (float2*)(ws + off);     // N float2 (deg, rnd)
    int*   rs        = (int*)(dr + N);          // N+1
    int*   col       = rs + N + 1;              // EP
    unsigned* degS   = (unsigned*)(col + EP);   // 2*nWloc words (packed u16)
    unsigned* gPair  = degS + 2*nWloc;          // NB2MAX
    float* pooled    = (float*)(gPair + NB2MAX);// G*HC
    int*   partBase  = (int*)(pooled + (size_t)G*HC);  // NB2MAX
    int*   gcur      = partBase + NB2MAX;       // NB2MAX
    int*   gb        = gcur + NB2MAX;           // G+1
    float4* tabA     = (float4*)((((size_t)(gb + G + 1)) + 15) & ~(size_t)15);
    float4* tabB     = tabA + HC;

    const int T = 256;
    const int gD16 = (N + (T>>4) - 1)/(T>>4);   // 16-lane-per-dst subgroups (layer 1)
    const int gD32 = (N + (T>>5) - 1)/(T>>5);   // 32-lane-per-dst subgroups (layer 2)
    const int nTiles = (EP + TILE - 1)/TILE;

    // degS + gPair + pooled adjacent: one memset zeroes all three
    (void)hipMemsetAsync(degS, 0, (size_t)(2*nWloc + NB2MAX + (size_t)G*HC)*sizeof(unsigned), stream);

    // ---- degree + CSR build (LDS-privatized histograms; NO global scatter atomics) ----
    k_hsrc <<<NSL*2, 512, 0, stream>>>(ei, E, halfN, hb, gPair);
    k_hred <<<(2*nWloc*HGRP + T-1)/T, T, 0, stream>>>(hb, degS, nWloc);
    k_setup<<<1, 512, 0, stream>>>(gPair, partBase, gcur, rs + N, EP, NB2,
                                   batch, gb, N, G,
                                   W1l, b1l, W1r, b1r, att1, bias1, tabA, tabB);
    k_p2   <<<nTiles, T, 0, stream>>>(ei, E, EP, gcur, part);
    k_fine <<<NB2, T, 0, stream>>>(part, partBase, gPair, degS, rnd, rs, dr, col, N);

    // ---- layer 1 fused with layer-2 projection (A16/B16; X never materialized) ----
    k_gat1<<<gD16, T, 0, stream>>>(rs, col, dr, tabA, tabB,
                                   W2l, b2l, W2r, b2r, A16, B16, N);

    // ---- layer 2 fused with mean-pool accumulation ----
    k_gat <<<gD32, T, 0, stream>>>(rs, col, A16, B16, att2, bias2, batch, pooled, N);

    // ---- tiny classifier ----
    k_fc  <<<(G + 1)/2, 64, 0, stream>>>(pooled, gb, Wfc, bfc, (float*)d_out, G);
}

// Round 4
// 242.732 us; speedup vs baseline: 1.0783x; 1.0783x over previous
//
#include <hip/hip_runtime.h>
#include <hip/hip_fp16.h>
#include <math.h>

#define HC 32      // H*C
#define CH 16      // channels per head
#define NSLOPE 0.2f
#define NB2MAX 512 // max coarse buckets (128 nodes each; N <= 65536)
#define TILE 8192
#define CBMAX 6144 // colbuf per 128-node bucket (avg ~4.2K pairs)
#define NSL 128    // edge slices for src histogram -> exactly 256 blocks (1/CU)
#define HGRP 8     // slice groups for k_hred (NSL % HGRP == 0)
#define HLDS 12544 // LDS words per half-range histogram (supports halfN <= 25088)

// pair entry: (dst<<16) | src ; self pairs appended
__device__ __forceinline__ unsigned gen_pair(const int* __restrict__ ei, int E, int i){
    if (i < E) return (unsigned(ei[E+i]) << 16) | unsigned(ei[i]);
    unsigned n = i - E; return (n << 16) | n;
}

// packed fp16 max (ROCm 7.2 header lacks __hmax2)
__device__ __forceinline__ __half2 pkmax2(__half2 a, __half2 b){
    union { __half2 h; unsigned u; } ua, ub, ud;
    ua.h = a; ub.h = b;
    asm("v_pk_max_f16 %0, %1, %2" : "=v"(ud.u) : "v"(ua.u), "v"(ub.u));
    return ud.h;
}

__device__ __forceinline__ __half2 sfx2(__half2 x, int off){
    union { __half2 h; int i; } u; u.h = x;
    u.i = __shfl_xor(u.i, off);
    return u.h;
}

// src-degree histogram (multi-copy LDS, packed u16 counters) + fused coarse
// dst histogram (p==0 blocks). NOTE: scattered global atomics are ~50MB of
// write-through traffic on MI355X (round-1 regression) — LDS privatization
// with a 12.8MB coalesced spill buffer is strictly faster.
__global__ void k_hsrc(const int* __restrict__ ei, int E, int halfN,
                       unsigned* __restrict__ hb, unsigned* __restrict__ gPair){
    __shared__ unsigned h[HLDS];
    __shared__ unsigned hp[NB2MAX];
    int t = threadIdx.x;                 // 512
    int nWloc = halfN >> 1;
    for (int i = t; i < nWloc; i += 512) h[i] = 0;
    int p = blockIdx.x & 1;
    if (p == 0) hp[t] = 0;
    __syncthreads();
    int slice = blockIdx.x >> 1;
    int base  = p * halfN;
    int chunk = (E + NSL - 1) / NSL;
    int lo = slice*chunk, hi = lo + chunk; if (hi > E) hi = E;
    if (p == 0){
        for (int i = lo + t; i < hi; i += 512){
            int s = ei[i] - base;
            if ((unsigned)s < (unsigned)halfN)
                atomicAdd(&h[s >> 1], 1u << (16*(s & 1)));
            atomicAdd(&hp[unsigned(ei[E+i]) >> 7], 1u);   // coarse dst histogram (128-node buckets)
        }
    } else {
        for (int i = lo + t; i < hi; i += 512){
            int s = ei[i] - base;
            if ((unsigned)s < (unsigned)halfN)
                atomicAdd(&h[s >> 1], 1u << (16*(s & 1)));
        }
    }
    __syncthreads();
    unsigned* out = hb + (size_t)blockIdx.x * nWloc;
    for (int w = t; w < nWloc; w += 512) out[w] = h[w];
    if (p == 0 && hp[t]) atomicAdd(&gPair[t], hp[t]);
}

// reduce NSL slice copies into degS (HGRP partial groups via dense atomics,
// degS pre-zeroed) + fused per-graph bounds binary searches (spread over this
// wide grid instead of serialized in the 1-block k_setup).
__global__ void k_hred(const unsigned* __restrict__ hb, unsigned* __restrict__ degS,
                       int nWloc,
                       const int* __restrict__ batch, int* __restrict__ gb,
                       int N, int G){
    int idx = blockIdx.x*blockDim.x + threadIdx.x;
    if (idx <= G){                          // graph bounds (independent work)
        int lo = 0, hi = N;
        while (lo < hi){ int mid = (lo+hi)>>1; if (batch[mid] < idx) lo = mid+1; else hi = mid; }
        gb[idx] = lo;
    }
    int total = 2*nWloc;
    int grp = idx / total;
    if (grp >= HGRP) return;
    int rem = idx - grp*total;
    int p = (rem < nWloc) ? 0 : 1;
    int w = rem - p*nWloc;
    unsigned s = 0;
    int sl0 = grp*(NSL/HGRP), sl1 = sl0 + NSL/HGRP;
    for (int sl = sl0; sl < sl1; ++sl)
        s += hb[(size_t)(sl*2 + p)*nWloc + w];
    if (s) atomicAdd(&degS[rem], s);
}

// fused: add self-loop counts, 512-bucket scan, layer-1 weight pack
__global__ void k_setup(unsigned* __restrict__ gPair,
                        int* __restrict__ partBase, int* __restrict__ gcur,
                        int* __restrict__ rsN, int EP, int nb, int N,
                        const float* __restrict__ W1l, const float* __restrict__ b1l,
                        const float* __restrict__ W1r, const float* __restrict__ b1r,
                        const float* __restrict__ att1, const float* __restrict__ bias1,
                        float4* __restrict__ tabA, float4* __restrict__ tabB){
    __shared__ int sp[NB2MAX];
    int t = threadIdx.x;   // 512
    int vp = 0;
    if (t < nb){
        int selfc = N - t*128;
        selfc = (selfc < 0) ? 0 : (selfc > 128 ? 128 : selfc);
        vp = (int)gPair[t] + selfc;
        gPair[t] = (unsigned)vp;          // total pairs per bucket (incl self-loops)
    }
    sp[t] = vp;
    __syncthreads();
    for (int d = 1; d < NB2MAX; d <<= 1){
        int x = (t >= d) ? sp[t-d] : 0;
        __syncthreads();
        sp[t] += x;
        __syncthreads();
    }
    if (t < nb){ partBase[t] = sp[t] - vp; gcur[t] = sp[t] - vp; }
    if (t == 0) rsN[0] = EP;
    if (t < HC){
        tabA[t] = make_float4(W1l[t*3] + b1l[t], W1l[t*3+1], W1l[t*3+2], att1[t]);
        tabB[t] = make_float4(W1r[t*3] + b1r[t], W1r[t*3+1], W1r[t*3+2], bias1[t]);
    }
}

// P2: per-tile LDS counting sort into 512 coarse buckets (bucket = dst>>7 = e>>23).
// Full tiles cache their 32 pair-entries in registers (static indices only) so
// the edge list is read once per tile, not twice.
__global__ void k_p2(const int* __restrict__ ei, int E, int EP,
                     int* __restrict__ gcur, unsigned* __restrict__ part){
    __shared__ int bcnt[NB2MAX], bstart[NB2MAX], c2[NB2MAX], gpos[NB2MAX], sc[256];
    __shared__ unsigned sorted[TILE];
    __shared__ unsigned short bktof[TILE];
    int t = threadIdx.x;   // 256
    int base = blockIdx.x * TILE;
    int cnt = EP - base; if (cnt > TILE) cnt = TILE;
    bool full = (cnt == TILE);

    bcnt[t] = 0; bcnt[t+256] = 0; c2[t] = 0; c2[t+256] = 0;
    __syncthreads();
    unsigned ec[TILE/256];
    if (full){
        #pragma unroll
        for (int q = 0; q < TILE/256; ++q)
            ec[q] = gen_pair(ei, E, base + t + q*256);
        #pragma unroll
        for (int q = 0; q < TILE/256; ++q)
            atomicAdd(&bcnt[ec[q] >> 23], 1);
    } else {
        for (int j = t; j < cnt; j += 256){
            unsigned e = gen_pair(ei, E, base + j);
            atomicAdd(&bcnt[e >> 23], 1);
        }
    }
    __syncthreads();
    int v0 = bcnt[2*t], v1 = bcnt[2*t+1];
    int s = v0 + v1;
    sc[t] = s;
    __syncthreads();
    for (int d = 1; d < 256; d <<= 1){
        int x = (t >= d) ? sc[t-d] : 0;
        __syncthreads();
        sc[t] += x;
        __syncthreads();
    }
    int excl = sc[t] - s;
    bstart[2*t]   = excl;
    bstart[2*t+1] = excl + v0;
    #pragma unroll
    for (int q = 0; q < 2; ++q){
        int bb = 2*t + q;
        int v = (q == 0) ? v0 : v1;
        if (v > 0){
            gpos[bb] = atomicAdd(&gcur[bb], v);
            int bs = bstart[bb];
            for (int j = 0; j < v; ++j) bktof[bs + j] = (unsigned short)bb;
        }
    }
    __syncthreads();
    if (full){
        #pragma unroll
        for (int q = 0; q < TILE/256; ++q){
            unsigned e = ec[q];
            int b = e >> 23;
            int off = atomicAdd(&c2[b], 1);
            sorted[bstart[b] + off] = e;
        }
    } else {
        for (int j = t; j < cnt; j += 256){
            unsigned e = gen_pair(ei, E, base + j);
            int b = e >> 23;
            int off = atomicAdd(&c2[b], 1);
            sorted[bstart[b] + off] = e;
        }
    }
    __syncthreads();
    for (int k = t; k < cnt; k += 256){
        int b = bktof[k];
        part[gpos[b] + (k - bstart[b])] = sorted[k];
    }
}

// fine pass: one block per 128-node bucket -> rs, (deg,rnd), col (coalesced out)
__global__ void k_fine(const unsigned* __restrict__ part, const int* __restrict__ partBase,
                       const unsigned* __restrict__ gPair,
                       const unsigned* __restrict__ degS, const float* __restrict__ rnd,
                       int* __restrict__ rs, float2* __restrict__ dr,
                       int* __restrict__ col, int N){
    __shared__ int pcnt[128], c2[128], lrs[129], sc[128];
    __shared__ int colbuf[CBMAX];
    int b = blockIdx.x, t = threadIdx.x;   // 256
    int beg = partBase[b], end = beg + (int)gPair[b];
    if (t < 128){ pcnt[t] = 0; c2[t] = 0; }
    __syncthreads();
    for (int k = beg + t; k < end; k += 256)
        atomicAdd(&pcnt[(part[k] >> 16) & 127], 1);
    __syncthreads();
    int v = (t < 128) ? pcnt[t] : 0;
    if (t < 128) sc[t] = v;
    __syncthreads();
    for (int d = 1; d < 128; d <<= 1){
        int x = (t >= d && t < 128) ? sc[t-d] : 0;
        __syncthreads();
        if (t < 128) sc[t] += x;
        __syncthreads();
    }
    if (t < 128){
        lrs[t] = sc[t] - v;
        if (t == 127) lrs[128] = sc[127];
    }
    __syncthreads();
    int n = (b << 7) + t;
    if (t < 128 && n < N){
        rs[n] = partBase[b] + lrs[t];
        unsigned s16 = (degS[n >> 1] >> (16*(n & 1))) & 0xFFFFu;
        dr[n] = make_float2((float)(pcnt[t] - 1 + (int)s16), rnd[n]);
    }
    for (int k = beg + t; k < end; k += 256){
        unsigned e = part[k];
        int j = (e >> 16) & 127;
        int pos = lrs[j] + atomicAdd(&c2[j], 1);
        if (pos < CBMAX) colbuf[pos] = (int)(e & 0xFFFFu);
    }
    __syncthreads();
    int npair = lrs[128];
    int cb = partBase[b];
    for (int k = t; k < npair; k += 256) col[cb + k] = colbuf[k];
}

// fused layer-1 GATv2 + layer-2 input projection:
// HEAD-PAIRED 16-lane subgroup per dst (8 lanes per head). Two-way edge loop
// (proven round-2 structure: VGPR ~32-class, occupancy first). The subgroup
// owns the full 32-channel ELU'd layer-1 row in registers, so the 32x32 xl/xr
// GEMM is done in-place via 16-step subgroup broadcast + LDS-staged transposed
// weights -> A16/B16 (both fp16), never materializing X.
__global__ void k_gat1(const int* __restrict__ rs, const int* __restrict__ col,
                       const float2* __restrict__ dr,
                       const float4* __restrict__ tabA, const float4* __restrict__ tabB,
                       const float* __restrict__ W2l, const float* __restrict__ b2l,
                       const float* __restrict__ W2r, const float* __restrict__ b2r,
                       __half* __restrict__ A16, __half* __restrict__ B16, int N){
    __shared__ float wl[HC][HC+1], wr[HC][HC+1];   // [j][k] transposed, +1 pad
    __shared__ float blS[HC], brS[HC];
    int t = threadIdx.x;                 // 256
    for (int w = t; w < HC*HC; w += 256){
        int k = w >> 5, j = w & 31;
        wl[j][k] = W2l[w];
        wr[j][k] = W2r[w];
    }
    if (t < HC){ blS[t] = b2l[t]; brS[t] = b2r[t]; }
    __syncthreads();

    int d = blockIdx.x*(blockDim.x >> 4) + (t >> 4);
    if (d >= N) return;
    int lane = t & 15;
    int h = lane >> 3, r = lane & 7;

    float2 drd = dr[d];
    float base[CH], v[CH], w[CH], at[CH];
    #pragma unroll
    for (int c = 0; c < CH; ++c){
        float4 a4 = tabA[h*CH + c];
        float4 b4 = tabB[h*CH + c];
        float xr = b4.x + b4.y*drd.x + b4.z*drd.y;
        base[c] = a4.x + xr; v[c] = a4.y; w[c] = a4.z; at[c] = a4.w;
    }

    float l = 0.f, S1 = 0.f, S2 = 0.f;
    int beg = rs[d], end = rs[d+1];
    int p = beg + r;
    for (; p + 8 < end; p += 16){
        int s0 = col[p], s1 = col[p+8];
        float2 da = dr[s0];
        float2 db = dr[s1];
        float sc0 = 0.f, sc1 = 0.f;
        #pragma unroll
        for (int c = 0; c < CH; ++c){
            float m0 = base[c] + v[c]*da.x + w[c]*da.y;
            float m1 = base[c] + v[c]*db.x + w[c]*db.y;
            m0 = (m0 > 0.f) ? m0 : NSLOPE*m0;
            m1 = (m1 > 0.f) ? m1 : NSLOPE*m1;
            sc0 += m0 * at[c];
            sc1 += m1 * at[c];
        }
        float ex0 = __expf(sc0), ex1 = __expf(sc1);
        l  += ex0 + ex1;
        S1 += ex0*da.x + ex1*db.x;
        S2 += ex0*da.y + ex1*db.y;
    }
    if (p < end){
        float2 ds = dr[col[p]];
        float sc = 0.f;
        #pragma unroll
        for (int c = 0; c < CH; ++c){
            float mm = base[c] + v[c]*ds.x + w[c]*ds.y;
            mm = (mm > 0.f) ? mm : NSLOPE*mm;
            sc += mm * at[c];
        }
        float ex = __expf(sc);
        l  += ex;
        S1 += ex*ds.x;
        S2 += ex*ds.y;
    }

    #pragma unroll
    for (int off = 4; off >= 1; off >>= 1){
        l  += __shfl_xor(l,  off);
        S1 += __shfl_xor(S1, off);
        S2 += __shfl_xor(S2, off);
    }

    // layer-1 output channels 2*lane, 2*lane+1 (ELU'd), in-register
    float invl = 1.f/(l + 1e-16f);
    int c0 = r*2;
    float4 a40 = tabA[h*CH + c0],     b40 = tabB[h*CH + c0];
    float4 a41 = tabA[h*CH + c0 + 1], b41 = tabB[h*CH + c0 + 1];
    float v0 = a40.x + (a40.y*S1 + a40.z*S2)*invl + b40.w;
    float v1 = a41.x + (a41.y*S1 + a41.z*S2)*invl + b41.w;
    float x0 = (v0 > 0.f) ? v0 : expm1f(v0);
    float x1 = (v1 > 0.f) ? v1 : expm1f(v1);

    // in-subgroup 32x32 projection: out[k] = b[k] + sum_j x[j]*W[k][j]
    int k0 = 2*lane;
    float a0 = blS[k0], a1 = blS[k0+1];
    float g0 = brS[k0], g1 = brS[k0+1];
    #pragma unroll
    for (int tt = 0; tt < 16; ++tt){
        float xa = __shfl(x0, tt, 16);     // x[2*tt]
        float xb = __shfl(x1, tt, 16);     // x[2*tt+1]
        int j = 2*tt;
        a0 += xa*wl[j][k0]   + xb*wl[j+1][k0];
        a1 += xa*wl[j][k0+1] + xb*wl[j+1][k0+1];
        g0 += xa*wr[j][k0]   + xb*wr[j+1][k0];
        g1 += xa*wr[j][k0+1] + xb*wr[j+1][k0+1];
    }
    *(__half2*)(A16 + (size_t)d*HC + k0) = __floats2half2_rn(a0, a1);
    *(__half2*)(B16 + (size_t)d*HC + k0) = __floats2half2_rn(g0, g1);
}

// fused layer-2 GATv2 + mean-pool accumulation: head-paired 32-lane subgroup
// per dst; two-way edge loop (round-2 proven: minimal live state, max
// occupancy); packed fp16 math; channel-splitting halving merge; epilogue
// ELUs and atomicAdds into pooled[batch[d]][k] (L2-resident).
__global__ void k_gat(const int* __restrict__ rs, const int* __restrict__ col,
                      const __half* __restrict__ A16, const __half* __restrict__ B16,
                      const float* __restrict__ att, const float* __restrict__ bias,
                      const int* __restrict__ batch, float* __restrict__ pooled, int N){
    int d = blockIdx.x*(blockDim.x >> 5) + (threadIdx.x >> 5);
    int lane = threadIdx.x & 31;
    if (d >= N) return;
    int h = lane >> 4, r = lane & 15;

    union U { uint4 u[2]; __half2 h2[8]; };
    U xr;
    {
        const uint4* bp = (const uint4*)(B16 + (size_t)d*HC + h*CH);
        xr.u[0] = bp[0]; xr.u[1] = bp[1];
    }
    __half2 at2[8];
    const float* atf = att + h*CH;
    #pragma unroll
    for (int i = 0; i < 8; ++i) at2[i] = __floats2half2_rn(atf[2*i], atf[2*i+1]);
    const __half2 ns2 = __float2half2_rn(NSLOPE);

    float l = 0.f;
    __half2 acc2[8];
    #pragma unroll
    for (int i = 0; i < 8; ++i) acc2[i] = __float2half2_rn(0.f);

    int beg = rs[d], end = rs[d+1];
    int p = beg + r;
    for (; p + 16 < end; p += 32){
        int s0 = col[p], s1 = col[p+16];
        const uint4* rp0 = (const uint4*)(A16 + (size_t)s0*HC + h*CH);
        const uint4* rp1 = (const uint4*)(A16 + (size_t)s1*HC + h*CH);
        U a, b;
        a.u[0] = rp0[0]; a.u[1] = rp0[1];     // both gathers in flight before use
        b.u[0] = rp1[0]; b.u[1] = rp1[1];
        __half2 sc2 = __float2half2_rn(0.f);
        #pragma unroll
        for (int i = 0; i < 8; ++i){
            __half2 m  = __hadd2(a.h2[i], xr.h2[i]);
            __half2 lk = pkmax2(m, __hmul2(m, ns2));
            sc2 = __hfma2(lk, at2[i], sc2);
        }
        float ex = __expf(__low2float(sc2) + __high2float(sc2));
        l += ex;
        __half2 exh = __float2half2_rn(ex);
        #pragma unroll
        for (int i = 0; i < 8; ++i) acc2[i] = __hfma2(a.h2[i], exh, acc2[i]);

        sc2 = __float2half2_rn(0.f);
        #pragma unroll
        for (int i = 0; i < 8; ++i){
            __half2 m  = __hadd2(b.h2[i], xr.h2[i]);
            __half2 lk = pkmax2(m, __hmul2(m, ns2));
            sc2 = __hfma2(lk, at2[i], sc2);
        }
        ex = __expf(__low2float(sc2) + __high2float(sc2));
        l += ex;
        exh = __float2half2_rn(ex);
        #pragma unroll
        for (int i = 0; i < 8; ++i) acc2[i] = __hfma2(b.h2[i], exh, acc2[i]);
    }
    if (p < end){
        int s = col[p];
        const uint4* rp = (const uint4*)(A16 + (size_t)s*HC + h*CH);
        U a;
        a.u[0] = rp[0]; a.u[1] = rp[1];
        __half2 sc2 = __float2half2_rn(0.f);
        #pragma unroll
        for (int i = 0; i < 8; ++i){
            __half2 m  = __hadd2(a.h2[i], xr.h2[i]);
            __half2 lk = pkmax2(m, __hmul2(m, ns2));
            sc2 = __hfma2(lk, at2[i], sc2);
        }
        float ex = __expf(__low2float(sc2) + __high2float(sc2));
        l += ex;
        __half2 exh = __float2half2_rn(ex);
        #pragma unroll
        for (int i = 0; i < 8; ++i) acc2[i] = __hfma2(a.h2[i], exh, acc2[i]);
    }

    // channel-splitting halving merge across the 16-lane half.
    __half2 v4[4];
    {
        bool hi = (r & 8) != 0;
        #pragma unroll
        for (int i = 0; i < 4; ++i){
            __half2 send = hi ? acc2[i] : acc2[i+4];
            __half2 recv = sfx2(send, 8);
            v4[i] = __hadd2(hi ? acc2[i+4] : acc2[i], recv);
        }
    }
    __half2 v2[2];
    {
        bool hi = (r & 4) != 0;
        __half2 s0 = hi ? v4[0] : v4[2];
        __half2 s1 = hi ? v4[1] : v4[3];
        __half2 r0 = sfx2(s0, 4);
        __half2 r1 = sfx2(s1, 4);
        v2[0] = __hadd2(hi ? v4[2] : v4[0], r0);
        v2[1] = __hadd2(hi ? v4[3] : v4[1], r1);
    }
    __half2 v1;
    {
        bool hi = (r & 2) != 0;
        __half2 send = hi ? v2[0] : v2[1];
        __half2 recv = sfx2(send, 2);
        v1 = __hadd2(hi ? v2[1] : v2[0], recv);
    }
    float mine;
    {
        bool hi = (r & 1) != 0;
        float lo = __low2float(v1), hf = __high2float(v1);
        float send = hi ? lo : hf;
        float recv = __shfl_xor(send, 1);
        mine = (hi ? hf : lo) + recv;   // lane r owns channel r total
    }
    #pragma unroll
    for (int off = 8; off >= 1; off >>= 1) l += __shfl_xor(l, off);

    float invl = 1.f/(l + 1e-16f);
    float val = mine*invl + bias[h*CH + r];
    val = (val > 0.f) ? val : expm1f(val);
    atomicAdd(&pooled[(size_t)batch[d]*HC + h*CH + r], val);
}

// tiny classifier: mean over graph (counts from gb) + fc + log_softmax
__global__ void k_fc(const float* __restrict__ pooled, const int* __restrict__ gb,
                     const float* __restrict__ Wfc, const float* __restrict__ bfc,
                     float* __restrict__ out, int G){
    int t = threadIdx.x;            // 64 -> two graphs per wave
    int g = blockIdx.x*2 + (t >> 5);
    int c = t & 31;
    if (g >= G) return;
    float cnt = (float)(gb[g+1] - gb[g]);
    if (cnt < 1.f) cnt = 1.f;
    float pv = pooled[g*HC + c] / cnt;
    float p0 = pv * Wfc[c];
    float p1 = pv * Wfc[HC + c];
    #pragma unroll
    for (int off = 16; off >= 1; off >>= 1){
        p0 += __shfl_xor(p0, off, 32);
        p1 += __shfl_xor(p1, off, 32);
    }
    if (c == 0){
        float l0 = p0 + bfc[0], l1 = p1 + bfc[1];
        float m = (l0 > l1) ? l0 : l1;
        float lse = m + logf(__expf(l0 - m) + __expf(l1 - m));
        out[g*2 + 0] = l0 - lse;
        out[g*2 + 1] = l1 - lse;
    }
}

extern "C" void kernel_launch(void* const* d_in, const int* in_sizes, int n_in,
                              void* d_out, int out_size, void* d_ws, size_t ws_size,
                              hipStream_t stream) {
    const int*   ei    = (const int*)  d_in[0];
    const int*   batch = (const int*)  d_in[1];
    const float* rnd   = (const float*)d_in[2];
    const float* W1l   = (const float*)d_in[3];
    const float* b1l   = (const float*)d_in[4];
    const float* W1r   = (const float*)d_in[5];
    const float* b1r   = (const float*)d_in[6];
    const float* att1  = (const float*)d_in[7];
    const float* bias1 = (const float*)d_in[8];
    const float* W2l   = (const float*)d_in[9];
    const float* b2l   = (const float*)d_in[10];
    const float* W2r   = (const float*)d_in[11];
    const float* b2r   = (const float*)d_in[12];
    const float* att2  = (const float*)d_in[13];
    const float* bias2 = (const float*)d_in[14];
    const float* Wfc   = (const float*)d_in[15];
    const float* bfc   = (const float*)d_in[16];

    const int E  = in_sizes[0] / 2;
    const int N  = in_sizes[1];
    const int G  = out_size / 2;
    const int EP = E + N;                    // pairs (edges + self-loops)
    const int NB2 = (N + 127) >> 7;          // 128-node coarse buckets
    const int halfN = (((N + 1) >> 1) + 1) & ~1;   // even half-range
    const int nWloc = halfN >> 1;            // packed u16 words per half

    // workspace layout. Liveness-based aliasing:
    //   hb (12.8MB, k_hsrc->k_hred) aliases [0 .. 12.8MB): A16,B16 and the low
    //     part of col are all written strictly AFTER hb dies.
    //   part (6.6MB, k_p2->k_fine) aliases [0 .. 6.6MB): A16/B16 written after.
    //   dr/rs/col sit above the hb region; degS+ctrl above those.
    float* ws        = (float*)d_ws;
    __half* A16      = (__half*)ws;             // N*HC halfs
    __half* B16      = A16 + (size_t)N*HC;      // N*HC halfs
    unsigned* hb     = (unsigned*)ws;           // NSL*2 * nWloc words
    unsigned* part   = (unsigned*)ws;           // EP u32
    size_t off       = (size_t)NSL*2*nWloc;     // words consumed by hb
    if (off < (size_t)EP)   off = EP;           // ... and part
    if (off < (size_t)N*HC) off = (size_t)N*HC; // ... and A16+B16 (N*HC words total)
    off = (off + 1) & ~(size_t)1;
    float2* dr       = (float2*)(ws + off);     // N float2 (deg, rnd)
    int*   rs        = (int*)(dr + N);          // N+1
    int*   col       = rs + N + 1;              // EP
    unsigned* degS   = (unsigned*)(col + EP);   // 2*nWloc words (packed u16)
    unsigned* gPair  = degS + 2*nWloc;          // NB2MAX
    float* pooled    = (float*)(gPair + NB2MAX);// G*HC
    int*   partBase  = (int*)(pooled + (size_t)G*HC);  // NB2MAX
    int*   gcur      = partBase + NB2MAX;       // NB2MAX
    int*   gb        = gcur + NB2MAX;           // G+1
    float4* tabA     = (float4*)((((size_t)(gb + G + 1)) + 15) & ~(size_t)15);
    float4* tabB     = tabA + HC;

    const int T = 256;
    const int gD16 = (N + (T>>4) - 1)/(T>>4);   // 16-lane-per-dst subgroups (layer 1)
    const int gD32 = (N + (T>>5) - 1)/(T>>5);   // 32-lane-per-dst subgroups (layer 2)
    const int nTiles = (EP + TILE - 1)/TILE;

    // degS + gPair + pooled adjacent: one memset zeroes all three
    (void)hipMemsetAsync(degS, 0, (size_t)(2*nWloc + NB2MAX + (size_t)G*HC)*sizeof(unsigned), stream);

    // ---- degree + CSR build (LDS-privatized histograms; NO global scatter atomics) ----
    k_hsrc <<<NSL*2, 512, 0, stream>>>(ei, E, halfN, hb, gPair);
    k_hred <<<(2*nWloc*HGRP + T-1)/T, T, 0, stream>>>(hb, degS, nWloc, batch, gb, N, G);
    k_setup<<<1, 512, 0, stream>>>(gPair, partBase, gcur, rs + N, EP, NB2, N,
                                   W1l, b1l, W1r, b1r, att1, bias1, tabA, tabB);
    k_p2   <<<nTiles, T, 0, stream>>>(ei, E, EP, gcur, part);
    k_fine <<<NB2, T, 0, stream>>>(part, partBase, gPair, degS, rnd, rs, dr, col, N);

    // ---- layer 1 fused with layer-2 projection (A16/B16; X never materialized) ----
    k_gat1<<<gD16, T, 0, stream>>>(rs, col, dr, tabA, tabB,
                                   W2l, b2l, W2r, b2r, A16, B16, N);

    // ---- layer 2 fused with mean-pool accumulation ----
    k_gat <<<gD32, T, 0, stream>>>(rs, col, A16, B16, att2, bias2, batch, pooled, N);

    // ---- tiny classifier ----
    k_fc  <<<(G + 1)/2, 64, 0, stream>>>(pooled, gb, Wfc, bfc, (float*)d_out, G);
}

// Round 5
// 233.282 us; speedup vs baseline: 1.1219x; 1.0405x over previous
//
#include <hip/hip_runtime.h>
#include <hip/hip_fp16.h>
#include <math.h>

#define HC 32      // H*C
#define CH 16      // channels per head
#define NSLOPE 0.2f
#define NB2MAX 512 // max coarse buckets (128 nodes each; N <= 65536)
#define TILE 8192
#define CBMAX 6144 // colbuf per 128-node bucket (avg ~4.2K pairs)
#define NSL 128    // edge slices for src histogram -> exactly 256 blocks (1/CU)
#define HGRP 8     // slice groups for k_hred (NSL % HGRP == 0)
#define HLDS 12544 // LDS words per half-range histogram (supports halfN <= 25088)

// pair entry: (dst<<16) | src ; self pairs appended
__device__ __forceinline__ unsigned gen_pair(const int* __restrict__ ei, int E, int i){
    if (i < E) return (unsigned(ei[E+i]) << 16) | unsigned(ei[i]);
    unsigned n = i - E; return (n << 16) | n;
}

// packed fp16 max (ROCm 7.2 header lacks __hmax2)
__device__ __forceinline__ __half2 pkmax2(__half2 a, __half2 b){
    union { __half2 h; unsigned u; } ua, ub, ud;
    ua.h = a; ub.h = b;
    asm("v_pk_max_f16 %0, %1, %2" : "=v"(ud.u) : "v"(ua.u), "v"(ub.u));
    return ud.h;
}

__device__ __forceinline__ __half2 sfx2(__half2 x, int off){
    union { __half2 h; int i; } u; u.h = x;
    u.i = __shfl_xor(u.i, off);
    return u.h;
}

// src-degree histogram (multi-copy LDS, packed u16 counters) + fused coarse
// dst histogram (p==0 blocks). NOTE: scattered global atomics are ~50MB of
// write-through traffic on MI355X (round-1 regression) — LDS privatization
// with a 12.8MB coalesced spill buffer is strictly faster.
__global__ void k_hsrc(const int* __restrict__ ei, int E, int halfN,
                       unsigned* __restrict__ hb, unsigned* __restrict__ gPair){
    __shared__ unsigned h[HLDS];
    __shared__ unsigned hp[NB2MAX];
    int t = threadIdx.x;                 // 512
    int nWloc = halfN >> 1;
    for (int i = t; i < nWloc; i += 512) h[i] = 0;
    int p = blockIdx.x & 1;
    if (p == 0) hp[t] = 0;
    __syncthreads();
    int slice = blockIdx.x >> 1;
    int base  = p * halfN;
    int chunk = (E + NSL - 1) / NSL;
    int lo = slice*chunk, hi = lo + chunk; if (hi > E) hi = E;
    if (p == 0){
        for (int i = lo + t; i < hi; i += 512){
            int s = ei[i] - base;
            if ((unsigned)s < (unsigned)halfN)
                atomicAdd(&h[s >> 1], 1u << (16*(s & 1)));
            atomicAdd(&hp[unsigned(ei[E+i]) >> 7], 1u);   // coarse dst histogram (128-node buckets)
        }
    } else {
        for (int i = lo + t; i < hi; i += 512){
            int s = ei[i] - base;
            if ((unsigned)s < (unsigned)halfN)
                atomicAdd(&h[s >> 1], 1u << (16*(s & 1)));
        }
    }
    __syncthreads();
    unsigned* out = hb + (size_t)blockIdx.x * nWloc;
    for (int w = t; w < nWloc; w += 512) out[w] = h[w];
    if (p == 0 && hp[t]) atomicAdd(&gPair[t], hp[t]);
}

// reduce NSL slice copies into degS (HGRP partial groups via dense atomics,
// degS pre-zeroed) + fused per-graph bounds binary searches (spread over this
// wide grid instead of serialized in the 1-block k_setup).
__global__ void k_hred(const unsigned* __restrict__ hb, unsigned* __restrict__ degS,
                       int nWloc,
                       const int* __restrict__ batch, int* __restrict__ gb,
                       int N, int G){
    int idx = blockIdx.x*blockDim.x + threadIdx.x;
    if (idx <= G){                          // graph bounds (independent work)
        int lo = 0, hi = N;
        while (lo < hi){ int mid = (lo+hi)>>1; if (batch[mid] < idx) lo = mid+1; else hi = mid; }
        gb[idx] = lo;
    }
    int total = 2*nWloc;
    int grp = idx / total;
    if (grp >= HGRP) return;
    int rem = idx - grp*total;
    int p = (rem < nWloc) ? 0 : 1;
    int w = rem - p*nWloc;
    unsigned s = 0;
    int sl0 = grp*(NSL/HGRP), sl1 = sl0 + NSL/HGRP;
    for (int sl = sl0; sl < sl1; ++sl)
        s += hb[(size_t)(sl*2 + p)*nWloc + w];
    if (s) atomicAdd(&degS[rem], s);
}

// fused: add self-loop counts, 512-bucket scan, layer-1 weight pack
__global__ void k_setup(unsigned* __restrict__ gPair,
                        int* __restrict__ partBase, int* __restrict__ gcur,
                        int* __restrict__ rsN, int EP, int nb, int N,
                        const float* __restrict__ W1l, const float* __restrict__ b1l,
                        const float* __restrict__ W1r, const float* __restrict__ b1r,
                        const float* __restrict__ att1, const float* __restrict__ bias1,
                        float4* __restrict__ tabA, float4* __restrict__ tabB){
    __shared__ int sp[NB2MAX];
    int t = threadIdx.x;   // 512
    int vp = 0;
    if (t < nb){
        int selfc = N - t*128;
        selfc = (selfc < 0) ? 0 : (selfc > 128 ? 128 : selfc);
        vp = (int)gPair[t] + selfc;
        gPair[t] = (unsigned)vp;          // total pairs per bucket (incl self-loops)
    }
    sp[t] = vp;
    __syncthreads();
    for (int d = 1; d < NB2MAX; d <<= 1){
        int x = (t >= d) ? sp[t-d] : 0;
        __syncthreads();
        sp[t] += x;
        __syncthreads();
    }
    if (t < nb){ partBase[t] = sp[t] - vp; gcur[t] = sp[t] - vp; }
    if (t == 0) rsN[0] = EP;
    if (t < HC){
        tabA[t] = make_float4(W1l[t*3] + b1l[t], W1l[t*3+1], W1l[t*3+2], att1[t]);
        tabB[t] = make_float4(W1r[t*3] + b1r[t], W1r[t*3+1], W1r[t*3+2], bias1[t]);
    }
}

// P2: per-tile LDS counting sort into 512 coarse buckets (bucket = dst>>7 = e>>23).
// Full tiles cache their 32 pair-entries in registers (static indices only) so
// the edge list is read once per tile, not twice.
__global__ void k_p2(const int* __restrict__ ei, int E, int EP,
                     int* __restrict__ gcur, unsigned* __restrict__ part){
    __shared__ int bcnt[NB2MAX], bstart[NB2MAX], c2[NB2MAX], gpos[NB2MAX], sc[256];
    __shared__ unsigned sorted[TILE];
    __shared__ unsigned short bktof[TILE];
    int t = threadIdx.x;   // 256
    int base = blockIdx.x * TILE;
    int cnt = EP - base; if (cnt > TILE) cnt = TILE;
    bool full = (cnt == TILE);

    bcnt[t] = 0; bcnt[t+256] = 0; c2[t] = 0; c2[t+256] = 0;
    __syncthreads();
    unsigned ec[TILE/256];
    if (full){
        #pragma unroll
        for (int q = 0; q < TILE/256; ++q)
            ec[q] = gen_pair(ei, E, base + t + q*256);
        #pragma unroll
        for (int q = 0; q < TILE/256; ++q)
            atomicAdd(&bcnt[ec[q] >> 23], 1);
    } else {
        for (int j = t; j < cnt; j += 256){
            unsigned e = gen_pair(ei, E, base + j);
            atomicAdd(&bcnt[e >> 23], 1);
        }
    }
    __syncthreads();
    int v0 = bcnt[2*t], v1 = bcnt[2*t+1];
    int s = v0 + v1;
    sc[t] = s;
    __syncthreads();
    for (int d = 1; d < 256; d <<= 1){
        int x = (t >= d) ? sc[t-d] : 0;
        __syncthreads();
        sc[t] += x;
        __syncthreads();
    }
    int excl = sc[t] - s;
    bstart[2*t]   = excl;
    bstart[2*t+1] = excl + v0;
    #pragma unroll
    for (int q = 0; q < 2; ++q){
        int bb = 2*t + q;
        int v = (q == 0) ? v0 : v1;
        if (v > 0){
            gpos[bb] = atomicAdd(&gcur[bb], v);
            int bs = bstart[bb];
            for (int j = 0; j < v; ++j) bktof[bs + j] = (unsigned short)bb;
        }
    }
    __syncthreads();
    if (full){
        #pragma unroll
        for (int q = 0; q < TILE/256; ++q){
            unsigned e = ec[q];
            int b = e >> 23;
            int off = atomicAdd(&c2[b], 1);
            sorted[bstart[b] + off] = e;
        }
    } else {
        for (int j = t; j < cnt; j += 256){
            unsigned e = gen_pair(ei, E, base + j);
            int b = e >> 23;
            int off = atomicAdd(&c2[b], 1);
            sorted[bstart[b] + off] = e;
        }
    }
    __syncthreads();
    for (int k = t; k < cnt; k += 256){
        int b = bktof[k];
        part[gpos[b] + (k - bstart[b])] = sorted[k];
    }
}

// fine pass: one block per 128-node bucket -> rs, (deg,rnd), col (coalesced out)
__global__ void k_fine(const unsigned* __restrict__ part, const int* __restrict__ partBase,
                       const unsigned* __restrict__ gPair,
                       const unsigned* __restrict__ degS, const float* __restrict__ rnd,
                       int* __restrict__ rs, float2* __restrict__ dr,
                       int* __restrict__ col, int N){
    __shared__ int pcnt[128], c2[128], lrs[129], sc[128];
    __shared__ int colbuf[CBMAX];
    int b = blockIdx.x, t = threadIdx.x;   // 256
    int beg = partBase[b], end = beg + (int)gPair[b];
    if (t < 128){ pcnt[t] = 0; c2[t] = 0; }
    __syncthreads();
    for (int k = beg + t; k < end; k += 256)
        atomicAdd(&pcnt[(part[k] >> 16) & 127], 1);
    __syncthreads();
    int v = (t < 128) ? pcnt[t] : 0;
    if (t < 128) sc[t] = v;
    __syncthreads();
    for (int d = 1; d < 128; d <<= 1){
        int x = (t >= d && t < 128) ? sc[t-d] : 0;
        __syncthreads();
        if (t < 128) sc[t] += x;
        __syncthreads();
    }
    if (t < 128){
        lrs[t] = sc[t] - v;
        if (t == 127) lrs[128] = sc[127];
    }
    __syncthreads();
    int n = (b << 7) + t;
    if (t < 128 && n < N){
        rs[n] = partBase[b] + lrs[t];
        unsigned s16 = (degS[n >> 1] >> (16*(n & 1))) & 0xFFFFu;
        dr[n] = make_float2((float)(pcnt[t] - 1 + (int)s16), rnd[n]);
    }
    for (int k = beg + t; k < end; k += 256){
        unsigned e = part[k];
        int j = (e >> 16) & 127;
        int pos = lrs[j] + atomicAdd(&c2[j], 1);
        if (pos < CBMAX) colbuf[pos] = (int)(e & 0xFFFFu);
    }
    __syncthreads();
    int npair = lrs[128];
    int cb = partBase[b];
    for (int k = t; k < npair; k += 256) col[cb + k] = colbuf[k];
}

// fused layer-1 GATv2 + layer-2 input projection:
// HEAD-PAIRED 16-lane subgroup per dst (8 lanes per head). Two-way edge loop
// (proven round-2 structure: minimal live state, occupancy first). col is
// streamed exactly once -> nontemporal loads keep the reused dr lines in L2.
__global__ void k_gat1(const int* __restrict__ rs, const int* __restrict__ col,
                       const float2* __restrict__ dr,
                       const float4* __restrict__ tabA, const float4* __restrict__ tabB,
                       const float* __restrict__ W2l, const float* __restrict__ b2l,
                       const float* __restrict__ W2r, const float* __restrict__ b2r,
                       __half* __restrict__ A16, __half* __restrict__ B16, int N){
    __shared__ float wl[HC][HC+1], wr[HC][HC+1];   // [j][k] transposed, +1 pad
    __shared__ float blS[HC], brS[HC];
    int t = threadIdx.x;                 // 256
    for (int w = t; w < HC*HC; w += 256){
        int k = w >> 5, j = w & 31;
        wl[j][k] = W2l[w];
        wr[j][k] = W2r[w];
    }
    if (t < HC){ blS[t] = b2l[t]; brS[t] = b2r[t]; }
    __syncthreads();

    int d = blockIdx.x*(blockDim.x >> 4) + (t >> 4);
    if (d >= N) return;
    int lane = t & 15;
    int h = lane >> 3, r = lane & 7;

    float2 drd = dr[d];
    float base[CH], v[CH], w[CH], at[CH];
    #pragma unroll
    for (int c = 0; c < CH; ++c){
        float4 a4 = tabA[h*CH + c];
        float4 b4 = tabB[h*CH + c];
        float xr = b4.x + b4.y*drd.x + b4.z*drd.y;
        base[c] = a4.x + xr; v[c] = a4.y; w[c] = a4.z; at[c] = a4.w;
    }

    float l = 0.f, S1 = 0.f, S2 = 0.f;
    int beg = rs[d], end = rs[d+1];
    int p = beg + r;
    for (; p + 8 < end; p += 16){
        int s0 = __builtin_nontemporal_load(col + p);
        int s1 = __builtin_nontemporal_load(col + p + 8);
        float2 da = dr[s0];
        float2 db = dr[s1];
        float sc0 = 0.f, sc1 = 0.f;
        #pragma unroll
        for (int c = 0; c < CH; ++c){
            float m0 = base[c] + v[c]*da.x + w[c]*da.y;
            float m1 = base[c] + v[c]*db.x + w[c]*db.y;
            m0 = (m0 > 0.f) ? m0 : NSLOPE*m0;
            m1 = (m1 > 0.f) ? m1 : NSLOPE*m1;
            sc0 += m0 * at[c];
            sc1 += m1 * at[c];
        }
        float ex0 = __expf(sc0), ex1 = __expf(sc1);
        l  += ex0 + ex1;
        S1 += ex0*da.x + ex1*db.x;
        S2 += ex0*da.y + ex1*db.y;
    }
    if (p < end){
        float2 ds = dr[__builtin_nontemporal_load(col + p)];
        float sc = 0.f;
        #pragma unroll
        for (int c = 0; c < CH; ++c){
            float mm = base[c] + v[c]*ds.x + w[c]*ds.y;
            mm = (mm > 0.f) ? mm : NSLOPE*mm;
            sc += mm * at[c];
        }
        float ex = __expf(sc);
        l  += ex;
        S1 += ex*ds.x;
        S2 += ex*ds.y;
    }

    #pragma unroll
    for (int off = 4; off >= 1; off >>= 1){
        l  += __shfl_xor(l,  off);
        S1 += __shfl_xor(S1, off);
        S2 += __shfl_xor(S2, off);
    }

    // layer-1 output channels 2*lane, 2*lane+1 (ELU'd), in-register
    float invl = 1.f/(l + 1e-16f);
    int c0 = r*2;
    float4 a40 = tabA[h*CH + c0],     b40 = tabB[h*CH + c0];
    float4 a41 = tabA[h*CH + c0 + 1], b41 = tabB[h*CH + c0 + 1];
    float v0 = a40.x + (a40.y*S1 + a40.z*S2)*invl + b40.w;
    float v1 = a41.x + (a41.y*S1 + a41.z*S2)*invl + b41.w;
    float x0 = (v0 > 0.f) ? v0 : expm1f(v0);
    float x1 = (v1 > 0.f) ? v1 : expm1f(v1);

    // in-subgroup 32x32 projection: out[k] = b[k] + sum_j x[j]*W[k][j]
    int k0 = 2*lane;
    float a0 = blS[k0], a1 = blS[k0+1];
    float g0 = brS[k0], g1 = brS[k0+1];
    #pragma unroll
    for (int tt = 0; tt < 16; ++tt){
        float xa = __shfl(x0, tt, 16);     // x[2*tt]
        float xb = __shfl(x1, tt, 16);     // x[2*tt+1]
        int j = 2*tt;
        a0 += xa*wl[j][k0]   + xb*wl[j+1][k0];
        a1 += xa*wl[j][k0+1] + xb*wl[j+1][k0+1];
        g0 += xa*wr[j][k0]   + xb*wr[j+1][k0];
        g1 += xa*wr[j][k0+1] + xb*wr[j+1][k0+1];
    }
    *(__half2*)(A16 + (size_t)d*HC + k0) = __floats2half2_rn(a0, a1);
    *(__half2*)(B16 + (size_t)d*HC + k0) = __floats2half2_rn(g0, g1);
}

// fused layer-2 GATv2 + mean-pool accumulation: head-paired 32-lane subgroup
// per dst; two-way edge loop (proven); packed fp16 math; channel-splitting
// halving merge. Epilogue: per-block LDS dedup of pooled contributions
// (batch-sorted -> a block's 8 dsts span 1-2 graphs), then ONE global
// atomicAdd per (block, graph, channel): ~8x fewer device-scope atomics.
__global__ void k_gat(const int* __restrict__ rs, const int* __restrict__ col,
                      const __half* __restrict__ A16, const __half* __restrict__ B16,
                      const float* __restrict__ att, const float* __restrict__ bias,
                      const int* __restrict__ batch, float* __restrict__ pooled, int N){
    __shared__ float pool[8][HC];
    __shared__ int sb[8];
    int sg = threadIdx.x >> 5;
    int d = blockIdx.x*(blockDim.x >> 5) + sg;
    int lane = threadIdx.x & 31;
    bool valid = (d < N);
    int dcl = valid ? d : 0;
    int h = lane >> 4, r = lane & 15;

    union U { uint4 u[2]; __half2 h2[8]; };
    U xr;
    {
        const uint4* bp = (const uint4*)(B16 + (size_t)dcl*HC + h*CH);
        xr.u[0] = bp[0]; xr.u[1] = bp[1];
    }
    __half2 at2[8];
    const float* atf = att + h*CH;
    #pragma unroll
    for (int i = 0; i < 8; ++i) at2[i] = __floats2half2_rn(atf[2*i], atf[2*i+1]);
    const __half2 ns2 = __float2half2_rn(NSLOPE);

    float l = 0.f;
    __half2 acc2[8];
    #pragma unroll
    for (int i = 0; i < 8; ++i) acc2[i] = __float2half2_rn(0.f);

    int beg = rs[dcl], end = valid ? rs[dcl+1] : beg;
    int p = beg + r;
    for (; p + 16 < end; p += 32){
        int s0 = __builtin_nontemporal_load(col + p);
        int s1 = __builtin_nontemporal_load(col + p + 16);
        const uint4* rp0 = (const uint4*)(A16 + (size_t)s0*HC + h*CH);
        const uint4* rp1 = (const uint4*)(A16 + (size_t)s1*HC + h*CH);
        U a, b;
        a.u[0] = rp0[0]; a.u[1] = rp0[1];     // both gathers in flight before use
        b.u[0] = rp1[0]; b.u[1] = rp1[1];
        __half2 sc2 = __float2half2_rn(0.f);
        #pragma unroll
        for (int i = 0; i < 8; ++i){
            __half2 m  = __hadd2(a.h2[i], xr.h2[i]);
            __half2 lk = pkmax2(m, __hmul2(m, ns2));
            sc2 = __hfma2(lk, at2[i], sc2);
        }
        float ex = __expf(__low2float(sc2) + __high2float(sc2));
        l += ex;
        __half2 exh = __float2half2_rn(ex);
        #pragma unroll
        for (int i = 0; i < 8; ++i) acc2[i] = __hfma2(a.h2[i], exh, acc2[i]);

        sc2 = __float2half2_rn(0.f);
        #pragma unroll
        for (int i = 0; i < 8; ++i){
            __half2 m  = __hadd2(b.h2[i], xr.h2[i]);
            __half2 lk = pkmax2(m, __hmul2(m, ns2));
            sc2 = __hfma2(lk, at2[i], sc2);
        }
        ex = __expf(__low2float(sc2) + __high2float(sc2));
        l += ex;
        exh = __float2half2_rn(ex);
        #pragma unroll
        for (int i = 0; i < 8; ++i) acc2[i] = __hfma2(b.h2[i], exh, acc2[i]);
    }
    if (p < end){
        int s = __builtin_nontemporal_load(col + p);
        const uint4* rp = (const uint4*)(A16 + (size_t)s*HC + h*CH);
        U a;
        a.u[0] = rp[0]; a.u[1] = rp[1];
        __half2 sc2 = __float2half2_rn(0.f);
        #pragma unroll
        for (int i = 0; i < 8; ++i){
            __half2 m  = __hadd2(a.h2[i], xr.h2[i]);
            __half2 lk = pkmax2(m, __hmul2(m, ns2));
            sc2 = __hfma2(lk, at2[i], sc2);
        }
        float ex = __expf(__low2float(sc2) + __high2float(sc2));
        l += ex;
        __half2 exh = __float2half2_rn(ex);
        #pragma unroll
        for (int i = 0; i < 8; ++i) acc2[i] = __hfma2(a.h2[i], exh, acc2[i]);
    }

    // channel-splitting halving merge across the 16-lane half.
    __half2 v4[4];
    {
        bool hi = (r & 8) != 0;
        #pragma unroll
        for (int i = 0; i < 4; ++i){
            __half2 send = hi ? acc2[i] : acc2[i+4];
            __half2 recv = sfx2(send, 8);
            v4[i] = __hadd2(hi ? acc2[i+4] : acc2[i], recv);
        }
    }
    __half2 v2[2];
    {
        bool hi = (r & 4) != 0;
        __half2 s0 = hi ? v4[0] : v4[2];
        __half2 s1 = hi ? v4[1] : v4[3];
        __half2 r0 = sfx2(s0, 4);
        __half2 r1 = sfx2(s1, 4);
        v2[0] = __hadd2(hi ? v4[2] : v4[0], r0);
        v2[1] = __hadd2(hi ? v4[3] : v4[1], r1);
    }
    __half2 v1;
    {
        bool hi = (r & 2) != 0;
        __half2 send = hi ? v2[0] : v2[1];
        __half2 recv = sfx2(send, 2);
        v1 = __hadd2(hi ? v2[1] : v2[0], recv);
    }
    float mine;
    {
        bool hi = (r & 1) != 0;
        float lo = __low2float(v1), hf = __high2float(v1);
        float send = hi ? lo : hf;
        float recv = __shfl_xor(send, 1);
        mine = (hi ? hf : lo) + recv;   // lane r owns channel r total
    }
    #pragma unroll
    for (int off = 8; off >= 1; off >>= 1) l += __shfl_xor(l, off);

    float invl = 1.f/(l + 1e-16f);
    float val = mine*invl + bias[h*CH + r];
    val = (val > 0.f) ? val : expm1f(val);

    // ---- block-level dedup, then one device atomic per (graph,channel) ----
    if (lane == 0) sb[sg] = valid ? batch[d] : (-1 - sg);   // unique sentinel
    pool[sg][h*CH + r] = val;                               // own row, plain store
    __syncthreads();
    int myb = sb[sg];
    int first = sg;
    #pragma unroll
    for (int j = 7; j >= 0; --j) if (sb[j] == myb) first = j;
    if (valid && first == sg){
        float s = 0.f;
        #pragma unroll
        for (int j = 0; j < 8; ++j) if (sb[j] == myb) s += pool[j][h*CH + r];
        atomicAdd(&pooled[(size_t)myb*HC + h*CH + r], s);
    }
}

// tiny classifier: mean over graph (counts from gb) + fc + log_softmax
__global__ void k_fc(const float* __restrict__ pooled, const int* __restrict__ gb,
                     const float* __restrict__ Wfc, const float* __restrict__ bfc,
                     float* __restrict__ out, int G){
    int t = threadIdx.x;            // 64 -> two graphs per wave
    int g = blockIdx.x*2 + (t >> 5);
    int c = t & 31;
    if (g >= G) return;
    float cnt = (float)(gb[g+1] - gb[g]);
    if (cnt < 1.f) cnt = 1.f;
    float pv = pooled[g*HC + c] / cnt;
    float p0 = pv * Wfc[c];
    float p1 = pv * Wfc[HC + c];
    #pragma unroll
    for (int off = 16; off >= 1; off >>= 1){
        p0 += __shfl_xor(p0, off, 32);
        p1 += __shfl_xor(p1, off, 32);
    }
    if (c == 0){
        float l0 = p0 + bfc[0], l1 = p1 + bfc[1];
        float m = (l0 > l1) ? l0 : l1;
        float lse = m + logf(__expf(l0 - m) + __expf(l1 - m));
        out[g*2 + 0] = l0 - lse;
        out[g*2 + 1] = l1 - lse;
    }
}

extern "C" void kernel_launch(void* const* d_in, const int* in_sizes, int n_in,
                              void* d_out, int out_size, void* d_ws, size_t ws_size,
                              hipStream_t stream) {
    const int*   ei    = (const int*)  d_in[0];
    const int*   batch = (const int*)  d_in[1];
    const float* rnd   = (const float*)d_in[2];
    const float* W1l   = (const float*)d_in[3];
    const float* b1l   = (const float*)d_in[4];
    const float* W1r   = (const float*)d_in[5];
    const float* b1r   = (const float*)d_in[6];
    const float* att1  = (const float*)d_in[7];
    const float* bias1 = (const float*)d_in[8];
    const float* W2l   = (const float*)d_in[9];
    const float* b2l   = (const float*)d_in[10];
    const float* W2r   = (const float*)d_in[11];
    const float* b2r   = (const float*)d_in[12];
    const float* att2  = (const float*)d_in[13];
    const float* bias2 = (const float*)d_in[14];
    const float* Wfc   = (const float*)d_in[15];
    const float* bfc   = (const float*)d_in[16];

    const int E  = in_sizes[0] / 2;
    const int N  = in_sizes[1];
    const int G  = out_size / 2;
    const int EP = E + N;                    // pairs (edges + self-loops)
    const int NB2 = (N + 127) >> 7;          // 128-node coarse buckets
    const int halfN = (((N + 1) >> 1) + 1) & ~1;   // even half-range
    const int nWloc = halfN >> 1;            // packed u16 words per half

    // workspace layout. Liveness-based aliasing:
    //   hb (12.8MB, k_hsrc->k_hred) aliases [0 .. 12.8MB): A16,B16 and the low
    //     part of col are all written strictly AFTER hb dies.
    //   part (6.6MB, k_p2->k_fine) aliases [0 .. 6.6MB): A16/B16 written after.
    //   dr/rs/col sit above the hb region; degS+ctrl above those.
    float* ws        = (float*)d_ws;
    __half* A16      = (__half*)ws;             // N*HC halfs
    __half* B16      = A16 + (size_t)N*HC;      // N*HC halfs
    unsigned* hb     = (unsigned*)ws;           // NSL*2 * nWloc words
    unsigned* part   = (unsigned*)ws;           // EP u32
    size_t off       = (size_t)NSL*2*nWloc;     // words consumed by hb
    if (off < (size_t)EP)   off = EP;           // ... and part
    if (off < (size_t)N*HC) off = (size_t)N*HC; // ... and A16+B16 (N*HC words total)
    off = (off + 1) & ~(size_t)1;
    float2* dr       = (float2*)(ws + off);     // N float2 (deg, rnd)
    int*   rs        = (int*)(dr + N);          // N+1
    int*   col       = rs + N + 1;              // EP
    unsigned* degS   = (unsigned*)(col + EP);   // 2*nWloc words (packed u16)
    unsigned* gPair  = degS + 2*nWloc;          // NB2MAX
    float* pooled    = (float*)(gPair + NB2MAX);// G*HC
    int*   partBase  = (int*)(pooled + (size_t)G*HC);  // NB2MAX
    int*   gcur      = partBase + NB2MAX;       // NB2MAX
    int*   gb        = gcur + NB2MAX;           // G+1
    float4* tabA     = (float4*)((((size_t)(gb + G + 1)) + 15) & ~(size_t)15);
    float4* tabB     = tabA + HC;

    const int T = 256;
    const int gD16 = (N + (T>>4) - 1)/(T>>4);   // 16-lane-per-dst subgroups (layer 1)
    const int gD32 = (N + (T>>5) - 1)/(T>>5);   // 32-lane-per-dst subgroups (layer 2)
    const int nTiles = (EP + TILE - 1)/TILE;

    // degS + gPair + pooled adjacent: one memset zeroes all three
    (void)hipMemsetAsync(degS, 0, (size_t)(2*nWloc + NB2MAX + (size_t)G*HC)*sizeof(unsigned), stream);

    // ---- degree + CSR build (LDS-privatized histograms; NO global scatter atomics) ----
    k_hsrc <<<NSL*2, 512, 0, stream>>>(ei, E, halfN, hb, gPair);
    k_hred <<<(2*nWloc*HGRP + T-1)/T, T, 0, stream>>>(hb, degS, nWloc, batch, gb, N, G);
    k_setup<<<1, 512, 0, stream>>>(gPair, partBase, gcur, rs + N, EP, NB2, N,
                                   W1l, b1l, W1r, b1r, att1, bias1, tabA, tabB);
    k_p2   <<<nTiles, T, 0, stream>>>(ei, E, EP, gcur, part);
    k_fine <<<NB2, T, 0, stream>>>(part, partBase, gPair, degS, rnd, rs, dr, col, N);

    // ---- layer 1 fused with layer-2 projection (A16/B16; X never materialized) ----
    k_gat1<<<gD16, T, 0, stream>>>(rs, col, dr, tabA, tabB,
                                   W2l, b2l, W2r, b2r, A16, B16, N);

    // ---- layer 2 fused with mean-pool accumulation ----
    k_gat <<<gD32, T, 0, stream>>>(rs, col, A16, B16, att2, bias2, batch, pooled, N);

    // ---- tiny classifier ----
    k_fc  <<<(G + 1)/2, 64, 0, stream>>>(pooled, gb, Wfc, bfc, (float*)d_out, G);
}

// Round 6
// 217.555 us; speedup vs baseline: 1.2030x; 1.0723x over previous
//
#include <hip/hip_runtime.h>
#include <hip/hip_fp16.h>
#include <math.h>

#define HC 32      // H*C
#define CH 16      // channels per head
#define NSLOPE 0.2f
#define NB2MAX 512 // max coarse buckets (128 nodes each; N <= 65536)
#define TILE 8192
#define CBMAX 6144 // colbuf per 128-node bucket (avg ~4.2K pairs)
#define NSL 128    // edge slices for src histogram -> exactly 256 blocks (1/CU)
#define HGRP 8     // slice groups for k_hred (NSL % HGRP == 0)
#define HLDS 12544 // LDS words per half-range histogram (supports halfN <= 25088)

// pair entry: (dst<<16) | src ; self pairs appended
__device__ __forceinline__ unsigned gen_pair(const int* __restrict__ ei, int E, int i){
    if (i < E) return (unsigned(ei[E+i]) << 16) | unsigned(ei[i]);
    unsigned n = i - E; return (n << 16) | n;
}

// packed fp16 max (ROCm 7.2 header lacks __hmax2)
__device__ __forceinline__ __half2 pkmax2(__half2 a, __half2 b){
    union { __half2 h; unsigned u; } ua, ub, ud;
    ua.h = a; ub.h = b;
    asm("v_pk_max_f16 %0, %1, %2" : "=v"(ud.u) : "v"(ua.u), "v"(ub.u));
    return ud.h;
}

__device__ __forceinline__ __half2 sfx2(__half2 x, int off){
    union { __half2 h; int i; } u; u.h = x;
    u.i = __shfl_xor(u.i, off);
    return u.h;
}

// src-degree histogram (multi-copy LDS, packed u16 counters) + fused coarse
// dst histogram (p==0 blocks). Scattered global atomics are ~50MB of
// write-through on MI355X (round-1 regression) — LDS privatization wins.
// int4-vectorized edge loads (4x fewer VMEM instructions), alignment-guarded.
__global__ void k_hsrc(const int* __restrict__ ei, int E, int halfN,
                       unsigned* __restrict__ hb, unsigned* __restrict__ gPair){
    __shared__ unsigned h[HLDS];
    __shared__ unsigned hp[NB2MAX];
    int t = threadIdx.x;                 // 512
    int nWloc = halfN >> 1;
    for (int i = t; i < nWloc; i += 512) h[i] = 0;
    int p = blockIdx.x & 1;
    if (p == 0){ hp[t] = 0; }
    __syncthreads();
    int slice = blockIdx.x >> 1;
    int base  = p * halfN;
    int chunk = (((E + NSL - 1) / NSL) + 3) & ~3;   // 4-aligned slice start
    int lo = slice*chunk, hi = lo + chunk; if (hi > E) hi = E;
    bool v4 = ((E & 3) == 0);
    if (v4 && lo < hi){
        int m4 = lo + ((hi - lo) & ~3);
        for (int i = lo + 4*t; i + 3 < hi; i += 4*512){
            int4 s4 = *(const int4*)(ei + i);
            int a0 = s4.x - base, a1 = s4.y - base, a2 = s4.z - base, a3 = s4.w - base;
            if ((unsigned)a0 < (unsigned)halfN) atomicAdd(&h[a0 >> 1], 1u << (16*(a0 & 1)));
            if ((unsigned)a1 < (unsigned)halfN) atomicAdd(&h[a1 >> 1], 1u << (16*(a1 & 1)));
            if ((unsigned)a2 < (unsigned)halfN) atomicAdd(&h[a2 >> 1], 1u << (16*(a2 & 1)));
            if ((unsigned)a3 < (unsigned)halfN) atomicAdd(&h[a3 >> 1], 1u << (16*(a3 & 1)));
            if (p == 0){
                int4 d4 = *(const int4*)(ei + E + i);
                atomicAdd(&hp[unsigned(d4.x) >> 7], 1u);
                atomicAdd(&hp[unsigned(d4.y) >> 7], 1u);
                atomicAdd(&hp[unsigned(d4.z) >> 7], 1u);
                atomicAdd(&hp[unsigned(d4.w) >> 7], 1u);
            }
        }
        for (int i = m4 + t; i < hi; i += 512){
            int s = ei[i] - base;
            if ((unsigned)s < (unsigned)halfN) atomicAdd(&h[s >> 1], 1u << (16*(s & 1)));
            if (p == 0) atomicAdd(&hp[unsigned(ei[E+i]) >> 7], 1u);
        }
    } else {
        for (int i = lo + t; i < hi; i += 512){
            int s = ei[i] - base;
            if ((unsigned)s < (unsigned)halfN) atomicAdd(&h[s >> 1], 1u << (16*(s & 1)));
            if (p == 0) atomicAdd(&hp[unsigned(ei[E+i]) >> 7], 1u);
        }
    }
    __syncthreads();
    unsigned* out = hb + (size_t)blockIdx.x * nWloc;
    for (int w = t; w < nWloc; w += 512) out[w] = h[w];
    if (p == 0 && hp[t]) atomicAdd(&gPair[t], hp[t]);
}

// reduce NSL slice copies into degS (HGRP partial groups via dense atomics,
// degS pre-zeroed) + fused per-graph bounds binary searches.
__global__ void k_hred(const unsigned* __restrict__ hb, unsigned* __restrict__ degS,
                       int nWloc,
                       const int* __restrict__ batch, int* __restrict__ gb,
                       int N, int G){
    int idx = blockIdx.x*blockDim.x + threadIdx.x;
    if (idx <= G){                          // graph bounds (independent work)
        int lo = 0, hi = N;
        while (lo < hi){ int mid = (lo+hi)>>1; if (batch[mid] < idx) lo = mid+1; else hi = mid; }
        gb[idx] = lo;
    }
    int total = 2*nWloc;
    int grp = idx / total;
    if (grp >= HGRP) return;
    int rem = idx - grp*total;
    int p = (rem < nWloc) ? 0 : 1;
    int w = rem - p*nWloc;
    unsigned s = 0;
    int sl0 = grp*(NSL/HGRP), sl1 = sl0 + NSL/HGRP;
    for (int sl = sl0; sl < sl1; ++sl)
        s += hb[(size_t)(sl*2 + p)*nWloc + w];
    if (s) atomicAdd(&degS[rem], s);
}

// fused: add self-loop counts, 512-bucket scan, layer-1 weight pack
__global__ void k_setup(unsigned* __restrict__ gPair,
                        int* __restrict__ partBase, int* __restrict__ gcur,
                        int* __restrict__ rsN, int EP, int nb, int N,
                        const float* __restrict__ W1l, const float* __restrict__ b1l,
                        const float* __restrict__ W1r, const float* __restrict__ b1r,
                        const float* __restrict__ att1, const float* __restrict__ bias1,
                        float4* __restrict__ tabA, float4* __restrict__ tabB){
    __shared__ int sp[NB2MAX];
    int t = threadIdx.x;   // 512
    int vp = 0;
    if (t < nb){
        int selfc = N - t*128;
        selfc = (selfc < 0) ? 0 : (selfc > 128 ? 128 : selfc);
        vp = (int)gPair[t] + selfc;
        gPair[t] = (unsigned)vp;          // total pairs per bucket (incl self-loops)
    }
    sp[t] = vp;
    __syncthreads();
    for (int d = 1; d < NB2MAX; d <<= 1){
        int x = (t >= d) ? sp[t-d] : 0;
        __syncthreads();
        sp[t] += x;
        __syncthreads();
    }
    if (t < nb){ partBase[t] = sp[t] - vp; gcur[t] = sp[t] - vp; }
    if (t == 0) rsN[0] = EP;
    if (t < HC){
        tabA[t] = make_float4(W1l[t*3] + b1l[t], W1l[t*3+1], W1l[t*3+2], att1[t]);
        tabB[t] = make_float4(W1r[t*3] + b1r[t], W1r[t*3+1], W1r[t*3+2], bias1[t]);
    }
}

// P2: per-tile LDS counting sort into 512 coarse buckets (bucket = dst>>7 = e>>23).
// Full tiles cache their 32 pair-entries in registers (static indices only) so
// the edge list is read once per tile, not twice.
__global__ void k_p2(const int* __restrict__ ei, int E, int EP,
                     int* __restrict__ gcur, unsigned* __restrict__ part){
    __shared__ int bcnt[NB2MAX], bstart[NB2MAX], c2[NB2MAX], gpos[NB2MAX], sc[256];
    __shared__ unsigned sorted[TILE];
    __shared__ unsigned short bktof[TILE];
    int t = threadIdx.x;   // 256
    int base = blockIdx.x * TILE;
    int cnt = EP - base; if (cnt > TILE) cnt = TILE;
    bool full = (cnt == TILE);

    bcnt[t] = 0; bcnt[t+256] = 0; c2[t] = 0; c2[t+256] = 0;
    __syncthreads();
    unsigned ec[TILE/256];
    if (full){
        #pragma unroll
        for (int q = 0; q < TILE/256; ++q)
            ec[q] = gen_pair(ei, E, base + t + q*256);
        #pragma unroll
        for (int q = 0; q < TILE/256; ++q)
            atomicAdd(&bcnt[ec[q] >> 23], 1);
    } else {
        for (int j = t; j < cnt; j += 256){
            unsigned e = gen_pair(ei, E, base + j);
            atomicAdd(&bcnt[e >> 23], 1);
        }
    }
    __syncthreads();
    int v0 = bcnt[2*t], v1 = bcnt[2*t+1];
    int s = v0 + v1;
    sc[t] = s;
    __syncthreads();
    for (int d = 1; d < 256; d <<= 1){
        int x = (t >= d) ? sc[t-d] : 0;
        __syncthreads();
        sc[t] += x;
        __syncthreads();
    }
    int excl = sc[t] - s;
    bstart[2*t]   = excl;
    bstart[2*t+1] = excl + v0;
    #pragma unroll
    for (int q = 0; q < 2; ++q){
        int bb = 2*t + q;
        int v = (q == 0) ? v0 : v1;
        if (v > 0){
            gpos[bb] = atomicAdd(&gcur[bb], v);
            int bs = bstart[bb];
            for (int j = 0; j < v; ++j) bktof[bs + j] = (unsigned short)bb;
        }
    }
    __syncthreads();
    if (full){
        #pragma unroll
        for (int q = 0; q < TILE/256; ++q){
            unsigned e = ec[q];
            int b = e >> 23;
            int off = atomicAdd(&c2[b], 1);
            sorted[bstart[b] + off] = e;
        }
    } else {
        for (int j = t; j < cnt; j += 256){
            unsigned e = gen_pair(ei, E, base + j);
            int b = e >> 23;
            int off = atomicAdd(&c2[b], 1);
            sorted[bstart[b] + off] = e;
        }
    }
    __syncthreads();
    for (int k = t; k < cnt; k += 256){
        int b = bktof[k];
        part[gpos[b] + (k - bstart[b])] = sorted[k];
    }
}

// fine pass: one block per 128-node bucket -> rs, (deg,rnd), col (coalesced out)
__global__ void k_fine(const unsigned* __restrict__ part, const int* __restrict__ partBase,
                       const unsigned* __restrict__ gPair,
                       const unsigned* __restrict__ degS, const float* __restrict__ rnd,
                       int* __restrict__ rs, float2* __restrict__ dr,
                       int* __restrict__ col, int N){
    __shared__ int pcnt[128], c2[128], lrs[129], sc[128];
    __shared__ int colbuf[CBMAX];
    int b = blockIdx.x, t = threadIdx.x;   // 256
    int beg = partBase[b], end = beg + (int)gPair[b];
    if (t < 128){ pcnt[t] = 0; c2[t] = 0; }
    __syncthreads();
    for (int k = beg + t; k < end; k += 256)
        atomicAdd(&pcnt[(part[k] >> 16) & 127], 1);
    __syncthreads();
    int v = (t < 128) ? pcnt[t] : 0;
    if (t < 128) sc[t] = v;
    __syncthreads();
    for (int d = 1; d < 128; d <<= 1){
        int x = (t >= d && t < 128) ? sc[t-d] : 0;
        __syncthreads();
        if (t < 128) sc[t] += x;
        __syncthreads();
    }
    if (t < 128){
        lrs[t] = sc[t] - v;
        if (t == 127) lrs[128] = sc[127];
    }
    __syncthreads();
    int n = (b << 7) + t;
    if (t < 128 && n < N){
        rs[n] = partBase[b] + lrs[t];
        unsigned s16 = (degS[n >> 1] >> (16*(n & 1))) & 0xFFFFu;
        dr[n] = make_float2((float)(pcnt[t] - 1 + (int)s16), rnd[n]);
    }
    for (int k = beg + t; k < end; k += 256){
        unsigned e = part[k];
        int j = (e >> 16) & 127;
        int pos = lrs[j] + atomicAdd(&c2[j], 1);
        if (pos < CBMAX) colbuf[pos] = (int)(e & 0xFFFFu);
    }
    __syncthreads();
    int npair = lrs[128];
    int cb = partBase[b];
    for (int k = t; k < npair; k += 256) col[cb + k] = colbuf[k];
}

// fused layer-1 GATv2 + layer-2 input projection. Params live in LDS
// (broadcast ds_read_b128 per channel) instead of 64-VGPR per-lane arrays —
// only the combined per-dst base[16] stays in registers. Epilogue projection
// weights pre-packed as float4 wq[j][lane] = {Wl[2k][j],Wl[2k+1][j],
// Wr[2k][j],Wr[2k+1][j]} -> 2 ds_read_b128 per step instead of 8 b32.
// All fp32 expressions/order identical to the proven round-2 kernel.
__global__ void k_gat1(const int* __restrict__ rs, const int* __restrict__ col,
                       const float2* __restrict__ dr,
                       const float4* __restrict__ tabA, const float4* __restrict__ tabB,
                       const float* __restrict__ W2l, const float* __restrict__ b2l,
                       const float* __restrict__ W2r, const float* __restrict__ b2r,
                       __half* __restrict__ A16, __half* __restrict__ B16, int N){
    __shared__ float4 tA[HC], tB[HC];      // layer-1 packed params (512 B)
    __shared__ float4 wq[HC][16];          // packed projection weights (8 KB)
    __shared__ float blS[HC], brS[HC];
    int t = threadIdx.x;                 // 256
    if (t < HC){ tA[t] = tabA[t]; tB[t] = tabB[t]; blS[t] = b2l[t]; brS[t] = b2r[t]; }
    for (int w = t; w < HC*16; w += 256){
        int j = w >> 4, k = w & 15;
        wq[j][k] = make_float4(W2l[(2*k)*HC + j], W2l[(2*k+1)*HC + j],
                               W2r[(2*k)*HC + j], W2r[(2*k+1)*HC + j]);
    }
    __syncthreads();

    int d = blockIdx.x*(blockDim.x >> 4) + (t >> 4);
    if (d >= N) return;
    int lane = t & 15;
    int h = lane >> 3, r = lane & 7;

    float2 drd = dr[d];
    float base[CH];
    #pragma unroll
    for (int c = 0; c < CH; ++c){
        float4 a4 = tA[h*CH + c];
        float4 b4 = tB[h*CH + c];
        float xr = b4.x + b4.y*drd.x + b4.z*drd.y;
        base[c] = a4.x + xr;
    }

    float l = 0.f, S1 = 0.f, S2 = 0.f;
    int beg = rs[d], end = rs[d+1];
    int p = beg + r;
    for (; p + 8 < end; p += 16){
        int s0 = __builtin_nontemporal_load(col + p);
        int s1 = __builtin_nontemporal_load(col + p + 8);
        float2 da = dr[s0];
        float2 db = dr[s1];
        float sc0 = 0.f, sc1 = 0.f;
        #pragma unroll
        for (int c = 0; c < CH; ++c){
            float4 a4 = tA[h*CH + c];
            float m0 = base[c] + a4.y*da.x + a4.z*da.y;
            float m1 = base[c] + a4.y*db.x + a4.z*db.y;
            m0 = (m0 > 0.f) ? m0 : NSLOPE*m0;
            m1 = (m1 > 0.f) ? m1 : NSLOPE*m1;
            sc0 += m0 * a4.w;
            sc1 += m1 * a4.w;
        }
        float ex0 = __expf(sc0), ex1 = __expf(sc1);
        l  += ex0 + ex1;
        S1 += ex0*da.x + ex1*db.x;
        S2 += ex0*da.y + ex1*db.y;
    }
    if (p < end){
        float2 ds = dr[__builtin_nontemporal_load(col + p)];
        float sc = 0.f;
        #pragma unroll
        for (int c = 0; c < CH; ++c){
            float4 a4 = tA[h*CH + c];
            float mm = base[c] + a4.y*ds.x + a4.z*ds.y;
            mm = (mm > 0.f) ? mm : NSLOPE*mm;
            sc += mm * a4.w;
        }
        float ex = __expf(sc);
        l  += ex;
        S1 += ex*ds.x;
        S2 += ex*ds.y;
    }

    #pragma unroll
    for (int off = 4; off >= 1; off >>= 1){
        l  += __shfl_xor(l,  off);
        S1 += __shfl_xor(S1, off);
        S2 += __shfl_xor(S2, off);
    }

    // layer-1 output channels 2*lane, 2*lane+1 (ELU'd), in-register
    float invl = 1.f/(l + 1e-16f);
    int c0 = r*2;
    float4 a40 = tA[h*CH + c0],     b40 = tB[h*CH + c0];
    float4 a41 = tA[h*CH + c0 + 1], b41 = tB[h*CH + c0 + 1];
    float v0 = a40.x + (a40.y*S1 + a40.z*S2)*invl + b40.w;
    float v1 = a41.x + (a41.y*S1 + a41.z*S2)*invl + b41.w;
    float x0 = (v0 > 0.f) ? v0 : expm1f(v0);
    float x1 = (v1 > 0.f) ? v1 : expm1f(v1);

    // in-subgroup 32x32 projection: out[k] = b[k] + sum_j x[j]*W[k][j]
    int k0 = 2*lane;
    float a0 = blS[k0], a1 = blS[k0+1];
    float g0 = brS[k0], g1 = brS[k0+1];
    #pragma unroll
    for (int tt = 0; tt < 16; ++tt){
        float xa = __shfl(x0, tt, 16);     // x[2*tt]
        float xb = __shfl(x1, tt, 16);     // x[2*tt+1]
        int j = 2*tt;
        float4 q0 = wq[j][lane];
        float4 q1 = wq[j+1][lane];
        a0 += xa*q0.x + xb*q1.x;
        a1 += xa*q0.y + xb*q1.y;
        g0 += xa*q0.z + xb*q1.z;
        g1 += xa*q0.w + xb*q1.w;
    }
    *(__half2*)(A16 + (size_t)d*HC + k0) = __floats2half2_rn(a0, a1);
    *(__half2*)(B16 + (size_t)d*HC + k0) = __floats2half2_rn(g0, g1);
}

// fused layer-2 GATv2 + mean-pool accumulation: head-paired 32-lane subgroup
// per dst; two-way edge loop (proven); packed fp16 math; channel-splitting
// halving merge. Epilogue: per-block LDS dedup of pooled contributions
// (batch-sorted -> a block's 8 dsts span 1-2 graphs), then ONE global
// atomicAdd per (block, graph, channel): ~8x fewer device-scope atomics.
__global__ void k_gat(const int* __restrict__ rs, const int* __restrict__ col,
                      const __half* __restrict__ A16, const __half* __restrict__ B16,
                      const float* __restrict__ att, const float* __restrict__ bias,
                      const int* __restrict__ batch, float* __restrict__ pooled, int N){
    __shared__ float pool[8][HC];
    __shared__ int sb[8];
    int sg = threadIdx.x >> 5;
    int d = blockIdx.x*(blockDim.x >> 5) + sg;
    int lane = threadIdx.x & 31;
    bool valid = (d < N);
    int dcl = valid ? d : 0;
    int h = lane >> 4, r = lane & 15;

    union U { uint4 u[2]; __half2 h2[8]; };
    U xr;
    {
        const uint4* bp = (const uint4*)(B16 + (size_t)dcl*HC + h*CH);
        xr.u[0] = bp[0]; xr.u[1] = bp[1];
    }
    __half2 at2[8];
    const float* atf = att + h*CH;
    #pragma unroll
    for (int i = 0; i < 8; ++i) at2[i] = __floats2half2_rn(atf[2*i], atf[2*i+1]);
    const __half2 ns2 = __float2half2_rn(NSLOPE);

    float l = 0.f;
    __half2 acc2[8];
    #pragma unroll
    for (int i = 0; i < 8; ++i) acc2[i] = __float2half2_rn(0.f);

    int beg = rs[dcl], end = valid ? rs[dcl+1] : beg;
    int p = beg + r;
    for (; p + 16 < end; p += 32){
        int s0 = __builtin_nontemporal_load(col + p);
        int s1 = __builtin_nontemporal_load(col + p + 16);
        const uint4* rp0 = (const uint4*)(A16 + (size_t)s0*HC + h*CH);
        const uint4* rp1 = (const uint4*)(A16 + (size_t)s1*HC + h*CH);
        U a, b;
        a.u[0] = rp0[0]; a.u[1] = rp0[1];     // both gathers in flight before use
        b.u[0] = rp1[0]; b.u[1] = rp1[1];
        __half2 sc2 = __float2half2_rn(0.f);
        #pragma unroll
        for (int i = 0; i < 8; ++i){
            __half2 m  = __hadd2(a.h2[i], xr.h2[i]);
            __half2 lk = pkmax2(m, __hmul2(m, ns2));
            sc2 = __hfma2(lk, at2[i], sc2);
        }
        float ex = __expf(__low2float(sc2) + __high2float(sc2));
        l += ex;
        __half2 exh = __float2half2_rn(ex);
        #pragma unroll
        for (int i = 0; i < 8; ++i) acc2[i] = __hfma2(a.h2[i], exh, acc2[i]);

        sc2 = __float2half2_rn(0.f);
        #pragma unroll
        for (int i = 0; i < 8; ++i){
            __half2 m  = __hadd2(b.h2[i], xr.h2[i]);
            __half2 lk = pkmax2(m, __hmul2(m, ns2));
            sc2 = __hfma2(lk, at2[i], sc2);
        }
        ex = __expf(__low2float(sc2) + __high2float(sc2));
        l += ex;
        exh = __float2half2_rn(ex);
        #pragma unroll
        for (int i = 0; i < 8; ++i) acc2[i] = __hfma2(b.h2[i], exh, acc2[i]);
    }
    if (p < end){
        int s = __builtin_nontemporal_load(col + p);
        const uint4* rp = (const uint4*)(A16 + (size_t)s*HC + h*CH);
        U a;
        a.u[0] = rp[0]; a.u[1] = rp[1];
        __half2 sc2 = __float2half2_rn(0.f);
        #pragma unroll
        for (int i = 0; i < 8; ++i){
            __half2 m  = __hadd2(a.h2[i], xr.h2[i]);
            __half2 lk = pkmax2(m, __hmul2(m, ns2));
            sc2 = __hfma2(lk, at2[i], sc2);
        }
        float ex = __expf(__low2float(sc2) + __high2float(sc2));
        l += ex;
        __half2 exh = __float2half2_rn(ex);
        #pragma unroll
        for (int i = 0; i < 8; ++i) acc2[i] = __hfma2(a.h2[i], exh, acc2[i]);
    }

    // channel-splitting halving merge across the 16-lane half.
    __half2 v4[4];
    {
        bool hi = (r & 8) != 0;
        #pragma unroll
        for (int i = 0; i < 4; ++i){
            __half2 send = hi ? acc2[i] : acc2[i+4];
            __half2 recv = sfx2(send, 8);
            v4[i] = __hadd2(hi ? acc2[i+4] : acc2[i], recv);
        }
    }
    __half2 v2[2];
    {
        bool hi = (r & 4) != 0;
        __half2 s0 = hi ? v4[0] : v4[2];
        __half2 s1 = hi ? v4[1] : v4[3];
        __half2 r0 = sfx2(s0, 4);
        __half2 r1 = sfx2(s1, 4);
        v2[0] = __hadd2(hi ? v4[2] : v4[0], r0);
        v2[1] = __hadd2(hi ? v4[3] : v4[1], r1);
    }
    __half2 v1;
    {
        bool hi = (r & 2) != 0;
        __half2 send = hi ? v2[0] : v2[1];
        __half2 recv = sfx2(send, 2);
        v1 = __hadd2(hi ? v2[1] : v2[0], recv);
    }
    float mine;
    {
        bool hi = (r & 1) != 0;
        float lo = __low2float(v1), hf = __high2float(v1);
        float send = hi ? lo : hf;
        float recv = __shfl_xor(send, 1);
        mine = (hi ? hf : lo) + recv;   // lane r owns channel r total
    }
    #pragma unroll
    for (int off = 8; off >= 1; off >>= 1) l += __shfl_xor(l, off);

    float invl = 1.f/(l + 1e-16f);
    float val = mine*invl + bias[h*CH + r];
    val = (val > 0.f) ? val : expm1f(val);

    // ---- block-level dedup, then one device atomic per (graph,channel) ----
    if (lane == 0) sb[sg] = valid ? batch[d] : (-1 - sg);   // unique sentinel
    pool[sg][h*CH + r] = val;                               // own row, plain store
    __syncthreads();
    int myb = sb[sg];
    int first = sg;
    #pragma unroll
    for (int j = 7; j >= 0; --j) if (sb[j] == myb) first = j;
    if (valid && first == sg){
        float s = 0.f;
        #pragma unroll
        for (int j = 0; j < 8; ++j) if (sb[j] == myb) s += pool[j][h*CH + r];
        atomicAdd(&pooled[(size_t)myb*HC + h*CH + r], s);
    }
}

// tiny classifier: mean over graph (counts from gb) + fc + log_softmax
__global__ void k_fc(const float* __restrict__ pooled, const int* __restrict__ gb,
                     const float* __restrict__ Wfc, const float* __restrict__ bfc,
                     float* __restrict__ out, int G){
    int t = threadIdx.x;            // 64 -> two graphs per wave
    int g = blockIdx.x*2 + (t >> 5);
    int c = t & 31;
    if (g >= G) return;
    float cnt = (float)(gb[g+1] - gb[g]);
    if (cnt < 1.f) cnt = 1.f;
    float pv = pooled[g*HC + c] / cnt;
    float p0 = pv * Wfc[c];
    float p1 = pv * Wfc[HC + c];
    #pragma unroll
    for (int off = 16; off >= 1; off >>= 1){
        p0 += __shfl_xor(p0, off, 32);
        p1 += __shfl_xor(p1, off, 32);
    }
    if (c == 0){
        float l0 = p0 + bfc[0], l1 = p1 + bfc[1];
        float m = (l0 > l1) ? l0 : l1;
        float lse = m + logf(__expf(l0 - m) + __expf(l1 - m));
        out[g*2 + 0] = l0 - lse;
        out[g*2 + 1] = l1 - lse;
    }
}

extern "C" void kernel_launch(void* const* d_in, const int* in_sizes, int n_in,
                              void* d_out, int out_size, void* d_ws, size_t ws_size,
                              hipStream_t stream) {
    const int*   ei    = (const int*)  d_in[0];
    const int*   batch = (const int*)  d_in[1];
    const float* rnd   = (const float*)d_in[2];
    const float* W1l   = (const float*)d_in[3];
    const float* b1l   = (const float*)d_in[4];
    const float* W1r   = (const float*)d_in[5];
    const float* b1r   = (const float*)d_in[6];
    const float* att1  = (const float*)d_in[7];
    const float* bias1 = (const float*)d_in[8];
    const float* W2l   = (const float*)d_in[9];
    const float* b2l   = (const float*)d_in[10];
    const float* W2r   = (const float*)d_in[11];
    const float* b2r   = (const float*)d_in[12];
    const float* att2  = (const float*)d_in[13];
    const float* bias2 = (const float*)d_in[14];
    const float* Wfc   = (const float*)d_in[15];
    const float* bfc   = (const float*)d_in[16];

    const int E  = in_sizes[0] / 2;
    const int N  = in_sizes[1];
    const int G  = out_size / 2;
    const int EP = E + N;                    // pairs (edges + self-loops)
    const int NB2 = (N + 127) >> 7;          // 128-node coarse buckets
    const int halfN = (((N + 1) >> 1) + 1) & ~1;   // even half-range
    const int nWloc = halfN >> 1;            // packed u16 words per half

    // workspace layout. Liveness-based aliasing:
    //   hb (12.8MB, k_hsrc->k_hred) aliases [0 .. 12.8MB): A16,B16 and the low
    //     part of col are all written strictly AFTER hb dies.
    //   part (6.6MB, k_p2->k_fine) aliases [0 .. 6.6MB): A16/B16 written after.
    //   dr/rs/col sit above the hb region; degS+ctrl above those.
    float* ws        = (float*)d_ws;
    __half* A16      = (__half*)ws;             // N*HC halfs
    __half* B16      = A16 + (size_t)N*HC;      // N*HC halfs
    unsigned* hb     = (unsigned*)ws;           // NSL*2 * nWloc words
    unsigned* part   = (unsigned*)ws;           // EP u32
    size_t off       = (size_t)NSL*2*nWloc;     // words consumed by hb
    if (off < (size_t)EP)   off = EP;           // ... and part
    if (off < (size_t)N*HC) off = (size_t)N*HC; // ... and A16+B16 (N*HC words total)
    off = (off + 1) & ~(size_t)1;
    float2* dr       = (float2*)(ws + off);     // N float2 (deg, rnd)
    int*   rs        = (int*)(dr + N);          // N+1
    int*   col       = rs + N + 1;              // EP
    unsigned* degS   = (unsigned*)(col + EP);   // 2*nWloc words (packed u16)
    unsigned* gPair  = degS + 2*nWloc;          // NB2MAX
    float* pooled    = (float*)(gPair + NB2MAX);// G*HC
    int*   partBase  = (int*)(pooled + (size_t)G*HC);  // NB2MAX
    int*   gcur      = partBase + NB2MAX;       // NB2MAX
    int*   gb        = gcur + NB2MAX;           // G+1
    float4* tabA     = (float4*)((((size_t)(gb + G + 1)) + 15) & ~(size_t)15);
    float4* tabB     = tabA + HC;

    const int T = 256;
    const int gD16 = (N + (T>>4) - 1)/(T>>4);   // 16-lane-per-dst subgroups (layer 1)
    const int gD32 = (N + (T>>5) - 1)/(T>>5);   // 32-lane-per-dst subgroups (layer 2)
    const int nTiles = (EP + TILE - 1)/TILE;

    // degS + gPair + pooled adjacent: one memset zeroes all three
    (void)hipMemsetAsync(degS, 0, (size_t)(2*nWloc + NB2MAX + (size_t)G*HC)*sizeof(unsigned), stream);

    // ---- degree + CSR build (LDS-privatized histograms; NO global scatter atomics) ----
    k_hsrc <<<NSL*2, 512, 0, stream>>>(ei, E, halfN, hb, gPair);
    k_hred <<<(2*nWloc*HGRP + T-1)/T, T, 0, stream>>>(hb, degS, nWloc, batch, gb, N, G);
    k_setup<<<1, 512, 0, stream>>>(gPair, partBase, gcur, rs + N, EP, NB2, N,
                                   W1l, b1l, W1r, b1r, att1, bias1, tabA, tabB);
    k_p2   <<<nTiles, T, 0, stream>>>(ei, E, EP, gcur, part);
    k_fine <<<NB2, T, 0, stream>>>(part, partBase, gPair, degS, rnd, rs, dr, col, N);

    // ---- layer 1 fused with layer-2 projection (A16/B16; X never materialized) ----
    k_gat1<<<gD16, T, 0, stream>>>(rs, col, dr, tabA, tabB,
                                   W2l, b2l, W2r, b2r, A16, B16, N);

    // ---- layer 2 fused with mean-pool accumulation ----
    k_gat <<<gD32, T, 0, stream>>>(rs, col, A16, B16, att2, bias2, batch, pooled, N);

    // ---- tiny classifier ----
    k_fc  <<<(G + 1)/2, 64, 0, stream>>>(pooled, gb, Wfc, bfc, (float*)d_out, G);
}

// Round 7
// 212.248 us; speedup vs baseline: 1.2331x; 1.0250x over previous
//
#include <hip/hip_runtime.h>
#include <hip/hip_fp16.h>
#include <math.h>

#define HC 32      // H*C
#define CH 16      // channels per head
#define NSLOPE 0.2f
#define NB2MAX 512 // max coarse buckets (128 nodes each; N <= 65536)
#define TILE 8192
#define CBMAX 6144 // fixed per-bucket capacity (mean ~4224, +30 sigma)
#define NSL 128    // edge slices for src histogram -> exactly 256 blocks (1/CU)
#define HGRP 8     // slice groups for hred (NSL % HGRP == 0)
#define HLDS 12544 // LDS words per half-range histogram (supports halfN <= 25088)

// pair entry: (dst<<16) | src ; self pairs appended
__device__ __forceinline__ unsigned gen_pair(const int* __restrict__ ei, int E, int i){
    if (i < E) return (unsigned(ei[E+i]) << 16) | unsigned(ei[i]);
    unsigned n = i - E; return (n << 16) | n;
}

// packed fp16 max (ROCm 7.2 header lacks __hmax2)
__device__ __forceinline__ __half2 pkmax2(__half2 a, __half2 b){
    union { __half2 h; unsigned u; } ua, ub, ud;
    ua.h = a; ub.h = b;
    asm("v_pk_max_f16 %0, %1, %2" : "=v"(ud.u) : "v"(ua.u), "v"(ub.u));
    return ud.h;
}

__device__ __forceinline__ __half2 sfx2(__half2 x, int off){
    union { __half2 h; int i; } u; u.h = x;
    u.i = __shfl_xor(u.i, off);
    return u.h;
}

// src-degree histogram (multi-copy LDS, packed u16 counters) + fused coarse
// dst histogram (p==0 blocks) + gcur fixed-base init (block 0 only).
// Scattered global atomics are ~50MB write-through on MI355X (round-1
// regression) — LDS privatization wins. int4-vectorized edge loads.
__global__ void k_hsrc(const int* __restrict__ ei, int E, int halfN,
                       unsigned* __restrict__ hb, unsigned* __restrict__ gPair,
                       int* __restrict__ gcur){
    __shared__ unsigned h[HLDS];
    __shared__ unsigned hp[NB2MAX];
    int t = threadIdx.x;                 // 512
    int nWloc = halfN >> 1;
    for (int i = t; i < nWloc; i += 512) h[i] = 0;
    int p = blockIdx.x & 1;
    if (p == 0){ hp[t] = 0; }
    if (blockIdx.x == 0 && t < NB2MAX) gcur[t] = t*CBMAX;   // fixed part bases
    __syncthreads();
    int slice = blockIdx.x >> 1;
    int base  = p * halfN;
    int chunk = (((E + NSL - 1) / NSL) + 3) & ~3;   // 4-aligned slice start
    int lo = slice*chunk, hi = lo + chunk; if (hi > E) hi = E;
    bool v4 = ((E & 3) == 0);
    if (v4 && lo < hi){
        int m4 = lo + ((hi - lo) & ~3);
        for (int i = lo + 4*t; i + 3 < hi; i += 4*512){
            int4 s4 = *(const int4*)(ei + i);
            int a0 = s4.x - base, a1 = s4.y - base, a2 = s4.z - base, a3 = s4.w - base;
            if ((unsigned)a0 < (unsigned)halfN) atomicAdd(&h[a0 >> 1], 1u << (16*(a0 & 1)));
            if ((unsigned)a1 < (unsigned)halfN) atomicAdd(&h[a1 >> 1], 1u << (16*(a1 & 1)));
            if ((unsigned)a2 < (unsigned)halfN) atomicAdd(&h[a2 >> 1], 1u << (16*(a2 & 1)));
            if ((unsigned)a3 < (unsigned)halfN) atomicAdd(&h[a3 >> 1], 1u << (16*(a3 & 1)));
            if (p == 0){
                int4 d4 = *(const int4*)(ei + E + i);
                atomicAdd(&hp[unsigned(d4.x) >> 7], 1u);
                atomicAdd(&hp[unsigned(d4.y) >> 7], 1u);
                atomicAdd(&hp[unsigned(d4.z) >> 7], 1u);
                atomicAdd(&hp[unsigned(d4.w) >> 7], 1u);
            }
        }
        for (int i = m4 + t; i < hi; i += 512){
            int s = ei[i] - base;
            if ((unsigned)s < (unsigned)halfN) atomicAdd(&h[s >> 1], 1u << (16*(s & 1)));
            if (p == 0) atomicAdd(&hp[unsigned(ei[E+i]) >> 7], 1u);
        }
    } else {
        for (int i = lo + t; i < hi; i += 512){
            int s = ei[i] - base;
            if ((unsigned)s < (unsigned)halfN) atomicAdd(&h[s >> 1], 1u << (16*(s & 1)));
            if (p == 0) atomicAdd(&hp[unsigned(ei[E+i]) >> 7], 1u);
        }
    }
    __syncthreads();
    unsigned* out = hb + (size_t)blockIdx.x * nWloc;
    for (int w = t; w < nWloc; w += 512) out[w] = h[w];
    if (p == 0 && hp[t]) atomicAdd(&gPair[t], hp[t]);
}

// MERGED middle stage: role-split by blockIdx (all roles depend only on
// k_hsrc outputs; on a captured graph, separate launches would fully
// serialize — merging overlaps them on the CU array).
//   blocks [0, nTiles)            : p2 counting sort into fixed-capacity part
//   blocks [nTiles, nTiles+nHred) : hred slice-copy reduction + gb searches
//   block  nTiles+nHred           : setup (self counts, scan -> partBase, tabs)
__global__ void k_mid(const int* __restrict__ ei, int E, int EP,
                      int* __restrict__ gcur, unsigned* __restrict__ part,
                      const unsigned* __restrict__ hb, unsigned* __restrict__ degS,
                      int nWloc, const int* __restrict__ batch, int* __restrict__ gb,
                      int N, int G, int nTiles, int nHred,
                      unsigned* __restrict__ gPair,
                      int* __restrict__ partBase, int* __restrict__ rsN, int nb,
                      const float* __restrict__ W1l, const float* __restrict__ b1l,
                      const float* __restrict__ W1r, const float* __restrict__ b1r,
                      const float* __restrict__ att1, const float* __restrict__ bias1,
                      float4* __restrict__ tabA, float4* __restrict__ tabB){
    __shared__ int bcnt[NB2MAX], bstart[NB2MAX], c2[NB2MAX], gpos[NB2MAX], sc[256];
    __shared__ unsigned sorted[TILE];
    __shared__ unsigned short bktof[TILE];
    int t = threadIdx.x;   // 256
    int blk = blockIdx.x;

    if (blk < nTiles){
        // ---------------- p2 role: LDS counting sort (bucket = e>>23) ----------------
        int base = blk * TILE;
        int cnt = EP - base; if (cnt > TILE) cnt = TILE;
        bool full = (cnt == TILE);
        bcnt[t] = 0; bcnt[t+256] = 0; c2[t] = 0; c2[t+256] = 0;
        __syncthreads();
        unsigned ec[TILE/256];
        if (full){
            #pragma unroll
            for (int q = 0; q < TILE/256; ++q)
                ec[q] = gen_pair(ei, E, base + t + q*256);
            #pragma unroll
            for (int q = 0; q < TILE/256; ++q)
                atomicAdd(&bcnt[ec[q] >> 23], 1);
        } else {
            for (int j = t; j < cnt; j += 256){
                unsigned e = gen_pair(ei, E, base + j);
                atomicAdd(&bcnt[e >> 23], 1);
            }
        }
        __syncthreads();
        int v0 = bcnt[2*t], v1 = bcnt[2*t+1];
        int s = v0 + v1;
        sc[t] = s;
        __syncthreads();
        for (int d = 1; d < 256; d <<= 1){
            int x = (t >= d) ? sc[t-d] : 0;
            __syncthreads();
            sc[t] += x;
            __syncthreads();
        }
        int excl = sc[t] - s;
        bstart[2*t]   = excl;
        bstart[2*t+1] = excl + v0;
        #pragma unroll
        for (int q = 0; q < 2; ++q){
            int bb = 2*t + q;
            int v = (q == 0) ? v0 : v1;
            if (v > 0){
                gpos[bb] = atomicAdd(&gcur[bb], v);
                int bs = bstart[bb];
                for (int j = 0; j < v; ++j) bktof[bs + j] = (unsigned short)bb;
            }
        }
        __syncthreads();
        if (full){
            #pragma unroll
            for (int q = 0; q < TILE/256; ++q){
                unsigned e = ec[q];
                int b = e >> 23;
                int off = atomicAdd(&c2[b], 1);
                sorted[bstart[b] + off] = e;
            }
        } else {
            for (int j = t; j < cnt; j += 256){
                unsigned e = gen_pair(ei, E, base + j);
                int b = e >> 23;
                int off = atomicAdd(&c2[b], 1);
                sorted[bstart[b] + off] = e;
            }
        }
        __syncthreads();
        for (int k = t; k < cnt; k += 256){
            int b = bktof[k];
            int w = gpos[b] + (k - bstart[b]);
            if (w < (b+1)*CBMAX) part[w] = sorted[k];   // capacity guard
        }
    } else if (blk < nTiles + nHred){
        // ---------------- hred role: reduce slice copies + graph bounds ----------------
        int idx = (blk - nTiles)*256 + t;
        if (idx <= G){
            int lo = 0, hi = N;
            while (lo < hi){ int mid = (lo+hi)>>1; if (batch[mid] < idx) lo = mid+1; else hi = mid; }
            gb[idx] = lo;
        }
        int total = 2*nWloc;
        int grp = idx / total;
        if (grp < HGRP){
            int rem = idx - grp*total;
            int p = (rem < nWloc) ? 0 : 1;
            int w = rem - p*nWloc;
            unsigned s = 0;
            int sl0 = grp*(NSL/HGRP), sl1 = sl0 + NSL/HGRP;
            for (int sl = sl0; sl < sl1; ++sl)
                s += hb[(size_t)(sl*2 + p)*nWloc + w];
            if (s) atomicAdd(&degS[rem], s);
        }
    } else {
        // ---------------- setup role: self counts + pair-scan + weight pack ----------------
        int vp0 = 0, vp1 = 0;
        int b0 = 2*t, b1 = 2*t + 1;
        if (b0 < nb){
            int selfc = N - b0*128;
            selfc = (selfc < 0) ? 0 : (selfc > 128 ? 128 : selfc);
            vp0 = (int)gPair[b0] + selfc;
            gPair[b0] = (unsigned)vp0;
        }
        if (b1 < nb){
            int selfc = N - b1*128;
            selfc = (selfc < 0) ? 0 : (selfc > 128 ? 128 : selfc);
            vp1 = (int)gPair[b1] + selfc;
            gPair[b1] = (unsigned)vp1;
        }
        int s = vp0 + vp1;
        sc[t] = s;
        __syncthreads();
        for (int d = 1; d < 256; d <<= 1){
            int x = (t >= d) ? sc[t-d] : 0;
            __syncthreads();
            sc[t] += x;
            __syncthreads();
        }
        int excl = sc[t] - s;
        if (b0 < nb) partBase[b0] = excl;
        if (b1 < nb) partBase[b1] = excl + vp0;
        if (t == 0) rsN[0] = EP;
        if (t < HC){
            tabA[t] = make_float4(W1l[t*3] + b1l[t], W1l[t*3+1], W1l[t*3+2], att1[t]);
            tabB[t] = make_float4(W1r[t*3] + b1r[t], W1r[t*3+1], W1r[t*3+2], bias1[t]);
        }
    }
}

// fine pass: one block per 128-node bucket -> rs, (deg,rnd), col (dense,
// coalesced out). part is read at FIXED base b*CBMAX; col stays dense via
// partBase (scan).
__global__ void k_fine(const unsigned* __restrict__ part, const int* __restrict__ partBase,
                       const unsigned* __restrict__ gPair,
                       const unsigned* __restrict__ degS, const float* __restrict__ rnd,
                       int* __restrict__ rs, float2* __restrict__ dr,
                       int* __restrict__ col, int N){
    __shared__ int pcnt[128], c2[128], lrs[129], sc[128];
    __shared__ int colbuf[CBMAX];
    int b = blockIdx.x, t = threadIdx.x;   // 256
    int beg = b*CBMAX, end = beg + (int)gPair[b];
    if (t < 128){ pcnt[t] = 0; c2[t] = 0; }
    __syncthreads();
    for (int k = beg + t; k < end; k += 256)
        atomicAdd(&pcnt[(part[k] >> 16) & 127], 1);
    __syncthreads();
    int v = (t < 128) ? pcnt[t] : 0;
    if (t < 128) sc[t] = v;
    __syncthreads();
    for (int d = 1; d < 128; d <<= 1){
        int x = (t >= d && t < 128) ? sc[t-d] : 0;
        __syncthreads();
        if (t < 128) sc[t] += x;
        __syncthreads();
    }
    if (t < 128){
        lrs[t] = sc[t] - v;
        if (t == 127) lrs[128] = sc[127];
    }
    __syncthreads();
    int n = (b << 7) + t;
    int pb = partBase[b];
    if (t < 128 && n < N){
        rs[n] = pb + lrs[t];
        unsigned s16 = (degS[n >> 1] >> (16*(n & 1))) & 0xFFFFu;
        dr[n] = make_float2((float)(pcnt[t] - 1 + (int)s16), rnd[n]);
    }
    for (int k = beg + t; k < end; k += 256){
        unsigned e = part[k];
        int j = (e >> 16) & 127;
        int pos = lrs[j] + atomicAdd(&c2[j], 1);
        if (pos < CBMAX) colbuf[pos] = (int)(e & 0xFFFFu);
    }
    __syncthreads();
    int npair = lrs[128];
    for (int k = t; k < npair; k += 256) col[pb + k] = colbuf[k];
}

// fused layer-1 GATv2 + layer-2 input projection. Params in LDS (broadcast
// ds_read_b128 per channel); only per-dst base[16] in registers. Projection
// weights pre-packed float4. (Round-6 proven: VGPR-64 rematerialization fix.)
__global__ void k_gat1(const int* __restrict__ rs, const int* __restrict__ col,
                       const float2* __restrict__ dr,
                       const float4* __restrict__ tabA, const float4* __restrict__ tabB,
                       const float* __restrict__ W2l, const float* __restrict__ b2l,
                       const float* __restrict__ W2r, const float* __restrict__ b2r,
                       __half* __restrict__ A16, __half* __restrict__ B16, int N){
    __shared__ float4 tA[HC], tB[HC];      // layer-1 packed params (512 B)
    __shared__ float4 wq[HC][16];          // packed projection weights (8 KB)
    __shared__ float blS[HC], brS[HC];
    int t = threadIdx.x;                 // 256
    if (t < HC){ tA[t] = tabA[t]; tB[t] = tabB[t]; blS[t] = b2l[t]; brS[t] = b2r[t]; }
    for (int w = t; w < HC*16; w += 256){
        int j = w >> 4, k = w & 15;
        wq[j][k] = make_float4(W2l[(2*k)*HC + j], W2l[(2*k+1)*HC + j],
                               W2r[(2*k)*HC + j], W2r[(2*k+1)*HC + j]);
    }
    __syncthreads();

    int d = blockIdx.x*(blockDim.x >> 4) + (t >> 4);
    if (d >= N) return;
    int lane = t & 15;
    int h = lane >> 3, r = lane & 7;

    float2 drd = dr[d];
    float base[CH];
    #pragma unroll
    for (int c = 0; c < CH; ++c){
        float4 a4 = tA[h*CH + c];
        float4 b4 = tB[h*CH + c];
        float xr = b4.x + b4.y*drd.x + b4.z*drd.y;
        base[c] = a4.x + xr;
    }

    float l = 0.f, S1 = 0.f, S2 = 0.f;
    int beg = rs[d], end = rs[d+1];
    int p = beg + r;
    for (; p + 8 < end; p += 16){
        int s0 = __builtin_nontemporal_load(col + p);
        int s1 = __builtin_nontemporal_load(col + p + 8);
        float2 da = dr[s0];
        float2 db = dr[s1];
        float sc0 = 0.f, sc1 = 0.f;
        #pragma unroll
        for (int c = 0; c < CH; ++c){
            float4 a4 = tA[h*CH + c];
            float m0 = base[c] + a4.y*da.x + a4.z*da.y;
            float m1 = base[c] + a4.y*db.x + a4.z*db.y;
            m0 = (m0 > 0.f) ? m0 : NSLOPE*m0;
            m1 = (m1 > 0.f) ? m1 : NSLOPE*m1;
            sc0 += m0 * a4.w;
            sc1 += m1 * a4.w;
        }
        float ex0 = __expf(sc0), ex1 = __expf(sc1);
        l  += ex0 + ex1;
        S1 += ex0*da.x + ex1*db.x;
        S2 += ex0*da.y + ex1*db.y;
    }
    if (p < end){
        float2 ds = dr[__builtin_nontemporal_load(col + p)];
        float sc = 0.f;
        #pragma unroll
        for (int c = 0; c < CH; ++c){
            float4 a4 = tA[h*CH + c];
            float mm = base[c] + a4.y*ds.x + a4.z*ds.y;
            mm = (mm > 0.f) ? mm : NSLOPE*mm;
            sc += mm * a4.w;
        }
        float ex = __expf(sc);
        l  += ex;
        S1 += ex*ds.x;
        S2 += ex*ds.y;
    }

    #pragma unroll
    for (int off = 4; off >= 1; off >>= 1){
        l  += __shfl_xor(l,  off);
        S1 += __shfl_xor(S1, off);
        S2 += __shfl_xor(S2, off);
    }

    // layer-1 output channels 2*lane, 2*lane+1 (ELU'd), in-register
    float invl = 1.f/(l + 1e-16f);
    int c0 = r*2;
    float4 a40 = tA[h*CH + c0],     b40 = tB[h*CH + c0];
    float4 a41 = tA[h*CH + c0 + 1], b41 = tB[h*CH + c0 + 1];
    float v0 = a40.x + (a40.y*S1 + a40.z*S2)*invl + b40.w;
    float v1 = a41.x + (a41.y*S1 + a41.z*S2)*invl + b41.w;
    float x0 = (v0 > 0.f) ? v0 : expm1f(v0);
    float x1 = (v1 > 0.f) ? v1 : expm1f(v1);

    // in-subgroup 32x32 projection: out[k] = b[k] + sum_j x[j]*W[k][j]
    int k0 = 2*lane;
    float a0 = blS[k0], a1 = blS[k0+1];
    float g0 = brS[k0], g1 = brS[k0+1];
    #pragma unroll
    for (int tt = 0; tt < 16; ++tt){
        float xa = __shfl(x0, tt, 16);     // x[2*tt]
        float xb = __shfl(x1, tt, 16);     // x[2*tt+1]
        int j = 2*tt;
        float4 q0 = wq[j][lane];
        float4 q1 = wq[j+1][lane];
        a0 += xa*q0.x + xb*q1.x;
        a1 += xa*q0.y + xb*q1.y;
        g0 += xa*q0.z + xb*q1.z;
        g1 += xa*q0.w + xb*q1.w;
    }
    *(__half2*)(A16 + (size_t)d*HC + k0) = __floats2half2_rn(a0, a1);
    *(__half2*)(B16 + (size_t)d*HC + k0) = __floats2half2_rn(g0, g1);
}

// fused layer-2 GATv2 + mean-pool accumulation: head-paired 32-lane subgroup
// per dst; two-way edge loop (proven); packed fp16 math; channel-splitting
// halving merge; per-block LDS pool dedup -> ~8x fewer device atomics.
__global__ void k_gat(const int* __restrict__ rs, const int* __restrict__ col,
                      const __half* __restrict__ A16, const __half* __restrict__ B16,
                      const float* __restrict__ att, const float* __restrict__ bias,
                      const int* __restrict__ batch, float* __restrict__ pooled, int N){
    __shared__ float pool[8][HC];
    __shared__ int sb[8];
    int sg = threadIdx.x >> 5;
    int d = blockIdx.x*(blockDim.x >> 5) + sg;
    int lane = threadIdx.x & 31;
    bool valid = (d < N);
    int dcl = valid ? d : 0;
    int h = lane >> 4, r = lane & 15;

    union U { uint4 u[2]; __half2 h2[8]; };
    U xr;
    {
        const uint4* bp = (const uint4*)(B16 + (size_t)dcl*HC + h*CH);
        xr.u[0] = bp[0]; xr.u[1] = bp[1];
    }
    __half2 at2[8];
    const float* atf = att + h*CH;
    #pragma unroll
    for (int i = 0; i < 8; ++i) at2[i] = __floats2half2_rn(atf[2*i], atf[2*i+1]);
    const __half2 ns2 = __float2half2_rn(NSLOPE);

    float l = 0.f;
    __half2 acc2[8];
    #pragma unroll
    for (int i = 0; i < 8; ++i) acc2[i] = __float2half2_rn(0.f);

    int beg = rs[dcl], end = valid ? rs[dcl+1] : beg;
    int p = beg + r;
    for (; p + 16 < end; p += 32){
        int s0 = __builtin_nontemporal_load(col + p);
        int s1 = __builtin_nontemporal_load(col + p + 16);
        const uint4* rp0 = (const uint4*)(A16 + (size_t)s0*HC + h*CH);
        const uint4* rp1 = (const uint4*)(A16 + (size_t)s1*HC + h*CH);
        U a, b;
        a.u[0] = rp0[0]; a.u[1] = rp0[1];     // both gathers in flight before use
        b.u[0] = rp1[0]; b.u[1] = rp1[1];
        __half2 sc2 = __float2half2_rn(0.f);
        #pragma unroll
        for (int i = 0; i < 8; ++i){
            __half2 m  = __hadd2(a.h2[i], xr.h2[i]);
            __half2 lk = pkmax2(m, __hmul2(m, ns2));
            sc2 = __hfma2(lk, at2[i], sc2);
        }
        float ex = __expf(__low2float(sc2) + __high2float(sc2));
        l += ex;
        __half2 exh = __float2half2_rn(ex);
        #pragma unroll
        for (int i = 0; i < 8; ++i) acc2[i] = __hfma2(a.h2[i], exh, acc2[i]);

        sc2 = __float2half2_rn(0.f);
        #pragma unroll
        for (int i = 0; i < 8; ++i){
            __half2 m  = __hadd2(b.h2[i], xr.h2[i]);
            __half2 lk = pkmax2(m, __hmul2(m, ns2));
            sc2 = __hfma2(lk, at2[i], sc2);
        }
        ex = __expf(__low2float(sc2) + __high2float(sc2));
        l += ex;
        exh = __float2half2_rn(ex);
        #pragma unroll
        for (int i = 0; i < 8; ++i) acc2[i] = __hfma2(b.h2[i], exh, acc2[i]);
    }
    if (p < end){
        int s = __builtin_nontemporal_load(col + p);
        const uint4* rp = (const uint4*)(A16 + (size_t)s*HC + h*CH);
        U a;
        a.u[0] = rp[0]; a.u[1] = rp[1];
        __half2 sc2 = __float2half2_rn(0.f);
        #pragma unroll
        for (int i = 0; i < 8; ++i){
            __half2 m  = __hadd2(a.h2[i], xr.h2[i]);
            __half2 lk = pkmax2(m, __hmul2(m, ns2));
            sc2 = __hfma2(lk, at2[i], sc2);
        }
        float ex = __expf(__low2float(sc2) + __high2float(sc2));
        l += ex;
        __half2 exh = __float2half2_rn(ex);
        #pragma unroll
        for (int i = 0; i < 8; ++i) acc2[i] = __hfma2(a.h2[i], exh, acc2[i]);
    }

    // channel-splitting halving merge across the 16-lane half.
    __half2 v4[4];
    {
        bool hi = (r & 8) != 0;
        #pragma unroll
        for (int i = 0; i < 4; ++i){
            __half2 send = hi ? acc2[i] : acc2[i+4];
            __half2 recv = sfx2(send, 8);
            v4[i] = __hadd2(hi ? acc2[i+4] : acc2[i], recv);
        }
    }
    __half2 v2[2];
    {
        bool hi = (r & 4) != 0;
        __half2 s0 = hi ? v4[0] : v4[2];
        __half2 s1 = hi ? v4[1] : v4[3];
        __half2 r0 = sfx2(s0, 4);
        __half2 r1 = sfx2(s1, 4);
        v2[0] = __hadd2(hi ? v4[2] : v4[0], r0);
        v2[1] = __hadd2(hi ? v4[3] : v4[1], r1);
    }
    __half2 v1;
    {
        bool hi = (r & 2) != 0;
        __half2 send = hi ? v2[0] : v2[1];
        __half2 recv = sfx2(send, 2);
        v1 = __hadd2(hi ? v2[1] : v2[0], recv);
    }
    float mine;
    {
        bool hi = (r & 1) != 0;
        float lo = __low2float(v1), hf = __high2float(v1);
        float send = hi ? lo : hf;
        float recv = __shfl_xor(send, 1);
        mine = (hi ? hf : lo) + recv;   // lane r owns channel r total
    }
    #pragma unroll
    for (int off = 8; off >= 1; off >>= 1) l += __shfl_xor(l, off);

    float invl = 1.f/(l + 1e-16f);
    float val = mine*invl + bias[h*CH + r];
    val = (val > 0.f) ? val : expm1f(val);

    // ---- block-level dedup, then one device atomic per (graph,channel) ----
    if (lane == 0) sb[sg] = valid ? batch[d] : (-1 - sg);   // unique sentinel
    pool[sg][h*CH + r] = val;                               // own row, plain store
    __syncthreads();
    int myb = sb[sg];
    int first = sg;
    #pragma unroll
    for (int j = 7; j >= 0; --j) if (sb[j] == myb) first = j;
    if (valid && first == sg){
        float s = 0.f;
        #pragma unroll
        for (int j = 0; j < 8; ++j) if (sb[j] == myb) s += pool[j][h*CH + r];
        atomicAdd(&pooled[(size_t)myb*HC + h*CH + r], s);
    }
}

// tiny classifier: mean over graph (counts from gb) + fc + log_softmax
__global__ void k_fc(const float* __restrict__ pooled, const int* __restrict__ gb,
                     const float* __restrict__ Wfc, const float* __restrict__ bfc,
                     float* __restrict__ out, int G){
    int t = threadIdx.x;            // 64 -> two graphs per wave
    int g = blockIdx.x*2 + (t >> 5);
    int c = t & 31;
    if (g >= G) return;
    float cnt = (float)(gb[g+1] - gb[g]);
    if (cnt < 1.f) cnt = 1.f;
    float pv = pooled[g*HC + c] / cnt;
    float p0 = pv * Wfc[c];
    float p1 = pv * Wfc[HC + c];
    #pragma unroll
    for (int off = 16; off >= 1; off >>= 1){
        p0 += __shfl_xor(p0, off, 32);
        p1 += __shfl_xor(p1, off, 32);
    }
    if (c == 0){
        float l0 = p0 + bfc[0], l1 = p1 + bfc[1];
        float m = (l0 > l1) ? l0 : l1;
        float lse = m + logf(__expf(l0 - m) + __expf(l1 - m));
        out[g*2 + 0] = l0 - lse;
        out[g*2 + 1] = l1 - lse;
    }
}

extern "C" void kernel_launch(void* const* d_in, const int* in_sizes, int n_in,
                              void* d_out, int out_size, void* d_ws, size_t ws_size,
                              hipStream_t stream) {
    const int*   ei    = (const int*)  d_in[0];
    const int*   batch = (const int*)  d_in[1];
    const float* rnd   = (const float*)d_in[2];
    const float* W1l   = (const float*)d_in[3];
    const float* b1l   = (const float*)d_in[4];
    const float* W1r   = (const float*)d_in[5];
    const float* b1r   = (const float*)d_in[6];
    const float* att1  = (const float*)d_in[7];
    const float* bias1 = (const float*)d_in[8];
    const float* W2l   = (const float*)d_in[9];
    const float* b2l   = (const float*)d_in[10];
    const float* W2r   = (const float*)d_in[11];
    const float* b2r   = (const float*)d_in[12];
    const float* att2  = (const float*)d_in[13];
    const float* bias2 = (const float*)d_in[14];
    const float* Wfc   = (const float*)d_in[15];
    const float* bfc   = (const float*)d_in[16];

    const int E  = in_sizes[0] / 2;
    const int N  = in_sizes[1];
    const int G  = out_size / 2;
    const int EP = E + N;                    // pairs (edges + self-loops)
    const int NB2 = (N + 127) >> 7;          // 128-node coarse buckets
    const int halfN = (((N + 1) >> 1) + 1) & ~1;   // even half-range
    const int nWloc = halfN >> 1;            // packed u16 words per half

    // workspace layout. Liveness-based aliasing:
    //   hb (12.8MB, hsrc->mid) and part (NB2*CBMAX*4 <= 12.6MB, mid->fine)
    //   alias [0 .. 12.8MB): A16/B16 written strictly after both die.
    //   dr/rs/col above the hb region; degS+ctrl above those.
    float* ws        = (float*)d_ws;
    __half* A16      = (__half*)ws;             // N*HC halfs
    __half* B16      = A16 + (size_t)N*HC;      // N*HC halfs
    unsigned* hb     = (unsigned*)ws;           // NSL*2 * nWloc words
    unsigned* part   = (unsigned*)ws;           // NB2*CBMAX u32 (fixed-capacity)
    size_t off       = (size_t)NSL*2*nWloc;     // words consumed by hb
    if (off < (size_t)NB2*CBMAX) off = (size_t)NB2*CBMAX;
    if (off < (size_t)N*HC)      off = (size_t)N*HC;
    off = (off + 1) & ~(size_t)1;
    float2* dr       = (float2*)(ws + off);     // N float2 (deg, rnd)
    int*   rs        = (int*)(dr + N);          // N+1
    int*   col       = rs + N + 1;              // EP
    unsigned* degS   = (unsigned*)(col + EP);   // 2*nWloc words (packed u16)
    unsigned* gPair  = degS + 2*nWloc;          // NB2MAX
    float* pooled    = (float*)(gPair + NB2MAX);// G*HC
    int*   partBase  = (int*)(pooled + (size_t)G*HC);  // NB2MAX
    int*   gcur      = partBase + NB2MAX;       // NB2MAX
    int*   gb        = gcur + NB2MAX;           // G+1
    float4* tabA     = (float4*)((((size_t)(gb + G + 1)) + 15) & ~(size_t)15);
    float4* tabB     = tabA + HC;

    const int T = 256;
    const int gD16 = (N + (T>>4) - 1)/(T>>4);   // 16-lane-per-dst subgroups (layer 1)
    const int gD32 = (N + (T>>5) - 1)/(T>>5);   // 32-lane-per-dst subgroups (layer 2)
    const int nTiles = (EP + TILE - 1)/TILE;
    const int nHred  = (2*nWloc*HGRP + T-1)/T;

    // degS + gPair + pooled adjacent: one memset zeroes all three
    (void)hipMemsetAsync(degS, 0, (size_t)(2*nWloc + NB2MAX + (size_t)G*HC)*sizeof(unsigned), stream);

    // ---- degree + CSR build ----
    k_hsrc<<<NSL*2, 512, 0, stream>>>(ei, E, halfN, hb, gPair, gcur);
    k_mid <<<nTiles + nHred + 1, T, 0, stream>>>(ei, E, EP, gcur, part,
                                   hb, degS, nWloc, batch, gb, N, G, nTiles, nHred,
                                   gPair, partBase, rs + N, NB2,
                                   W1l, b1l, W1r, b1r, att1, bias1, tabA, tabB);
    k_fine<<<NB2, T, 0, stream>>>(part, partBase, gPair, degS, rnd, rs, dr, col, N);

    // ---- layer 1 fused with layer-2 projection (A16/B16; X never materialized) ----
    k_gat1<<<gD16, T, 0, stream>>>(rs, col, dr, tabA, tabB,
                                   W2l, b2l, W2r, b2r, A16, B16, N);

    // ---- layer 2 fused with mean-pool accumulation ----
    k_gat <<<gD32, T, 0, stream>>>(rs, col, A16, B16, att2, bias2, batch, pooled, N);

    // ---- tiny classifier ----
    k_fc  <<<(G + 1)/2, 64, 0, stream>>>(pooled, gb, Wfc, bfc, (float*)d_out, G);
}

// Round 8
// 201.322 us; speedup vs baseline: 1.3000x; 1.0543x over previous
//
#include <hip/hip_runtime.h>
#include <hip/hip_fp16.h>
#include <math.h>

#define HC 32      // H*C
#define CH 16      // channels per head
#define NSLOPE 0.2f
#define NB2MAX 512 // max coarse buckets (128 nodes each; N <= 65536)
#define TILE 8192
#define CBMAX 5120 // fixed per-bucket capacity (mean ~4220, +14 sigma)
#define NSL 64     // edge slices for src histogram (merged launch: no 1/CU need)
#define HGRP 8     // slice groups for hred (NSL % HGRP == 0)
#define HLDS 12544 // LDS words per half-range histogram (supports halfN <= 25088)

// pair entry: (dst<<16) | src ; self pairs appended
__device__ __forceinline__ unsigned gen_pair(const int* __restrict__ ei, int E, int i){
    if (i < E) return (unsigned(ei[E+i]) << 16) | unsigned(ei[i]);
    unsigned n = i - E; return (n << 16) | n;
}

// packed fp16 max (ROCm 7.2 header lacks __hmax2)
__device__ __forceinline__ __half2 pkmax2(__half2 a, __half2 b){
    union { __half2 h; unsigned u; } ua, ub, ud;
    ua.h = a; ub.h = b;
    asm("v_pk_max_f16 %0, %1, %2" : "=v"(ud.u) : "v"(ua.u), "v"(ub.u));
    return ud.h;
}

__device__ __forceinline__ __half2 sfx2(__half2 x, int off){
    union { __half2 h; int i; } u; u.h = x;
    u.i = __shfl_xor(u.i, off);
    return u.h;
}

// FRONT stage, role-split by blockIdx (both roles depend only on ei; on a
// captured graph separate launches would serialize ~25+28us — merged they
// overlap across the CU array):
//   blocks [0, NSL*2)            : src-degree LDS histogram + coarse dst hist
//   blocks [NSL*2, NSL*2+nTiles) : p2 counting sort into fixed-capacity part
//                                  (gcur memset-zeroed; offsets bucket-relative)
// Shared memory manually overlaid (59392B union).
__global__ __launch_bounds__(512) void k_front(const int* __restrict__ ei, int E, int EP,
                        int halfN, unsigned* __restrict__ hb, unsigned* __restrict__ gPair,
                        int* __restrict__ gcur, unsigned* __restrict__ part){
    __shared__ unsigned smem[14848];   // 59392 B
    int t = threadIdx.x;               // 512
    int blk = blockIdx.x;

    if (blk < NSL*2){
        // ---------------- hsrc role ----------------
        unsigned* h  = smem;           // HLDS words
        unsigned* hp = smem + HLDS;    // NB2MAX words
        int nWloc = halfN >> 1;
        for (int i = t; i < nWloc; i += 512) h[i] = 0;
        int p = blk & 1;
        if (p == 0){ hp[t] = 0; hp[t] = 0; }
        __syncthreads();
        int slice = blk >> 1;
        int base  = p * halfN;
        int chunk = (((E + NSL - 1) / NSL) + 3) & ~3;   // 4-aligned slice start
        int lo = slice*chunk, hi = lo + chunk; if (hi > E) hi = E;
        bool v4 = ((E & 3) == 0);
        if (v4 && lo < hi){
            int m4 = lo + ((hi - lo) & ~3);
            for (int i = lo + 4*t; i + 3 < hi; i += 4*512){
                int4 s4 = *(const int4*)(ei + i);
                int a0 = s4.x - base, a1 = s4.y - base, a2 = s4.z - base, a3 = s4.w - base;
                if ((unsigned)a0 < (unsigned)halfN) atomicAdd(&h[a0 >> 1], 1u << (16*(a0 & 1)));
                if ((unsigned)a1 < (unsigned)halfN) atomicAdd(&h[a1 >> 1], 1u << (16*(a1 & 1)));
                if ((unsigned)a2 < (unsigned)halfN) atomicAdd(&h[a2 >> 1], 1u << (16*(a2 & 1)));
                if ((unsigned)a3 < (unsigned)halfN) atomicAdd(&h[a3 >> 1], 1u << (16*(a3 & 1)));
                if (p == 0){
                    int4 d4 = *(const int4*)(ei + E + i);
                    atomicAdd(&hp[unsigned(d4.x) >> 7], 1u);
                    atomicAdd(&hp[unsigned(d4.y) >> 7], 1u);
                    atomicAdd(&hp[unsigned(d4.z) >> 7], 1u);
                    atomicAdd(&hp[unsigned(d4.w) >> 7], 1u);
                }
            }
            for (int i = m4 + t; i < hi; i += 512){
                int s = ei[i] - base;
                if ((unsigned)s < (unsigned)halfN) atomicAdd(&h[s >> 1], 1u << (16*(s & 1)));
                if (p == 0) atomicAdd(&hp[unsigned(ei[E+i]) >> 7], 1u);
            }
        } else {
            for (int i = lo + t; i < hi; i += 512){
                int s = ei[i] - base;
                if ((unsigned)s < (unsigned)halfN) atomicAdd(&h[s >> 1], 1u << (16*(s & 1)));
                if (p == 0) atomicAdd(&hp[unsigned(ei[E+i]) >> 7], 1u);
            }
        }
        __syncthreads();
        unsigned* out = hb + (size_t)blk * nWloc;
        for (int w = t; w < nWloc; w += 512) out[w] = h[w];
        if (p == 0 && hp[t]) atomicAdd(&gPair[t], hp[t]);
    } else {
        // ---------------- p2 role: LDS counting sort (bucket = e>>23) ----------------
        int* bcnt   = (int*)smem;              // 512
        int* bstart = bcnt + 512;              // 512
        int* c2     = bstart + 512;            // 512
        int* gpos   = c2 + 512;                // 512
        int* sc     = gpos + 512;              // 512
        unsigned* sorted = (unsigned*)(sc + 512);          // TILE
        unsigned short* bktof = (unsigned short*)(sorted + TILE);  // TILE ushort
        int tile = blk - NSL*2;
        int base = tile * TILE;
        int cnt = EP - base; if (cnt > TILE) cnt = TILE;
        bool full = (cnt == TILE);
        bcnt[t] = 0; c2[t] = 0;
        __syncthreads();
        unsigned ec[TILE/512];
        if (full){
            #pragma unroll
            for (int q = 0; q < TILE/512; ++q)
                ec[q] = gen_pair(ei, E, base + t + q*512);
            #pragma unroll
            for (int q = 0; q < TILE/512; ++q)
                atomicAdd(&bcnt[ec[q] >> 23], 1);
        } else {
            for (int j = t; j < cnt; j += 512){
                unsigned e = gen_pair(ei, E, base + j);
                atomicAdd(&bcnt[e >> 23], 1);
            }
        }
        __syncthreads();
        int v = bcnt[t];
        sc[t] = v;
        __syncthreads();
        for (int d = 1; d < 512; d <<= 1){
            int x = (t >= d) ? sc[t-d] : 0;
            __syncthreads();
            sc[t] += x;
            __syncthreads();
        }
        int excl = sc[t] - v;
        bstart[t] = excl;
        if (v > 0){
            gpos[t] = atomicAdd(&gcur[t], v);   // bucket-relative (gcur zeroed)
            for (int j = 0; j < v; ++j) bktof[excl + j] = (unsigned short)t;
        }
        __syncthreads();
        if (full){
            #pragma unroll
            for (int q = 0; q < TILE/512; ++q){
                unsigned e = ec[q];
                int b = e >> 23;
                int off = atomicAdd(&c2[b], 1);
                sorted[bstart[b] + off] = e;
            }
        } else {
            for (int j = t; j < cnt; j += 512){
                unsigned e = gen_pair(ei, E, base + j);
                int b = e >> 23;
                int off = atomicAdd(&c2[b], 1);
                sorted[bstart[b] + off] = e;
            }
        }
        __syncthreads();
        for (int k = t; k < cnt; k += 512){
            int b = bktof[k];
            int rel = gpos[b] + (k - bstart[b]);
            if (rel < CBMAX) part[(size_t)b*CBMAX + rel] = sorted[k];
        }
    }
}

// BACK stage: hred slice-copy reduction + graph bounds (blocks < nHred) and
// setup (self counts, scan -> partBase, weight pack; last block).
__global__ void k_back(const unsigned* __restrict__ hb, unsigned* __restrict__ degS,
                       int nWloc, const int* __restrict__ batch, int* __restrict__ gb,
                       int N, int G, int nHred,
                       unsigned* __restrict__ gPair, int* __restrict__ partBase,
                       int* __restrict__ rsN, int EP, int nb,
                       const float* __restrict__ W1l, const float* __restrict__ b1l,
                       const float* __restrict__ W1r, const float* __restrict__ b1r,
                       const float* __restrict__ att1, const float* __restrict__ bias1,
                       float4* __restrict__ tabA, float4* __restrict__ tabB){
    __shared__ int sc[256];
    int t = threadIdx.x;   // 256
    int blk = blockIdx.x;
    if (blk < nHred){
        int idx = blk*256 + t;
        if (idx <= G){
            int lo = 0, hi = N;
            while (lo < hi){ int mid = (lo+hi)>>1; if (batch[mid] < idx) lo = mid+1; else hi = mid; }
            gb[idx] = lo;
        }
        int total = 2*nWloc;
        int grp = idx / total;
        if (grp < HGRP){
            int rem = idx - grp*total;
            int p = (rem < nWloc) ? 0 : 1;
            int w = rem - p*nWloc;
            unsigned s = 0;
            int sl0 = grp*(NSL/HGRP), sl1 = sl0 + NSL/HGRP;
            for (int sl = sl0; sl < sl1; ++sl)
                s += hb[(size_t)(sl*2 + p)*nWloc + w];
            if (s) atomicAdd(&degS[rem], s);
        }
    } else {
        // setup role: self counts + pair-scan + weight pack
        int vp0 = 0, vp1 = 0;
        int b0 = 2*t, b1 = 2*t + 1;
        if (b0 < nb){
            int selfc = N - b0*128;
            selfc = (selfc < 0) ? 0 : (selfc > 128 ? 128 : selfc);
            vp0 = (int)gPair[b0] + selfc;
            gPair[b0] = (unsigned)vp0;
        }
        if (b1 < nb){
            int selfc = N - b1*128;
            selfc = (selfc < 0) ? 0 : (selfc > 128 ? 128 : selfc);
            vp1 = (int)gPair[b1] + selfc;
            gPair[b1] = (unsigned)vp1;
        }
        int s = vp0 + vp1;
        sc[t] = s;
        __syncthreads();
        for (int d = 1; d < 256; d <<= 1){
            int x = (t >= d) ? sc[t-d] : 0;
            __syncthreads();
            sc[t] += x;
            __syncthreads();
        }
        int excl = sc[t] - s;
        if (b0 < nb) partBase[b0] = excl;
        if (b1 < nb) partBase[b1] = excl + vp0;
        if (t == 0) rsN[0] = EP;
        if (t < HC){
            tabA[t] = make_float4(W1l[t*3] + b1l[t], W1l[t*3+1], W1l[t*3+2], att1[t]);
            tabB[t] = make_float4(W1r[t*3] + b1r[t], W1r[t*3+1], W1r[t*3+2], bias1[t]);
        }
    }
}

// fine pass: one block per 128-node bucket -> rs, (deg,rnd), col (dense,
// coalesced out). part read at FIXED base b*CBMAX; col dense via partBase.
__global__ void k_fine(const unsigned* __restrict__ part, const int* __restrict__ partBase,
                       const unsigned* __restrict__ gPair,
                       const unsigned* __restrict__ degS, const float* __restrict__ rnd,
                       int* __restrict__ rs, float2* __restrict__ dr,
                       int* __restrict__ col, int N){
    __shared__ int pcnt[128], c2[128], lrs[129], sc[128];
    __shared__ int colbuf[CBMAX];
    int b = blockIdx.x, t = threadIdx.x;   // 256
    int np = (int)gPair[b]; if (np > CBMAX) np = CBMAX;
    int beg = b*CBMAX, end = beg + np;
    if (t < 128){ pcnt[t] = 0; c2[t] = 0; }
    __syncthreads();
    for (int k = beg + t; k < end; k += 256)
        atomicAdd(&pcnt[(part[k] >> 16) & 127], 1);
    __syncthreads();
    int v = (t < 128) ? pcnt[t] : 0;
    if (t < 128) sc[t] = v;
    __syncthreads();
    for (int d = 1; d < 128; d <<= 1){
        int x = (t >= d && t < 128) ? sc[t-d] : 0;
        __syncthreads();
        if (t < 128) sc[t] += x;
        __syncthreads();
    }
    if (t < 128){
        lrs[t] = sc[t] - v;
        if (t == 127) lrs[128] = sc[127];
    }
    __syncthreads();
    int n = (b << 7) + t;
    int pb = partBase[b];
    if (t < 128 && n < N){
        rs[n] = pb + lrs[t];
        unsigned s16 = (degS[n >> 1] >> (16*(n & 1))) & 0xFFFFu;
        dr[n] = make_float2((float)(pcnt[t] - 1 + (int)s16), rnd[n]);
    }
    for (int k = beg + t; k < end; k += 256){
        unsigned e = part[k];
        int j = (e >> 16) & 127;
        int pos = lrs[j] + atomicAdd(&c2[j], 1);
        if (pos < CBMAX) colbuf[pos] = (int)(e & 0xFFFFu);
    }
    __syncthreads();
    int npair = lrs[128];
    for (int k = t; k < npair; k += 256) col[pb + k] = colbuf[k];
}

// fused layer-1 GATv2 + layer-2 input projection. Params in LDS (broadcast
// ds_read_b128 per channel); only per-dst base[16] in registers. Projection
// weights pre-packed float4. (Round-6 proven: VGPR-64 rematerialization fix.)
__global__ void k_gat1(const int* __restrict__ rs, const int* __restrict__ col,
                       const float2* __restrict__ dr,
                       const float4* __restrict__ tabA, const float4* __restrict__ tabB,
                       const float* __restrict__ W2l, const float* __restrict__ b2l,
                       const float* __restrict__ W2r, const float* __restrict__ b2r,
                       __half* __restrict__ A16, __half* __restrict__ B16, int N){
    __shared__ float4 tA[HC], tB[HC];      // layer-1 packed params (512 B)
    __shared__ float4 wq[HC][16];          // packed projection weights (8 KB)
    __shared__ float blS[HC], brS[HC];
    int t = threadIdx.x;                 // 256
    if (t < HC){ tA[t] = tabA[t]; tB[t] = tabB[t]; blS[t] = b2l[t]; brS[t] = b2r[t]; }
    for (int w = t; w < HC*16; w += 256){
        int j = w >> 4, k = w & 15;
        wq[j][k] = make_float4(W2l[(2*k)*HC + j], W2l[(2*k+1)*HC + j],
                               W2r[(2*k)*HC + j], W2r[(2*k+1)*HC + j]);
    }
    __syncthreads();

    int d = blockIdx.x*(blockDim.x >> 4) + (t >> 4);
    if (d >= N) return;
    int lane = t & 15;
    int h = lane >> 3, r = lane & 7;

    float2 drd = dr[d];
    float base[CH];
    #pragma unroll
    for (int c = 0; c < CH; ++c){
        float4 a4 = tA[h*CH + c];
        float4 b4 = tB[h*CH + c];
        float xr = b4.x + b4.y*drd.x + b4.z*drd.y;
        base[c] = a4.x + xr;
    }

    float l = 0.f, S1 = 0.f, S2 = 0.f;
    int beg = rs[d], end = rs[d+1];
    int p = beg + r;
    for (; p + 8 < end; p += 16){
        int s0 = __builtin_nontemporal_load(col + p);
        int s1 = __builtin_nontemporal_load(col + p + 8);
        float2 da = dr[s0];
        float2 db = dr[s1];
        float sc0 = 0.f, sc1 = 0.f;
        #pragma unroll
        for (int c = 0; c < CH; ++c){
            float4 a4 = tA[h*CH + c];
            float m0 = base[c] + a4.y*da.x + a4.z*da.y;
            float m1 = base[c] + a4.y*db.x + a4.z*db.y;
            m0 = (m0 > 0.f) ? m0 : NSLOPE*m0;
            m1 = (m1 > 0.f) ? m1 : NSLOPE*m1;
            sc0 += m0 * a4.w;
            sc1 += m1 * a4.w;
        }
        float ex0 = __expf(sc0), ex1 = __expf(sc1);
        l  += ex0 + ex1;
        S1 += ex0*da.x + ex1*db.x;
        S2 += ex0*da.y + ex1*db.y;
    }
    if (p < end){
        float2 ds = dr[__builtin_nontemporal_load(col + p)];
        float sc = 0.f;
        #pragma unroll
        for (int c = 0; c < CH; ++c){
            float4 a4 = tA[h*CH + c];
            float mm = base[c] + a4.y*ds.x + a4.z*ds.y;
            mm = (mm > 0.f) ? mm : NSLOPE*mm;
            sc += mm * a4.w;
        }
        float ex = __expf(sc);
        l  += ex;
        S1 += ex*ds.x;
        S2 += ex*ds.y;
    }

    #pragma unroll
    for (int off = 4; off >= 1; off >>= 1){
        l  += __shfl_xor(l,  off);
        S1 += __shfl_xor(S1, off);
        S2 += __shfl_xor(S2, off);
    }

    // layer-1 output channels 2*lane, 2*lane+1 (ELU'd), in-register
    float invl = 1.f/(l + 1e-16f);
    int c0 = r*2;
    float4 a40 = tA[h*CH + c0],     b40 = tB[h*CH + c0];
    float4 a41 = tA[h*CH + c0 + 1], b41 = tB[h*CH + c0 + 1];
    float v0 = a40.x + (a40.y*S1 + a40.z*S2)*invl + b40.w;
    float v1 = a41.x + (a41.y*S1 + a41.z*S2)*invl + b41.w;
    float x0 = (v0 > 0.f) ? v0 : expm1f(v0);
    float x1 = (v1 > 0.f) ? v1 : expm1f(v1);

    // in-subgroup 32x32 projection: out[k] = b[k] + sum_j x[j]*W[k][j]
    int k0 = 2*lane;
    float a0 = blS[k0], a1 = blS[k0+1];
    float g0 = brS[k0], g1 = brS[k0+1];
    #pragma unroll
    for (int tt = 0; tt < 16; ++tt){
        float xa = __shfl(x0, tt, 16);     // x[2*tt]
        float xb = __shfl(x1, tt, 16);     // x[2*tt+1]
        int j = 2*tt;
        float4 q0 = wq[j][lane];
        float4 q1 = wq[j+1][lane];
        a0 += xa*q0.x + xb*q1.x;
        a1 += xa*q0.y + xb*q1.y;
        g0 += xa*q0.z + xb*q1.z;
        g1 += xa*q0.w + xb*q1.w;
    }
    *(__half2*)(A16 + (size_t)d*HC + k0) = __floats2half2_rn(a0, a1);
    *(__half2*)(B16 + (size_t)d*HC + k0) = __floats2half2_rn(g0, g1);
}

// fused layer-2 GATv2 + mean-pool accumulation: head-paired 32-lane subgroup
// per dst; two-way edge loop (proven); packed fp16 math; channel-splitting
// halving merge; per-block LDS pool dedup -> ~8x fewer device atomics.
__global__ void k_gat(const int* __restrict__ rs, const int* __restrict__ col,
                      const __half* __restrict__ A16, const __half* __restrict__ B16,
                      const float* __restrict__ att, const float* __restrict__ bias,
                      const int* __restrict__ batch, float* __restrict__ pooled, int N){
    __shared__ float pool[8][HC];
    __shared__ int sb[8];
    int sg = threadIdx.x >> 5;
    int d = blockIdx.x*(blockDim.x >> 5) + sg;
    int lane = threadIdx.x & 31;
    bool valid = (d < N);
    int dcl = valid ? d : 0;
    int h = lane >> 4, r = lane & 15;

    union U { uint4 u[2]; __half2 h2[8]; };
    U xr;
    {
        const uint4* bp = (const uint4*)(B16 + (size_t)dcl*HC + h*CH);
        xr.u[0] = bp[0]; xr.u[1] = bp[1];
    }
    __half2 at2[8];
    const float* atf = att + h*CH;
    #pragma unroll
    for (int i = 0; i < 8; ++i) at2[i] = __floats2half2_rn(atf[2*i], atf[2*i+1]);
    const __half2 ns2 = __float2half2_rn(NSLOPE);

    float l = 0.f;
    __half2 acc2[8];
    #pragma unroll
    for (int i = 0; i < 8; ++i) acc2[i] = __float2half2_rn(0.f);

    int beg = rs[dcl], end = valid ? rs[dcl+1] : beg;
    int p = beg + r;
    for (; p + 16 < end; p += 32){
        int s0 = __builtin_nontemporal_load(col + p);
        int s1 = __builtin_nontemporal_load(col + p + 16);
        const uint4* rp0 = (const uint4*)(A16 + (size_t)s0*HC + h*CH);
        const uint4* rp1 = (const uint4*)(A16 + (size_t)s1*HC + h*CH);
        U a, b;
        a.u[0] = rp0[0]; a.u[1] = rp0[1];     // both gathers in flight before use
        b.u[0] = rp1[0]; b.u[1] = rp1[1];
        __half2 sc2 = __float2half2_rn(0.f);
        #pragma unroll
        for (int i = 0; i < 8; ++i){
            __half2 m  = __hadd2(a.h2[i], xr.h2[i]);
            __half2 lk = pkmax2(m, __hmul2(m, ns2));
            sc2 = __hfma2(lk, at2[i], sc2);
        }
        float ex = __expf(__low2float(sc2) + __high2float(sc2));
        l += ex;
        __half2 exh = __float2half2_rn(ex);
        #pragma unroll
        for (int i = 0; i < 8; ++i) acc2[i] = __hfma2(a.h2[i], exh, acc2[i]);

        sc2 = __float2half2_rn(0.f);
        #pragma unroll
        for (int i = 0; i < 8; ++i){
            __half2 m  = __hadd2(b.h2[i], xr.h2[i]);
            __half2 lk = pkmax2(m, __hmul2(m, ns2));
            sc2 = __hfma2(lk, at2[i], sc2);
        }
        ex = __expf(__low2float(sc2) + __high2float(sc2));
        l += ex;
        exh = __float2half2_rn(ex);
        #pragma unroll
        for (int i = 0; i < 8; ++i) acc2[i] = __hfma2(b.h2[i], exh, acc2[i]);
    }
    if (p < end){
        int s = __builtin_nontemporal_load(col + p);
        const uint4* rp = (const uint4*)(A16 + (size_t)s*HC + h*CH);
        U a;
        a.u[0] = rp[0]; a.u[1] = rp[1];
        __half2 sc2 = __float2half2_rn(0.f);
        #pragma unroll
        for (int i = 0; i < 8; ++i){
            __half2 m  = __hadd2(a.h2[i], xr.h2[i]);
            __half2 lk = pkmax2(m, __hmul2(m, ns2));
            sc2 = __hfma2(lk, at2[i], sc2);
        }
        float ex = __expf(__low2float(sc2) + __high2float(sc2));
        l += ex;
        __half2 exh = __float2half2_rn(ex);
        #pragma unroll
        for (int i = 0; i < 8; ++i) acc2[i] = __hfma2(a.h2[i], exh, acc2[i]);
    }

    // channel-splitting halving merge across the 16-lane half.
    __half2 v4[4];
    {
        bool hi = (r & 8) != 0;
        #pragma unroll
        for (int i = 0; i < 4; ++i){
            __half2 send = hi ? acc2[i] : acc2[i+4];
            __half2 recv = sfx2(send, 8);
            v4[i] = __hadd2(hi ? acc2[i+4] : acc2[i], recv);
        }
    }
    __half2 v2[2];
    {
        bool hi = (r & 4) != 0;
        __half2 s0 = hi ? v4[0] : v4[2];
        __half2 s1 = hi ? v4[1] : v4[3];
        __half2 r0 = sfx2(s0, 4);
        __half2 r1 = sfx2(s1, 4);
        v2[0] = __hadd2(hi ? v4[2] : v4[0], r0);
        v2[1] = __hadd2(hi ? v4[3] : v4[1], r1);
    }
    __half2 v1;
    {
        bool hi = (r & 2) != 0;
        __half2 send = hi ? v2[0] : v2[1];
        __half2 recv = sfx2(send, 2);
        v1 = __hadd2(hi ? v2[1] : v2[0], recv);
    }
    float mine;
    {
        bool hi = (r & 1) != 0;
        float lo = __low2float(v1), hf = __high2float(v1);
        float send = hi ? lo : hf;
        float recv = __shfl_xor(send, 1);
        mine = (hi ? hf : lo) + recv;   // lane r owns channel r total
    }
    #pragma unroll
    for (int off = 8; off >= 1; off >>= 1) l += __shfl_xor(l, off);

    float invl = 1.f/(l + 1e-16f);
    float val = mine*invl + bias[h*CH + r];
    val = (val > 0.f) ? val : expm1f(val);

    // ---- block-level dedup, then one device atomic per (graph,channel) ----
    if (lane == 0) sb[sg] = valid ? batch[d] : (-1 - sg);   // unique sentinel
    pool[sg][h*CH + r] = val;                               // own row, plain store
    __syncthreads();
    int myb = sb[sg];
    int first = sg;
    #pragma unroll
    for (int j = 7; j >= 0; --j) if (sb[j] == myb) first = j;
    if (valid && first == sg){
        float s = 0.f;
        #pragma unroll
        for (int j = 0; j < 8; ++j) if (sb[j] == myb) s += pool[j][h*CH + r];
        atomicAdd(&pooled[(size_t)myb*HC + h*CH + r], s);
    }
}

// tiny classifier: mean over graph (counts from gb) + fc + log_softmax
__global__ void k_fc(const float* __restrict__ pooled, const int* __restrict__ gb,
                     const float* __restrict__ Wfc, const float* __restrict__ bfc,
                     float* __restrict__ out, int G){
    int t = threadIdx.x;            // 64 -> two graphs per wave
    int g = blockIdx.x*2 + (t >> 5);
    int c = t & 31;
    if (g >= G) return;
    float cnt = (float)(gb[g+1] - gb[g]);
    if (cnt < 1.f) cnt = 1.f;
    float pv = pooled[g*HC + c] / cnt;
    float p0 = pv * Wfc[c];
    float p1 = pv * Wfc[HC + c];
    #pragma unroll
    for (int off = 16; off >= 1; off >>= 1){
        p0 += __shfl_xor(p0, off, 32);
        p1 += __shfl_xor(p1, off, 32);
    }
    if (c == 0){
        float l0 = p0 + bfc[0], l1 = p1 + bfc[1];
        float m = (l0 > l1) ? l0 : l1;
        float lse = m + logf(__expf(l0 - m) + __expf(l1 - m));
        out[g*2 + 0] = l0 - lse;
        out[g*2 + 1] = l1 - lse;
    }
}

extern "C" void kernel_launch(void* const* d_in, const int* in_sizes, int n_in,
                              void* d_out, int out_size, void* d_ws, size_t ws_size,
                              hipStream_t stream) {
    const int*   ei    = (const int*)  d_in[0];
    const int*   batch = (const int*)  d_in[1];
    const float* rnd   = (const float*)d_in[2];
    const float* W1l   = (const float*)d_in[3];
    const float* b1l   = (const float*)d_in[4];
    const float* W1r   = (const float*)d_in[5];
    const float* b1r   = (const float*)d_in[6];
    const float* att1  = (const float*)d_in[7];
    const float* bias1 = (const float*)d_in[8];
    const float* W2l   = (const float*)d_in[9];
    const float* b2l   = (const float*)d_in[10];
    const float* W2r   = (const float*)d_in[11];
    const float* b2r   = (const float*)d_in[12];
    const float* att2  = (const float*)d_in[13];
    const float* bias2 = (const float*)d_in[14];
    const float* Wfc   = (const float*)d_in[15];
    const float* bfc   = (const float*)d_in[16];

    const int E  = in_sizes[0] / 2;
    const int N  = in_sizes[1];
    const int G  = out_size / 2;
    const int EP = E + N;                    // pairs (edges + self-loops)
    const int NB2 = (N + 127) >> 7;          // 128-node coarse buckets
    const int halfN = (((N + 1) >> 1) + 1) & ~1;   // even half-range
    const int nWloc = halfN >> 1;            // packed u16 words per half

    // workspace layout. hb and part are now SIMULTANEOUSLY live (k_front) so
    // they no longer alias each other; A16/B16 alias the hb region (written
    // only after k_back). dr/rs/col above part; degS+ctrl above those.
    float* ws        = (float*)d_ws;
    __half* A16      = (__half*)ws;             // N*HC halfs
    __half* B16      = A16 + (size_t)N*HC;      // N*HC halfs
    unsigned* hb     = (unsigned*)ws;           // NSL*2*nWloc words
    size_t off1      = (size_t)NSL*2*nWloc;
    if (off1 < (size_t)N*HC) off1 = (size_t)N*HC;   // cover A16+B16
    unsigned* part   = (unsigned*)ws + off1;    // NB2*CBMAX u32 (fixed-capacity)
    size_t off2      = off1 + (size_t)NB2*CBMAX;
    off2 = (off2 + 1) & ~(size_t)1;
    float2* dr       = (float2*)(ws + off2);    // N float2 (deg, rnd)
    int*   rs        = (int*)(dr + N);          // N+1
    int*   col       = rs + N + 1;              // EP
    unsigned* degS   = (unsigned*)(col + EP);   // 2*nWloc words (packed u16) [zeroed]
    unsigned* gPair  = degS + 2*nWloc;          // NB2MAX                     [zeroed]
    float* pooled    = (float*)(gPair + NB2MAX);// G*HC                       [zeroed]
    int*   gcur      = (int*)(pooled + (size_t)G*HC);  // NB2MAX              [zeroed]
    int*   partBase  = gcur + NB2MAX;           // NB2MAX
    int*   gb        = partBase + NB2MAX;       // G+1
    float4* tabA     = (float4*)((((size_t)(gb + G + 1)) + 15) & ~(size_t)15);
    float4* tabB     = tabA + HC;

    const int T = 256;
    const int gD16 = (N + (T>>4) - 1)/(T>>4);   // 16-lane-per-dst subgroups (layer 1)
    const int gD32 = (N + (T>>5) - 1)/(T>>5);   // 32-lane-per-dst subgroups (layer 2)
    const int nTiles = (EP + TILE - 1)/TILE;
    const int nHred  = (2*nWloc*HGRP + T-1)/T;

    // degS + gPair + pooled + gcur adjacent: one memset zeroes all four
    (void)hipMemsetAsync(degS, 0,
        (size_t)(2*nWloc + NB2MAX + (size_t)G*HC + NB2MAX)*sizeof(unsigned), stream);

    // ---- CSR build: front (hsrc ∥ p2), back (hred + setup), fine ----
    k_front<<<NSL*2 + nTiles, 512, 0, stream>>>(ei, E, EP, halfN, hb, gPair, gcur, part);
    k_back <<<nHred + 1, T, 0, stream>>>(hb, degS, nWloc, batch, gb, N, G, nHred,
                                   gPair, partBase, rs + N, EP, NB2,
                                   W1l, b1l, W1r, b1r, att1, bias1, tabA, tabB);
    k_fine <<<NB2, T, 0, stream>>>(part, partBase, gPair, degS, rnd, rs, dr, col, N);

    // ---- layer 1 fused with layer-2 projection (A16/B16; X never materialized) ----
    k_gat1<<<gD16, T, 0, stream>>>(rs, col, dr, tabA, tabB,
                                   W2l, b2l, W2r, b2r, A16, B16, N);

    // ---- layer 2 fused with mean-pool accumulation ----
    k_gat <<<gD32, T, 0, stream>>>(rs, col, A16, B16, att2, bias2, batch, pooled, N);

    // ---- tiny classifier ----
    k_fc  <<<(G + 1)/2, 64, 0, stream>>>(pooled, gb, Wfc, bfc, (float*)d_out, G);
}

// Round 10
// 200.985 us; speedup vs baseline: 1.3022x; 1.0017x over previous
//
#include <hip/hip_runtime.h>
#include <hip/hip_fp16.h>
#include <math.h>

#define HC 32      // H*C
#define CH 16      // channels per head
#define NSLOPE 0.2f
#define NB2MAX 512 // max coarse buckets (128 nodes each; N <= 65536)
#define TILE 8192
#define CBMAX 5120 // fixed per-bucket capacity (mean ~4220, +14 sigma)
#define NSL 64     // edge slices for src histogram (merged launch: no 1/CU need)
#define HLDS 12544 // LDS words per half-range histogram (supports halfN <= 25088)

// pair entry: (dst<<16) | src ; self pairs appended
__device__ __forceinline__ unsigned gen_pair(const int* __restrict__ ei, int E, int i){
    if (i < E) return (unsigned(ei[E+i]) << 16) | unsigned(ei[i]);
    unsigned n = i - E; return (n << 16) | n;
}

// packed fp16 max (ROCm 7.2 header lacks __hmax2)
__device__ __forceinline__ __half2 pkmax2(__half2 a, __half2 b){
    union { __half2 h; unsigned u; } ua, ub, ud;
    ua.h = a; ub.h = b;
    asm("v_pk_max_f16 %0, %1, %2" : "=v"(ud.u) : "v"(ua.u), "v"(ub.u));
    return ud.h;
}

__device__ __forceinline__ __half2 sfx2(__half2 x, int off){
    union { __half2 h; int i; } u; u.h = x;
    u.i = __shfl_xor(u.i, off);
    return u.h;
}

// FRONT stage, role-split by blockIdx (all roles depend only on kernel inputs;
// separate launches would serialize on the captured graph):
//   blocks [0, NSL*2)                   : src-degree LDS histogram + coarse dst hist
//   blocks [NSL*2, NSL*2+nTiles)        : p2 counting sort into fixed-capacity part
//   blocks [NSL*2+nTiles, +nGb)         : per-graph bounds binary searches
// Shared memory manually overlaid (59392B union).
__global__ __launch_bounds__(512) void k_front(const int* __restrict__ ei, int E, int EP,
                        int halfN, unsigned* __restrict__ hb, unsigned* __restrict__ gPair,
                        int* __restrict__ gcur, unsigned* __restrict__ part,
                        const int* __restrict__ batch, int* __restrict__ gb,
                        int N, int G, int nTiles){
    __shared__ unsigned smem[14848];   // 59392 B
    int t = threadIdx.x;               // 512
    int blk = blockIdx.x;

    if (blk < NSL*2){
        // ---------------- hsrc role ----------------
        unsigned* h  = smem;           // HLDS words
        unsigned* hp = smem + HLDS;    // NB2MAX words
        int nWloc = halfN >> 1;
        for (int i = t; i < nWloc; i += 512) h[i] = 0;
        int p = blk & 1;
        if (p == 0) hp[t] = 0;
        __syncthreads();
        int slice = blk >> 1;
        int base  = p * halfN;
        int chunk = (((E + NSL - 1) / NSL) + 3) & ~3;   // 4-aligned slice start
        int lo = slice*chunk, hi = lo + chunk; if (hi > E) hi = E;
        bool v4 = ((E & 3) == 0);
        if (v4 && lo < hi){
            int m4 = lo + ((hi - lo) & ~3);
            for (int i = lo + 4*t; i + 3 < hi; i += 4*512){
                int4 s4 = *(const int4*)(ei + i);
                int a0 = s4.x - base, a1 = s4.y - base, a2 = s4.z - base, a3 = s4.w - base;
                if ((unsigned)a0 < (unsigned)halfN) atomicAdd(&h[a0 >> 1], 1u << (16*(a0 & 1)));
                if ((unsigned)a1 < (unsigned)halfN) atomicAdd(&h[a1 >> 1], 1u << (16*(a1 & 1)));
                if ((unsigned)a2 < (unsigned)halfN) atomicAdd(&h[a2 >> 1], 1u << (16*(a2 & 1)));
                if ((unsigned)a3 < (unsigned)halfN) atomicAdd(&h[a3 >> 1], 1u << (16*(a3 & 1)));
                if (p == 0){
                    int4 d4 = *(const int4*)(ei + E + i);
                    atomicAdd(&hp[unsigned(d4.x) >> 7], 1u);
                    atomicAdd(&hp[unsigned(d4.y) >> 7], 1u);
                    atomicAdd(&hp[unsigned(d4.z) >> 7], 1u);
                    atomicAdd(&hp[unsigned(d4.w) >> 7], 1u);
                }
            }
            for (int i = m4 + t; i < hi; i += 512){
                int s = ei[i] - base;
                if ((unsigned)s < (unsigned)halfN) atomicAdd(&h[s >> 1], 1u << (16*(s & 1)));
                if (p == 0) atomicAdd(&hp[unsigned(ei[E+i]) >> 7], 1u);
            }
        } else {
            for (int i = lo + t; i < hi; i += 512){
                int s = ei[i] - base;
                if ((unsigned)s < (unsigned)halfN) atomicAdd(&h[s >> 1], 1u << (16*(s & 1)));
                if (p == 0) atomicAdd(&hp[unsigned(ei[E+i]) >> 7], 1u);
            }
        }
        __syncthreads();
        unsigned* out = hb + (size_t)blk * nWloc;
        for (int w = t; w < nWloc; w += 512) out[w] = h[w];
        if (p == 0 && hp[t]) atomicAdd(&gPair[t], hp[t]);
    } else if (blk < NSL*2 + nTiles){
        // ---------------- p2 role: LDS counting sort (bucket = e>>23) ----------------
        int* bcnt   = (int*)smem;              // 512
        int* bstart = bcnt + 512;              // 512
        int* c2     = bstart + 512;            // 512
        int* gpos   = c2 + 512;                // 512
        int* sc     = gpos + 512;              // 512
        unsigned* sorted = (unsigned*)(sc + 512);          // TILE
        unsigned short* bktof = (unsigned short*)(sorted + TILE);  // TILE ushort
        int tile = blk - NSL*2;
        int base = tile * TILE;
        int cnt = EP - base; if (cnt > TILE) cnt = TILE;
        bool full = (cnt == TILE);
        bcnt[t] = 0; c2[t] = 0;
        __syncthreads();
        unsigned ec[TILE/512];
        if (full){
            #pragma unroll
            for (int q = 0; q < TILE/512; ++q)
                ec[q] = gen_pair(ei, E, base + t + q*512);
            #pragma unroll
            for (int q = 0; q < TILE/512; ++q)
                atomicAdd(&bcnt[ec[q] >> 23], 1);
        } else {
            for (int j = t; j < cnt; j += 512){
                unsigned e = gen_pair(ei, E, base + j);
                atomicAdd(&bcnt[e >> 23], 1);
            }
        }
        __syncthreads();
        int v = bcnt[t];
        sc[t] = v;
        __syncthreads();
        for (int d = 1; d < 512; d <<= 1){
            int x = (t >= d) ? sc[t-d] : 0;
            __syncthreads();
            sc[t] += x;
            __syncthreads();
        }
        int excl = sc[t] - v;
        bstart[t] = excl;
        if (v > 0){
            gpos[t] = atomicAdd(&gcur[t], v);   // bucket-relative (gcur zeroed)
            for (int j = 0; j < v; ++j) bktof[excl + j] = (unsigned short)t;
        }
        __syncthreads();
        if (full){
            #pragma unroll
            for (int q = 0; q < TILE/512; ++q){
                unsigned e = ec[q];
                int b = e >> 23;
                int off = atomicAdd(&c2[b], 1);
                sorted[bstart[b] + off] = e;
            }
        } else {
            for (int j = t; j < cnt; j += 512){
                unsigned e = gen_pair(ei, E, base + j);
                int b = e >> 23;
                int off = atomicAdd(&c2[b], 1);
                sorted[bstart[b] + off] = e;
            }
        }
        __syncthreads();
        for (int k = t; k < cnt; k += 512){
            int b = bktof[k];
            int rel = gpos[b] + (k - bstart[b]);
            if (rel < CBMAX) part[(size_t)b*CBMAX + rel] = sorted[k];
        }
    } else {
        // ---------------- gb role: per-graph node bounds ----------------
        int idx = (blk - NSL*2 - nTiles)*512 + t;
        if (idx <= G){
            int lo = 0, hi = N;
            while (lo < hi){ int mid = (lo+hi)>>1; if (batch[mid] < idx) lo = mid+1; else hi = mid; }
            gb[idx] = lo;
        }
    }
}

// fine pass: one block per 128-node bucket. Self-contained (no k_back):
//  - partBase via cooperative sum of gPair[0..b-1] (+ closed-form self prefix)
//  - per-node src-degree summed directly from hb's window (hred folded)
//  - rs, (deg,rnd), col (dense, coalesced out)
// RACE FIX (round-9 fault candidate): barrier after the cross-wave read of
// redbuf[0] (pb) and BEFORE redbuf is reused for the degree staging.
__global__ void k_fine(const unsigned* __restrict__ part, const unsigned* __restrict__ hb,
                       const unsigned* __restrict__ gPair, int halfN,
                       const float* __restrict__ rnd,
                       int* __restrict__ rs, float2* __restrict__ dr,
                       int* __restrict__ col, int N, int EP){
    __shared__ int pcnt[128], c2[128], lrs[129], sc[128], sdeg[128], redbuf[256];
    __shared__ int colbuf[CBMAX];
    int b = blockIdx.x, t = threadIdx.x;   // 256
    int nWloc = halfN >> 1;

    // ---- partBase: sum gPair[0..b-1] + min(b*128, N) self-loops before b ----
    int acc = 0;
    for (int j = t; j < b; j += 256) acc += (int)gPair[j];
    redbuf[t] = acc;
    __syncthreads();
    for (int s = 128; s > 0; s >>= 1){
        if (t < s) redbuf[t] += redbuf[t+s];
        __syncthreads();
    }
    int selfpre = b*128; if (selfpre > N) selfpre = N;
    int pb = redbuf[0] + selfpre;
    int selfc = N - b*128; selfc = (selfc < 0) ? 0 : (selfc > 128 ? 128 : selfc);
    int np = (int)gPair[b] + selfc; if (np > CBMAX) np = CBMAX;
    __syncthreads();   // all waves have read redbuf[0] before it is reused below

    // ---- per-node src out-degree from hb (hred folded in); 2 slice-halves ----
    {
        int node = t & 127, half = t >> 7;        // half 0: slices 0..31, half 1: 32..63
        int n = (b << 7) + node;
        unsigned sum = 0;
        if (n < N){
            int pn = (n >= halfN) ? 1 : 0;
            int idx = n - pn*halfN;
            int w = idx >> 1, sh = 16*(idx & 1);
            int sl0 = half*(NSL/2), sl1 = sl0 + NSL/2;
            for (int sl = sl0; sl < sl1; ++sl)
                sum += (hb[(size_t)(sl*2 + pn)*nWloc + w] >> sh) & 0xFFFFu;
        }
        redbuf[t] = (int)sum;
    }
    if (t < 128){ pcnt[t] = 0; c2[t] = 0; }
    __syncthreads();
    if (t < 128) sdeg[t] = redbuf[t] + redbuf[t+128];

    // ---- count in-bucket dsts ----
    int beg = b*CBMAX, end = beg + np;
    __syncthreads();
    for (int k = beg + t; k < end; k += 256)
        atomicAdd(&pcnt[(part[k] >> 16) & 127], 1);
    __syncthreads();
    int v = (t < 128) ? pcnt[t] : 0;
    if (t < 128) sc[t] = v;
    __syncthreads();
    for (int d = 1; d < 128; d <<= 1){
        int x = (t >= d && t < 128) ? sc[t-d] : 0;
        __syncthreads();
        if (t < 128) sc[t] += x;
        __syncthreads();
    }
    if (t < 128){
        lrs[t] = sc[t] - v;
        if (t == 127) lrs[128] = sc[127];
    }
    __syncthreads();
    int n = (b << 7) + t;
    if (t < 128 && n < N){
        rs[n] = pb + lrs[t];
        dr[n] = make_float2((float)(pcnt[t] - 1 + sdeg[t]), rnd[n]);
    }
    if (b == 0 && t == 0) rs[N] = EP;
    for (int k = beg + t; k < end; k += 256){
        unsigned e = part[k];
        int j = (e >> 16) & 127;
        int pos = lrs[j] + atomicAdd(&c2[j], 1);
        if (pos < CBMAX) colbuf[pos] = (int)(e & 0xFFFFu);
    }
    __syncthreads();
    int npair = lrs[128];
    for (int k = t; k < npair; k += 256) col[pb + k] = colbuf[k];
}

// fused layer-1 GATv2 + layer-2 input projection. Params computed into LDS
// directly from raw weights (no tab workspace / setup stage). Only per-dst
// base[16] in registers (round-6 VGPR fix). Projection weights pre-packed f4.
__global__ void k_gat1(const int* __restrict__ rs, const int* __restrict__ col,
                       const float2* __restrict__ dr,
                       const float* __restrict__ W1l, const float* __restrict__ b1l,
                       const float* __restrict__ W1r, const float* __restrict__ b1r,
                       const float* __restrict__ att1, const float* __restrict__ bias1,
                       const float* __restrict__ W2l, const float* __restrict__ b2l,
                       const float* __restrict__ W2r, const float* __restrict__ b2r,
                       __half* __restrict__ A16, __half* __restrict__ B16, int N){
    __shared__ float4 tA[HC], tB[HC];      // layer-1 packed params (512 B)
    __shared__ float4 wq[HC][16];          // packed projection weights (8 KB)
    __shared__ float blS[HC], brS[HC];
    int t = threadIdx.x;                 // 256
    if (t < HC){
        tA[t] = make_float4(W1l[t*3] + b1l[t], W1l[t*3+1], W1l[t*3+2], att1[t]);
        tB[t] = make_float4(W1r[t*3] + b1r[t], W1r[t*3+1], W1r[t*3+2], bias1[t]);
        blS[t] = b2l[t]; brS[t] = b2r[t];
    }
    for (int w = t; w < HC*16; w += 256){
        int j = w >> 4, k = w & 15;
        wq[j][k] = make_float4(W2l[(2*k)*HC + j], W2l[(2*k+1)*HC + j],
                               W2r[(2*k)*HC + j], W2r[(2*k+1)*HC + j]);
    }
    __syncthreads();

    int d = blockIdx.x*(blockDim.x >> 4) + (t >> 4);
    if (d >= N) return;
    int lane = t & 15;
    int h = lane >> 3, r = lane & 7;

    float2 drd = dr[d];
    float base[CH];
    #pragma unroll
    for (int c = 0; c < CH; ++c){
        float4 a4 = tA[h*CH + c];
        float4 b4 = tB[h*CH + c];
        float xr = b4.x + b4.y*drd.x + b4.z*drd.y;
        base[c] = a4.x + xr;
    }

    float l = 0.f, S1 = 0.f, S2 = 0.f;
    int beg = rs[d], end = rs[d+1];
    int p = beg + r;
    for (; p + 8 < end; p += 16){
        int s0 = __builtin_nontemporal_load(col + p);
        int s1 = __builtin_nontemporal_load(col + p + 8);
        float2 da = dr[s0];
        float2 db = dr[s1];
        float sc0 = 0.f, sc1 = 0.f;
        #pragma unroll
        for (int c = 0; c < CH; ++c){
            float4 a4 = tA[h*CH + c];
            float m0 = base[c] + a4.y*da.x + a4.z*da.y;
            float m1 = base[c] + a4.y*db.x + a4.z*db.y;
            m0 = (m0 > 0.f) ? m0 : NSLOPE*m0;
            m1 = (m1 > 0.f) ? m1 : NSLOPE*m1;
            sc0 += m0 * a4.w;
            sc1 += m1 * a4.w;
        }
        float ex0 = __expf(sc0), ex1 = __expf(sc1);
        l  += ex0 + ex1;
        S1 += ex0*da.x + ex1*db.x;
        S2 += ex0*da.y + ex1*db.y;
    }
    if (p < end){
        float2 ds = dr[__builtin_nontemporal_load(col + p)];
        float sc = 0.f;
        #pragma unroll
        for (int c = 0; c < CH; ++c){
            float4 a4 = tA[h*CH + c];
            float mm = base[c] + a4.y*ds.x + a4.z*ds.y;
            mm = (mm > 0.f) ? mm : NSLOPE*mm;
            sc += mm * a4.w;
        }
        float ex = __expf(sc);
        l  += ex;
        S1 += ex*ds.x;
        S2 += ex*ds.y;
    }

    #pragma unroll
    for (int off = 4; off >= 1; off >>= 1){
        l  += __shfl_xor(l,  off);
        S1 += __shfl_xor(S1, off);
        S2 += __shfl_xor(S2, off);
    }

    // layer-1 output channels 2*lane, 2*lane+1 (ELU'd), in-register
    float invl = 1.f/(l + 1e-16f);
    int c0 = r*2;
    float4 a40 = tA[h*CH + c0],     b40 = tB[h*CH + c0];
    float4 a41 = tA[h*CH + c0 + 1], b41 = tB[h*CH + c0 + 1];
    float v0 = a40.x + (a40.y*S1 + a40.z*S2)*invl + b40.w;
    float v1 = a41.x + (a41.y*S1 + a41.z*S2)*invl + b41.w;
    float x0 = (v0 > 0.f) ? v0 : expm1f(v0);
    float x1 = (v1 > 0.f) ? v1 : expm1f(v1);

    // in-subgroup 32x32 projection: out[k] = b[k] + sum_j x[j]*W[k][j]
    int k0 = 2*lane;
    float a0 = blS[k0], a1 = blS[k0+1];
    float g0 = brS[k0], g1 = brS[k0+1];
    #pragma unroll
    for (int tt = 0; tt < 16; ++tt){
        float xa = __shfl(x0, tt, 16);     // x[2*tt]
        float xb = __shfl(x1, tt, 16);     // x[2*tt+1]
        int j = 2*tt;
        float4 q0 = wq[j][lane];
        float4 q1 = wq[j+1][lane];
        a0 += xa*q0.x + xb*q1.x;
        a1 += xa*q0.y + xb*q1.y;
        g0 += xa*q0.z + xb*q1.z;
        g1 += xa*q0.w + xb*q1.w;
    }
    *(__half2*)(A16 + (size_t)d*HC + k0) = __floats2half2_rn(a0, a1);
    *(__half2*)(B16 + (size_t)d*HC + k0) = __floats2half2_rn(g0, g1);
}

// fused layer-2 GATv2 + mean-pool accumulation: head-paired 32-lane subgroup
// per dst; two-way edge loop (proven); packed fp16 math; channel-splitting
// halving merge; per-block LDS pool dedup -> ~8x fewer device atomics.
__global__ void k_gat(const int* __restrict__ rs, const int* __restrict__ col,
                      const __half* __restrict__ A16, const __half* __restrict__ B16,
                      const float* __restrict__ att, const float* __restrict__ bias,
                      const int* __restrict__ batch, float* __restrict__ pooled, int N){
    __shared__ float pool[8][HC];
    __shared__ int sb[8];
    int sg = threadIdx.x >> 5;
    int d = blockIdx.x*(blockDim.x >> 5) + sg;
    int lane = threadIdx.x & 31;
    bool valid = (d < N);
    int dcl = valid ? d : 0;
    int h = lane >> 4, r = lane & 15;

    union U { uint4 u[2]; __half2 h2[8]; };
    U xr;
    {
        const uint4* bp = (const uint4*)(B16 + (size_t)dcl*HC + h*CH);
        xr.u[0] = bp[0]; xr.u[1] = bp[1];
    }
    __half2 at2[8];
    const float* atf = att + h*CH;
    #pragma unroll
    for (int i = 0; i < 8; ++i) at2[i] = __floats2half2_rn(atf[2*i], atf[2*i+1]);
    const __half2 ns2 = __float2half2_rn(NSLOPE);

    float l = 0.f;
    __half2 acc2[8];
    #pragma unroll
    for (int i = 0; i < 8; ++i) acc2[i] = __float2half2_rn(0.f);

    int beg = rs[dcl], end = valid ? rs[dcl+1] : beg;
    int p = beg + r;
    for (; p + 16 < end; p += 32){
        int s0 = __builtin_nontemporal_load(col + p);
        int s1 = __builtin_nontemporal_load(col + p + 16);
        const uint4* rp0 = (const uint4*)(A16 + (size_t)s0*HC + h*CH);
        const uint4* rp1 = (const uint4*)(A16 + (size_t)s1*HC + h*CH);
        U a, b;
        a.u[0] = rp0[0]; a.u[1] = rp0[1];     // both gathers in flight before use
        b.u[0] = rp1[0]; b.u[1] = rp1[1];
        __half2 sc2 = __float2half2_rn(0.f);
        #pragma unroll
        for (int i = 0; i < 8; ++i){
            __half2 m  = __hadd2(a.h2[i], xr.h2[i]);
            __half2 lk = pkmax2(m, __hmul2(m, ns2));
            sc2 = __hfma2(lk, at2[i], sc2);
        }
        float ex = __expf(__low2float(sc2) + __high2float(sc2));
        l += ex;
        __half2 exh = __float2half2_rn(ex);
        #pragma unroll
        for (int i = 0; i < 8; ++i) acc2[i] = __hfma2(a.h2[i], exh, acc2[i]);

        sc2 = __float2half2_rn(0.f);
        #pragma unroll
        for (int i = 0; i < 8; ++i){
            __half2 m  = __hadd2(b.h2[i], xr.h2[i]);
            __half2 lk = pkmax2(m, __hmul2(m, ns2));
            sc2 = __hfma2(lk, at2[i], sc2);
        }
        ex = __expf(__low2float(sc2) + __high2float(sc2));
        l += ex;
        exh = __float2half2_rn(ex);
        #pragma unroll
        for (int i = 0; i < 8; ++i) acc2[i] = __hfma2(b.h2[i], exh, acc2[i]);
    }
    if (p < end){
        int s = __builtin_nontemporal_load(col + p);
        const uint4* rp = (const uint4*)(A16 + (size_t)s*HC + h*CH);
        U a;
        a.u[0] = rp[0]; a.u[1] = rp[1];
        __half2 sc2 = __float2half2_rn(0.f);
        #pragma unroll
        for (int i = 0; i < 8; ++i){
            __half2 m  = __hadd2(a.h2[i], xr.h2[i]);
            __half2 lk = pkmax2(m, __hmul2(m, ns2));
            sc2 = __hfma2(lk, at2[i], sc2);
        }
        float ex = __expf(__low2float(sc2) + __high2float(sc2));
        l += ex;
        __half2 exh = __float2half2_rn(ex);
        #pragma unroll
        for (int i = 0; i < 8; ++i) acc2[i] = __hfma2(a.h2[i], exh, acc2[i]);
    }

    // channel-splitting halving merge across the 16-lane half.
    __half2 v4[4];
    {
        bool hi = (r & 8) != 0;
        #pragma unroll
        for (int i = 0; i < 4; ++i){
            __half2 send = hi ? acc2[i] : acc2[i+4];
            __half2 recv = sfx2(send, 8);
            v4[i] = __hadd2(hi ? acc2[i+4] : acc2[i], recv);
        }
    }
    __half2 v2[2];
    {
        bool hi = (r & 4) != 0;
        __half2 s0 = hi ? v4[0] : v4[2];
        __half2 s1 = hi ? v4[1] : v4[3];
        __half2 r0 = sfx2(s0, 4);
        __half2 r1 = sfx2(s1, 4);
        v2[0] = __hadd2(hi ? v4[2] : v4[0], r0);
        v2[1] = __hadd2(hi ? v4[3] : v4[1], r1);
    }
    __half2 v1;
    {
        bool hi = (r & 2) != 0;
        __half2 send = hi ? v2[0] : v2[1];
        __half2 recv = sfx2(send, 2);
        v1 = __hadd2(hi ? v2[1] : v2[0], recv);
    }
    float mine;
    {
        bool hi = (r & 1) != 0;
        float lo = __low2float(v1), hf = __high2float(v1);
        float send = hi ? lo : hf;
        float recv = __shfl_xor(send, 1);
        mine = (hi ? hf : lo) + recv;   // lane r owns channel r total
    }
    #pragma unroll
    for (int off = 8; off >= 1; off >>= 1) l += __shfl_xor(l, off);

    float invl = 1.f/(l + 1e-16f);
    float val = mine*invl + bias[h*CH + r];
    val = (val > 0.f) ? val : expm1f(val);

    // ---- block-level dedup, then one device atomic per (graph,channel) ----
    if (lane == 0) sb[sg] = valid ? batch[d] : (-1 - sg);   // unique sentinel
    pool[sg][h*CH + r] = val;                               // own row, plain store
    __syncthreads();
    int myb = sb[sg];
    int first = sg;
    #pragma unroll
    for (int j = 7; j >= 0; --j) if (sb[j] == myb) first = j;
    if (valid && first == sg){
        float s = 0.f;
        #pragma unroll
        for (int j = 0; j < 8; ++j) if (sb[j] == myb) s += pool[j][h*CH + r];
        atomicAdd(&pooled[(size_t)myb*HC + h*CH + r], s);
    }
}

// tiny classifier: mean over graph (counts from gb) + fc + log_softmax
__global__ void k_fc(const float* __restrict__ pooled, const int* __restrict__ gb,
                     const float* __restrict__ Wfc, const float* __restrict__ bfc,
                     float* __restrict__ out, int G){
    int t = threadIdx.x;            // 64 -> two graphs per wave
    int g = blockIdx.x*2 + (t >> 5);
    int c = t & 31;
    if (g >= G) return;
    float cnt = (float)(gb[g+1] - gb[g]);
    if (cnt < 1.f) cnt = 1.f;
    float pv = pooled[g*HC + c] / cnt;
    float p0 = pv * Wfc[c];
    float p1 = pv * Wfc[HC + c];
    #pragma unroll
    for (int off = 16; off >= 1; off >>= 1){
        p0 += __shfl_xor(p0, off, 32);
        p1 += __shfl_xor(p1, off, 32);
    }
    if (c == 0){
        float l0 = p0 + bfc[0], l1 = p1 + bfc[1];
        float m = (l0 > l1) ? l0 : l1;
        float lse = m + logf(__expf(l0 - m) + __expf(l1 - m));
        out[g*2 + 0] = l0 - lse;
        out[g*2 + 1] = l1 - lse;
    }
}

extern "C" void kernel_launch(void* const* d_in, const int* in_sizes, int n_in,
                              void* d_out, int out_size, void* d_ws, size_t ws_size,
                              hipStream_t stream) {
    const int*   ei    = (const int*)  d_in[0];
    const int*   batch = (const int*)  d_in[1];
    const float* rnd   = (const float*)d_in[2];
    const float* W1l   = (const float*)d_in[3];
    const float* b1l   = (const float*)d_in[4];
    const float* W1r   = (const float*)d_in[5];
    const float* b1r   = (const float*)d_in[6];
    const float* att1  = (const float*)d_in[7];
    const float* bias1 = (const float*)d_in[8];
    const float* W2l   = (const float*)d_in[9];
    const float* b2l   = (const float*)d_in[10];
    const float* W2r   = (const float*)d_in[11];
    const float* b2r   = (const float*)d_in[12];
    const float* att2  = (const float*)d_in[13];
    const float* bias2 = (const float*)d_in[14];
    const float* Wfc   = (const float*)d_in[15];
    const float* bfc   = (const float*)d_in[16];

    const int E  = in_sizes[0] / 2;
    const int N  = in_sizes[1];
    const int G  = out_size / 2;
    const int EP = E + N;                    // pairs (edges + self-loops)
    const int NB2 = (N + 127) >> 7;          // 128-node coarse buckets
    const int halfN = (((N + 1) >> 1) + 1) & ~1;   // even half-range
    const int nWloc = halfN >> 1;            // packed u16 words per half

    // workspace layout. hb and part simultaneously live (k_front, k_fine);
    // A16/B16 alias the hb region (written only after k_fine). dr/rs/col
    // above part; zeroed ctrl (gPair/pooled/gcur) above those.
    float* ws        = (float*)d_ws;
    __half* A16      = (__half*)ws;             // N*HC halfs
    __half* B16      = A16 + (size_t)N*HC;      // N*HC halfs
    unsigned* hb     = (unsigned*)ws;           // NSL*2*nWloc words
    size_t off1      = (size_t)NSL*2*nWloc;
    if (off1 < (size_t)N*HC) off1 = (size_t)N*HC;   // cover A16+B16
    unsigned* part   = (unsigned*)ws + off1;    // NB2*CBMAX u32 (fixed-capacity)
    size_t off2      = off1 + (size_t)NB2*CBMAX;
    off2 = (off2 + 1) & ~(size_t)1;
    float2* dr       = (float2*)(ws + off2);    // N float2 (deg, rnd)
    int*   rs        = (int*)(dr + N);          // N+1
    int*   col       = rs + N + 1;              // EP
    unsigned* gPair  = (unsigned*)(col + EP);   // NB2MAX   [zeroed]
    float* pooled    = (float*)(gPair + NB2MAX);// G*HC     [zeroed]
    int*   gcur      = (int*)(pooled + (size_t)G*HC);  // NB2MAX [zeroed]
    int*   gb        = gcur + NB2MAX;           // G+1

    const int T = 256;
    const int gD16 = (N + (T>>4) - 1)/(T>>4);   // 16-lane-per-dst subgroups (layer 1)
    const int gD32 = (N + (T>>5) - 1)/(T>>5);   // 32-lane-per-dst subgroups (layer 2)
    const int nTiles = (EP + TILE - 1)/TILE;
    const int nGb    = (G + 1 + 511)/512;

    // gPair + pooled + gcur adjacent: one memset zeroes all three
    (void)hipMemsetAsync(gPair, 0,
        (size_t)(NB2MAX + (size_t)G*HC + NB2MAX)*sizeof(unsigned), stream);

    // ---- CSR build: front (hsrc ∥ p2 ∥ gb), fine (+hred +scan) ----
    k_front<<<NSL*2 + nTiles + nGb, 512, 0, stream>>>(ei, E, EP, halfN, hb, gPair,
                                   gcur, part, batch, gb, N, G, nTiles);
    k_fine <<<NB2, T, 0, stream>>>(part, hb, gPair, halfN, rnd, rs, dr, col, N, EP);

    // ---- layer 1 fused with layer-2 projection (A16/B16; X never materialized) ----
    k_gat1<<<gD16, T, 0, stream>>>(rs, col, dr,
                                   W1l, b1l, W1r, b1r, att1, bias1,
                                   W2l, b2l, W2r, b2r, A16, B16, N);

    // ---- layer 2 fused with mean-pool accumulation ----
    k_gat <<<gD32, T, 0, stream>>>(rs, col, A16, B16, att2, bias2, batch, pooled, N);

    // ---- tiny classifier ----
    k_fc  <<<(G + 1)/2, 64, 0, stream>>>(pooled, gb, Wfc, bfc, (float*)d_out, G);
}